// Round 2
// baseline (1377.064 us; speedup 1.0000x reference)
//
#include <hip/hip_runtime.h>

#define LM 56

// ---------------- ws layout (bytes) ----------------
#define OFF_TMPA  0ull
#define OFF_Z1    16777216ull
#define OFF_Z2    33554432ull
#define OFF_EIG   50331648ull            // 128*4 floats
#define OFF_DIFFP (OFF_EIG + 4096ull)    // 128 doubles
#define OFF_OFFP  (OFF_DIFFP + 1024ull)  // 128 doubles
#define OFF_TRP   (OFF_OFFP + 1024ull)   // 128 doubles
#define OFF_SMALL (OFF_TRP + 1024ull)    // [0]=cp_sum, [1]=sreg_total

static __device__ __forceinline__ float blockReduceSumF(float v, float* red, int t) {
  red[t] = v; __syncthreads();
  #pragma unroll
  for (int s = 128; s > 0; s >>= 1) { if (t < s) red[t] += red[t + s]; __syncthreads(); }
  float r = red[0]; __syncthreads();
  return r;
}

static __device__ __forceinline__ double blockReduceSumD(double v, double* red, int t) {
  red[t] = v; __syncthreads();
  #pragma unroll
  for (int s = 128; s > 0; s >>= 1) { if (t < s) red[t] += red[t + s]; __syncthreads(); }
  double r = red[0]; __syncthreads();
  return r;
}

// ---------------- batched GEMM: C[b] = A[b] @ op(B[b]) (all 256x256 fp32) ----------------
template<bool TRANSB, bool BATB>
__global__ __launch_bounds__(256) void gemmk(const float* __restrict__ A, size_t sA,
                                             const float* __restrict__ B, size_t sB,
                                             float* __restrict__ C)
{
  __shared__ float As[16][68];
  __shared__ float Bs[16][68];
  const int b = blockIdx.z;
  const float* Ab = A + (size_t)b * sA;
  const float* Bb = BATB ? (B + (size_t)b * sB) : B;
  float* Cb = C + (size_t)b * 65536;
  const int tile_m = blockIdx.y * 64, tile_n = blockIdx.x * 64;
  const int tid = threadIdx.x;
  const int tm = tid >> 4, tn = tid & 15;
  float acc[4][4] = {{0.f,0.f,0.f,0.f},{0.f,0.f,0.f,0.f},{0.f,0.f,0.f,0.f},{0.f,0.f,0.f,0.f}};

  for (int k0 = 0; k0 < 256; k0 += 16) {
    {
      int r = tid >> 2, c4 = (tid & 3) << 2;
      float4 av = *(const float4*)(Ab + (size_t)(tile_m + r) * 256 + k0 + c4);
      As[c4 + 0][r] = av.x; As[c4 + 1][r] = av.y; As[c4 + 2][r] = av.z; As[c4 + 3][r] = av.w;
    }
    if (!TRANSB) {
      int r = tid >> 4, c4 = (tid & 15) << 2;
      float4 bv = *(const float4*)(Bb + (size_t)(k0 + r) * 256 + tile_n + c4);
      *(float4*)&Bs[r][c4] = bv;
    } else {
      int r = tid >> 2, c4 = (tid & 3) << 2;
      float4 bv = *(const float4*)(Bb + (size_t)(tile_n + r) * 256 + k0 + c4);
      Bs[c4 + 0][r] = bv.x; Bs[c4 + 1][r] = bv.y; Bs[c4 + 2][r] = bv.z; Bs[c4 + 3][r] = bv.w;
    }
    __syncthreads();
    #pragma unroll
    for (int kk = 0; kk < 16; ++kk) {
      float4 av = *(const float4*)&As[kk][tm << 2];
      float4 bv = *(const float4*)&Bs[kk][tn << 2];
      acc[0][0] += av.x * bv.x; acc[0][1] += av.x * bv.y; acc[0][2] += av.x * bv.z; acc[0][3] += av.x * bv.w;
      acc[1][0] += av.y * bv.x; acc[1][1] += av.y * bv.y; acc[1][2] += av.y * bv.z; acc[1][3] += av.y * bv.w;
      acc[2][0] += av.z * bv.x; acc[2][1] += av.z * bv.y; acc[2][2] += av.z * bv.z; acc[2][3] += av.z * bv.w;
      acc[3][0] += av.w * bv.x; acc[3][1] += av.w * bv.y; acc[3][2] += av.w * bv.z; acc[3][3] += av.w * bv.w;
    }
    __syncthreads();
  }
  #pragma unroll
  for (int q = 0; q < 4; ++q) {
    float4 cv = make_float4(acc[q][0], acc[q][1], acc[q][2], acc[q][3]);
    *(float4*)(Cb + (size_t)(tile_m + (tm << 2) + q) * 256 + tile_n + (tn << 2)) = cv;
  }
}

// ---------------- per-(z,b) reductions: diff, offdiag, transform ----------------
__global__ __launch_bounds__(256) void reduce_zk(const float* __restrict__ Z1, const float* __restrict__ Z2,
                                                 const float* __restrict__ ti,
                                                 double* __restrict__ diffP, double* __restrict__ offP,
                                                 double* __restrict__ trP)
{
  __shared__ double red[256];
  int blk = blockIdx.x, t = threadIdx.x;
  int z = blk >> 6, b = blk & 63;
  const float* M = (z ? Z2 : Z1) + (size_t)b * 65536;
  const float* Mr = ti + ((size_t)b * 6 + (z ? 5 : 4)) * 65536;
  double d = 0, o = 0, tr = 0;
  for (int e = t; e < 65536; e += 256) {
    float a = M[e];
    int i = e >> 8, j = e & 255;
    d += (double)fabsf(a - (i == j ? 1.0f : 0.0f));
    if (i != j) o += (double)fabsf(a);
    tr += (double)fabsf(a - Mr[e]);
  }
  d = blockReduceSumD(d, red, t);
  o = blockReduceSumD(o, red, t);
  tr = blockReduceSumD(tr, red, t);
  if (t == 0) { diffP[blk] = d; offP[blk] = o; trP[blk] = tr; }
}

// ---------------- CP reconstruction loss ----------------
__global__ __launch_bounds__(256) void cp_kernel(const float* __restrict__ ti,
                                                 const float* __restrict__ Z1, const float* __restrict__ Z2,
                                                 const float* __restrict__ cpA, const float* __restrict__ cpB,
                                                 const float* __restrict__ cpC, double* __restrict__ smallp)
{
  __shared__ float Bsh[256][4];
  __shared__ float Csh[256][4];
  __shared__ double red[256];
  int blk = blockIdx.x, t = threadIdx.x;
  int b = blk / 6, i = blk - b * 6;
  const float* T = (i < 4) ? (ti + ((size_t)b * 6 + i) * 65536)
                           : ((i == 4 ? Z1 : Z2) + (size_t)b * 65536);
  *(float4*)&Bsh[t][0] = *(const float4*)(cpB + ((size_t)b * 256 + t) * 4);
  *(float4*)&Csh[t][0] = *(const float4*)(cpC + ((size_t)b * 256 + t) * 4);
  float a0 = cpA[((size_t)b * 6 + i) * 4 + 0];
  float a1 = cpA[((size_t)b * 6 + i) * 4 + 1];
  float a2 = cpA[((size_t)b * 6 + i) * 4 + 2];
  float a3 = cpA[((size_t)b * 6 + i) * 4 + 3];
  __syncthreads();
  float c0 = Csh[t][0], c1 = Csh[t][1], c2 = Csh[t][2], c3 = Csh[t][3];
  double acc = 0;
  for (int j = 0; j < 256; ++j) {
    float recon = a0 * Bsh[j][0] * c0 + a1 * Bsh[j][1] * c1 + a2 * Bsh[j][2] * c2 + a3 * Bsh[j][3] * c3;
    float dv = recon - T[(size_t)j * 256 + t];
    acc += (double)dv * (double)dv;
  }
  acc = blockReduceSumD(acc, red, t);
  if (t == 0) atomicAdd(&smallp[0], acc);
}

// ---------------- S-matrix regularizers ----------------
__global__ __launch_bounds__(256) void sreg_kernel(const float* __restrict__ S1, const float* __restrict__ S2,
                                                   const float* __restrict__ S3, const float* __restrict__ S4,
                                                   double* __restrict__ smallp)
{
  __shared__ double red[256];
  int t = threadIdx.x;
  double tot = 0;
  #pragma unroll
  for (int s = 0; s < 4; ++s) {
    const float* S = (s == 0) ? S1 : (s == 1) ? S2 : (s == 2) ? S3 : S4;
    for (int e = t; e < 65536; e += 256) {
      int i = e >> 8, j = e & 255;
      float a = S[e];
      tot += (double)fabsf(a - (i == j ? 1.0f : 0.0f));
      if (i != j) tot += (double)fabsf(a);
    }
  }
  tot = blockReduceSumD(tot, red, t);
  if (t == 0) smallp[1] = -tot / 65536.0;
}

__global__ void initk(double* smallp) { smallp[0] = 0.0; smallp[1] = 0.0; }

// ---------------- MLP heads -> logits ----------------
__global__ __launch_bounds__(64) void head_kernel(
    const float* __restrict__ seed_ic, const float* __restrict__ seed_sir,
    const float* __restrict__ seed_icc, const float* __restrict__ seed_sirc,
    const float* __restrict__ scalars,
    const float* __restrict__ cpA, const float* __restrict__ cpB, const float* __restrict__ cpC,
    const float* __restrict__ cpW1, const float* __restrict__ cpb1,
    const float* __restrict__ cpw2, const float* __restrict__ cpb2,
    const float* __restrict__ sW1, const float* __restrict__ sb1,
    const float* __restrict__ sw2, const float* __restrict__ sb2,
    const float* __restrict__ fW1, const float* __restrict__ fb1,
    const float* __restrict__ fw2, const float* __restrict__ fb2,
    float* __restrict__ out)
{
  int b = blockIdx.x, l = threadIdx.x;
  __shared__ float tri[4][3];
  __shared__ float cps[4], seds[4];
  __shared__ float hbuf[128];
  if (l < 4) {
    float s = 0;
    #pragma unroll
    for (int i = 0; i < 6; ++i) s += cpA[((size_t)b * 6 + i) * 4 + l];
    tri[l][0] = s * (1.0f / 6.0f);
  }
  float4 sB = make_float4(0,0,0,0), sC = make_float4(0,0,0,0);
  for (int j = l; j < 256; j += 64) {
    float4 v = *(const float4*)(cpB + ((size_t)b * 256 + j) * 4);
    sB.x += v.x; sB.y += v.y; sB.z += v.z; sB.w += v.w;
    float4 w = *(const float4*)(cpC + ((size_t)b * 256 + j) * 4);
    sC.x += w.x; sC.y += w.y; sC.z += w.z; sC.w += w.w;
  }
  #pragma unroll
  for (int off = 32; off > 0; off >>= 1) {
    sB.x += __shfl_down(sB.x, off); sB.y += __shfl_down(sB.y, off);
    sB.z += __shfl_down(sB.z, off); sB.w += __shfl_down(sB.w, off);
    sC.x += __shfl_down(sC.x, off); sC.y += __shfl_down(sC.y, off);
    sC.z += __shfl_down(sC.z, off); sC.w += __shfl_down(sC.w, off);
  }
  if (l == 0) {
    tri[0][1] = sB.x * (1.0f/256.0f); tri[1][1] = sB.y * (1.0f/256.0f);
    tri[2][1] = sB.z * (1.0f/256.0f); tri[3][1] = sB.w * (1.0f/256.0f);
    tri[0][2] = sC.x * (1.0f/256.0f); tri[1][2] = sC.y * (1.0f/256.0f);
    tri[2][2] = sC.z * (1.0f/256.0f); tri[3][2] = sC.w * (1.0f/256.0f);
  }
  __syncthreads();
  if (l < 4) {
    float s = 0;
    for (int hh = 0; hh < 32; ++hh) {
      float z = cpb1[l * 32 + hh];
      #pragma unroll
      for (int d = 0; d < 3; ++d) z += tri[l][d] * cpW1[(l * 32 + hh) * 3 + d];
      z = fmaxf(z, 0.0f);
      s += z * cpw2[l * 32 + hh];
    }
    cps[l] = s + cpb2[l];
  }
  for (int p = l; p < 128; p += 64) {
    int j = p >> 5, hh = p & 31;
    const float* sv = (j == 0) ? seed_ic : (j == 1) ? seed_sir : (j == 2) ? seed_icc : seed_sirc;
    sv += (size_t)b * 256;
    const float* wrow = sW1 + ((size_t)(j * 32 + hh)) * 256;
    float z = sb1[j * 32 + hh];
    for (int k = 0; k < 256; ++k) z += sv[k] * wrow[k];
    z = fmaxf(z, 0.0f);
    hbuf[p] = z * sw2[j * 32 + hh];
  }
  __syncthreads();
  if (l < 4) {
    float s = 0;
    #pragma unroll
    for (int hh = 0; hh < 32; ++hh) s += hbuf[l * 32 + hh];
    seds[l] = s + sb2[l];
  }
  __syncthreads();
  float av = 0.0f;
  if (l < 32) {
    float z = fb1[l];
    #pragma unroll
    for (int d = 0; d < 10; ++d) {
      float cd = (d < 4) ? cps[d] : (d < 8) ? seds[d - 4] : scalars[b * 2 + (d - 8)];
      z += cd * fW1[l * 10 + d];
    }
    z = fmaxf(z, 0.0f);
    av = z * fw2[l];
  }
  #pragma unroll
  for (int off = 16; off > 0; off >>= 1) av += __shfl_down(av, off);
  if (l == 0) out[b] = av + fb2[0];
}

// ---------------- in-place symmetrize M <- (M + M^T)/2 (JAX eigvalsh symmetrize_input) ----------------
__global__ __launch_bounds__(256) void symm_kernel(float* __restrict__ Z1, float* __restrict__ Z2)
{
  int mtx = blockIdx.x >> 8;
  int i = blockIdx.x & 255;
  int j = threadIdx.x;
  float* M = (mtx < 64) ? (Z1 + (size_t)mtx * 65536) : (Z2 + (size_t)(mtx - 64) * 65536);
  if (i < j) {
    float up = M[(size_t)i * 256 + j];
    float lo = M[(size_t)j * 256 + i];
    float m = 0.5f * (up + lo);
    M[(size_t)i * 256 + j] = m;
    M[(size_t)j * 256 + i] = m;
  }
}

// ---------------- Lanczos (m=LM, CGS2 reortho) + Sturm bisection for eigenvalues idx 1..4 ----------------
__global__ __launch_bounds__(256) void lanczos_kernel(const float* __restrict__ Z1, const float* __restrict__ Z2,
                                                      float* __restrict__ eig)
{
  __shared__ float V[LM][257];
  __shared__ float wsv[256];
  __shared__ float red[256];
  __shared__ float dots[256];
  __shared__ float alpha[LM];
  __shared__ float beta[LM + 1];
  __shared__ int meff_s;
  int t = threadIdx.x;
  int mtx = blockIdx.x;
  const float* M = (mtx < 64) ? (Z1 + (size_t)mtx * 65536) : (Z2 + (size_t)(mtx - 64) * 65536);
  const float* col = M + t;

  unsigned u = (unsigned)t * 1103515245u + 12345u;
  float r0 = 0.05f + (float)((u >> 9) & 0x7FFF) * (1.0f / 32768.0f);
  float nrm2 = blockReduceSumF(r0 * r0, red, t);
  V[0][t] = r0 * rsqrtf(nrm2);
  if (t == 0) { beta[0] = 0.0f; meff_s = LM; }
  __syncthreads();

  float beta_prev = 0.0f;
  for (int j = 0; j < LM; ++j) {
    float acc = 0.0f;
    for (int jj = 0; jj < 256; ++jj) acc += col[(size_t)jj * 256] * V[j][jj];
    float aj = blockReduceSumF(acc * V[j][t], red, t);
    if (t == 0) alpha[j] = aj;
    acc -= aj * V[j][t];
    if (j > 0) acc -= beta_prev * V[j - 1][t];
    #pragma unroll
    for (int pass = 0; pass < 2; ++pass) {
      wsv[t] = acc; __syncthreads();
      float d = 0.0f;
      if (t <= j) {
        for (int k2 = 0; k2 < 256; ++k2) d += V[t][k2] * wsv[k2];
      }
      dots[t] = d; __syncthreads();
      for (int tt = 0; tt <= j; ++tt) acc -= dots[tt] * V[tt][t];
      __syncthreads();
    }
    float b2 = blockReduceSumF(acc * acc, red, t);
    float bn = sqrtf(b2);
    if (bn < 1e-6f * (fabsf(aj) + 1.0f)) {
      if (t == 0) meff_s = j + 1;
      __syncthreads();
      break;
    }
    if (t == 0) beta[j + 1] = bn;
    if (j + 1 < LM) V[j + 1][t] = acc / bn;
    beta_prev = bn;
    __syncthreads();
  }
  __syncthreads();
  int meff = meff_s;

  if (t < 4) {
    float lo = 1e30f, hi = -1e30f;
    for (int i = 0; i < meff; ++i) {
      float bl = (i > 0) ? fabsf(beta[i]) : 0.0f;
      float bu = (i + 1 < meff) ? fabsf(beta[i + 1]) : 0.0f;
      lo = fminf(lo, alpha[i] - bl - bu);
      hi = fmaxf(hi, alpha[i] + bl + bu);
    }
    int q = t + 1; if (q > meff - 1) q = meff - 1;
    for (int it = 0; it < 48; ++it) {
      float mid = 0.5f * (lo + hi);
      int cnt = 0;
      float d = alpha[0] - mid;
      if (fabsf(d) < 1e-20f) d = -1e-20f;
      cnt += (d < 0.0f);
      for (int i = 1; i < meff; ++i) {
        d = alpha[i] - mid - beta[i] * beta[i] / d;
        if (fabsf(d) < 1e-20f) d = -1e-20f;
        cnt += (d < 0.0f);
      }
      if (cnt >= q + 1) hi = mid; else lo = mid;
    }
    eig[mtx * 4 + t] = 0.5f * (lo + hi);
  }
}

// ---------------- final combine ----------------
__global__ __launch_bounds__(64) void combine_kernel(const float* __restrict__ eig,
    const double* __restrict__ diffP, const double* __restrict__ offP, const double* __restrict__ trP,
    const float* __restrict__ valo, const float* __restrict__ vali,
    const double* __restrict__ smallp, float* __restrict__ out)
{
  int l = threadIdx.x;
  float vo = valo[l], vi = vali[l];
  float el = 0, el2 = 0;
  #pragma unroll
  for (int e = 0; e < 4; ++e) {
    el  += fabsf(vo - eig[l * 4 + e]);
    el2 += fabsf(vi - eig[(64 + l) * 4 + e]);
  }
  float lo_ = el * 0.25f + 0.2f * (float)(diffP[l] * (1.0/65536.0)) - 0.1f * (float)(offP[l] * (1.0/65536.0));
  float li_ = el2 * 0.25f + 0.2f * (float)(diffP[64 + l] * (1.0/65536.0)) - 0.1f * (float)(offP[64 + l] * (1.0/65536.0));
  if (vo == 0.0f) lo_ = 0.0f;
  if (vi == 0.0f) li_ = 0.0f;
  float trb = (float)((trP[l] + trP[64 + l]) * (1.0/65536.0));
  #pragma unroll
  for (int off = 32; off > 0; off >>= 1) {
    lo_ += __shfl_down(lo_, off);
    li_ += __shfl_down(li_, off);
    trb += __shfl_down(trb, off);
  }
  if (l == 0) {
    out[64] = lo_ * (1.0f / 64.0f);
    out[65] = li_ * (1.0f / 64.0f);
    out[66] = (float)(smallp[0] / (64.0 * 6.0 * 65536.0));
    out[67] = 0.5f * (float)smallp[1] + 0.5f * (trb * (1.0f / 64.0f));
  }
}

extern "C" void kernel_launch(void* const* d_in, const int* in_sizes, int n_in,
                              void* d_out, int out_size, void* d_ws, size_t ws_size,
                              hipStream_t stream) {
  (void)in_sizes; (void)n_in; (void)out_size; (void)ws_size;
  const float* ti       = (const float*)d_in[0];
  const float* seed_ic  = (const float*)d_in[1];
  const float* seed_sir = (const float*)d_in[2];
  const float* seed_icc = (const float*)d_in[3];
  const float* seed_sirc= (const float*)d_in[4];
  const float* scalars  = (const float*)d_in[5];
  const float* valo     = (const float*)d_in[6];
  const float* vali     = (const float*)d_in[7];
  const float* S1p      = (const float*)d_in[8];
  const float* S2p      = (const float*)d_in[9];
  const float* S3p      = (const float*)d_in[10];
  const float* S4p      = (const float*)d_in[11];
  const float* cpA      = (const float*)d_in[12];
  const float* cpB      = (const float*)d_in[13];
  const float* cpC      = (const float*)d_in[14];
  const float* cpW1     = (const float*)d_in[15];
  const float* cpb1     = (const float*)d_in[16];
  const float* cpw2     = (const float*)d_in[17];
  const float* cpb2     = (const float*)d_in[18];
  const float* sW1      = (const float*)d_in[19];
  const float* sb1      = (const float*)d_in[20];
  const float* sw2      = (const float*)d_in[21];
  const float* sb2      = (const float*)d_in[22];
  const float* fW1      = (const float*)d_in[23];
  const float* fb1      = (const float*)d_in[24];
  const float* fw2      = (const float*)d_in[25];
  const float* fb2      = (const float*)d_in[26];

  char* ws = (char*)d_ws;
  float*  tmpA   = (float*)(ws + OFF_TMPA);
  float*  Z1     = (float*)(ws + OFF_Z1);
  float*  Z2     = (float*)(ws + OFF_Z2);
  float*  eig    = (float*)(ws + OFF_EIG);
  double* diffP  = (double*)(ws + OFF_DIFFP);
  double* offP   = (double*)(ws + OFF_OFFP);
  double* trP    = (double*)(ws + OFF_TRP);
  double* smallp = (double*)(ws + OFF_SMALL);
  float*  out    = (float*)d_out;

  initk<<<1, 1, 0, stream>>>(smallp);

  dim3 gg(4, 4, 64), gb(256);
  const size_t S6 = 6ull * 65536ull, S1b = 65536ull;
  // Z1 = ((ic1 @ S1) @ Z1r) @ S2 @ sir2^T
  gemmk<false,false><<<gg, gb, 0, stream>>>(ti + 0 * 65536, S6, S1p, 0, tmpA);
  gemmk<false,true ><<<gg, gb, 0, stream>>>(tmpA, S1b, ti + 4 * 65536, S6, Z1);
  gemmk<false,false><<<gg, gb, 0, stream>>>(Z1, S1b, S2p, 0, tmpA);
  gemmk<true ,true ><<<gg, gb, 0, stream>>>(tmpA, S1b, ti + 3 * 65536, S6, Z1);
  // Z2 = ((sir1 @ S3) @ Z2r) @ S4 @ ic2^T
  gemmk<false,false><<<gg, gb, 0, stream>>>(ti + 2 * 65536, S6, S3p, 0, tmpA);
  gemmk<false,true ><<<gg, gb, 0, stream>>>(tmpA, S1b, ti + 5 * 65536, S6, Z2);
  gemmk<false,false><<<gg, gb, 0, stream>>>(Z2, S1b, S4p, 0, tmpA);
  gemmk<true ,true ><<<gg, gb, 0, stream>>>(tmpA, S1b, ti + 1 * 65536, S6, Z2);

  reduce_zk<<<128, 256, 0, stream>>>(Z1, Z2, ti, diffP, offP, trP);
  cp_kernel<<<384, 256, 0, stream>>>(ti, Z1, Z2, cpA, cpB, cpC, smallp);
  sreg_kernel<<<1, 256, 0, stream>>>(S1p, S2p, S3p, S4p, smallp);
  head_kernel<<<64, 64, 0, stream>>>(seed_ic, seed_sir, seed_icc, seed_sirc, scalars,
                                     cpA, cpB, cpC, cpW1, cpb1, cpw2, cpb2,
                                     sW1, sb1, sw2, sb2, fW1, fb1, fw2, fb2, out);

  symm_kernel<<<32768, 256, 0, stream>>>(Z1, Z2);
  lanczos_kernel<<<128, 256, 0, stream>>>(Z1, Z2, eig);
  combine_kernel<<<1, 64, 0, stream>>>(eig, diffP, offP, trP, valo, vali, smallp, out);
}

// Round 3
// 781.204 us; speedup vs baseline: 1.7627x; 1.7627x over previous
//
#include <hip/hip_runtime.h>

#define LM 40

// ---------------- ws layout (bytes) ----------------
#define OFF_TMPA  0ull                   // 16MB scratch; reused as bf16 Msym (128*65536*2B = 16MB)
#define OFF_Z1    16777216ull
#define OFF_Z2    33554432ull
#define OFF_EIG   50331648ull            // 128*4 floats
#define OFF_DIFFP (OFF_EIG + 4096ull)    // 128 doubles
#define OFF_OFFP  (OFF_DIFFP + 1024ull)  // 128 doubles
#define OFF_TRP   (OFF_OFFP + 1024ull)   // 128 doubles
#define OFF_SMALL (OFF_TRP + 1024ull)    // [0]=cp_sum, [1]=sreg_total

typedef unsigned short ushort_t;

static __device__ __forceinline__ double blockReduceSumD(double v, double* red, int t) {
  red[t] = v; __syncthreads();
  #pragma unroll
  for (int s = 128; s > 0; s >>= 1) { if (t < s) red[t] += red[t + s]; __syncthreads(); }
  double r = red[0]; __syncthreads();
  return r;
}

// shuffle-based 256-thread reduce: 2 syncthreads
static __device__ __forceinline__ float blockReduce256(float v, float* red4, int lane, int wid) {
  #pragma unroll
  for (int off = 32; off > 0; off >>= 1) v += __shfl_down(v, off);
  if (lane == 0) red4[wid] = v;
  __syncthreads();
  float r = red4[0] + red4[1] + red4[2] + red4[3];
  __syncthreads();
  return r;
}

static __device__ __forceinline__ ushort_t f2bf(float f) {
  unsigned u = __float_as_uint(f);
  unsigned r = (u + 0x7fffu + ((u >> 16) & 1u)) >> 16;
  return (ushort_t)r;
}

// ---------------- batched GEMM: C[b] = A[b] @ op(B[b]) (all 256x256 fp32) ----------------
template<bool TRANSB, bool BATB>
__global__ __launch_bounds__(256) void gemmk(const float* __restrict__ A, size_t sA,
                                             const float* __restrict__ B, size_t sB,
                                             float* __restrict__ C)
{
  __shared__ float As[16][68];
  __shared__ float Bs[16][68];
  const int b = blockIdx.z;
  const float* Ab = A + (size_t)b * sA;
  const float* Bb = BATB ? (B + (size_t)b * sB) : B;
  float* Cb = C + (size_t)b * 65536;
  const int tile_m = blockIdx.y * 64, tile_n = blockIdx.x * 64;
  const int tid = threadIdx.x;
  const int tm = tid >> 4, tn = tid & 15;
  float acc[4][4] = {{0.f,0.f,0.f,0.f},{0.f,0.f,0.f,0.f},{0.f,0.f,0.f,0.f},{0.f,0.f,0.f,0.f}};

  for (int k0 = 0; k0 < 256; k0 += 16) {
    {
      int r = tid >> 2, c4 = (tid & 3) << 2;
      float4 av = *(const float4*)(Ab + (size_t)(tile_m + r) * 256 + k0 + c4);
      As[c4 + 0][r] = av.x; As[c4 + 1][r] = av.y; As[c4 + 2][r] = av.z; As[c4 + 3][r] = av.w;
    }
    if (!TRANSB) {
      int r = tid >> 4, c4 = (tid & 15) << 2;
      float4 bv = *(const float4*)(Bb + (size_t)(k0 + r) * 256 + tile_n + c4);
      *(float4*)&Bs[r][c4] = bv;
    } else {
      int r = tid >> 2, c4 = (tid & 3) << 2;
      float4 bv = *(const float4*)(Bb + (size_t)(tile_n + r) * 256 + k0 + c4);
      Bs[c4 + 0][r] = bv.x; Bs[c4 + 1][r] = bv.y; Bs[c4 + 2][r] = bv.z; Bs[c4 + 3][r] = bv.w;
    }
    __syncthreads();
    #pragma unroll
    for (int kk = 0; kk < 16; ++kk) {
      float4 av = *(const float4*)&As[kk][tm << 2];
      float4 bv = *(const float4*)&Bs[kk][tn << 2];
      acc[0][0] += av.x * bv.x; acc[0][1] += av.x * bv.y; acc[0][2] += av.x * bv.z; acc[0][3] += av.x * bv.w;
      acc[1][0] += av.y * bv.x; acc[1][1] += av.y * bv.y; acc[1][2] += av.y * bv.z; acc[1][3] += av.y * bv.w;
      acc[2][0] += av.z * bv.x; acc[2][1] += av.z * bv.y; acc[2][2] += av.z * bv.z; acc[2][3] += av.z * bv.w;
      acc[3][0] += av.w * bv.x; acc[3][1] += av.w * bv.y; acc[3][2] += av.w * bv.z; acc[3][3] += av.w * bv.w;
    }
    __syncthreads();
  }
  #pragma unroll
  for (int q = 0; q < 4; ++q) {
    float4 cv = make_float4(acc[q][0], acc[q][1], acc[q][2], acc[q][3]);
    *(float4*)(Cb + (size_t)(tile_m + (tm << 2) + q) * 256 + tile_n + (tn << 2)) = cv;
  }
}

// ---------------- per-(z,b) reductions: diff, offdiag, transform ----------------
__global__ __launch_bounds__(256) void reduce_zk(const float* __restrict__ Z1, const float* __restrict__ Z2,
                                                 const float* __restrict__ ti,
                                                 double* __restrict__ diffP, double* __restrict__ offP,
                                                 double* __restrict__ trP)
{
  __shared__ double red[256];
  int blk = blockIdx.x, t = threadIdx.x;
  int z = blk >> 6, b = blk & 63;
  const float* M = (z ? Z2 : Z1) + (size_t)b * 65536;
  const float* Mr = ti + ((size_t)b * 6 + (z ? 5 : 4)) * 65536;
  double d = 0, o = 0, tr = 0;
  for (int e = t; e < 65536; e += 256) {
    float a = M[e];
    int i = e >> 8, j = e & 255;
    d += (double)fabsf(a - (i == j ? 1.0f : 0.0f));
    if (i != j) o += (double)fabsf(a);
    tr += (double)fabsf(a - Mr[e]);
  }
  d = blockReduceSumD(d, red, t);
  o = blockReduceSumD(o, red, t);
  tr = blockReduceSumD(tr, red, t);
  if (t == 0) { diffP[blk] = d; offP[blk] = o; trP[blk] = tr; }
}

// ---------------- CP reconstruction loss ----------------
__global__ __launch_bounds__(256) void cp_kernel(const float* __restrict__ ti,
                                                 const float* __restrict__ Z1, const float* __restrict__ Z2,
                                                 const float* __restrict__ cpA, const float* __restrict__ cpB,
                                                 const float* __restrict__ cpC, double* __restrict__ smallp)
{
  __shared__ float Bsh[256][4];
  __shared__ float Csh[256][4];
  __shared__ double red[256];
  int blk = blockIdx.x, t = threadIdx.x;
  int b = blk / 6, i = blk - b * 6;
  const float* T = (i < 4) ? (ti + ((size_t)b * 6 + i) * 65536)
                           : ((i == 4 ? Z1 : Z2) + (size_t)b * 65536);
  *(float4*)&Bsh[t][0] = *(const float4*)(cpB + ((size_t)b * 256 + t) * 4);
  *(float4*)&Csh[t][0] = *(const float4*)(cpC + ((size_t)b * 256 + t) * 4);
  float a0 = cpA[((size_t)b * 6 + i) * 4 + 0];
  float a1 = cpA[((size_t)b * 6 + i) * 4 + 1];
  float a2 = cpA[((size_t)b * 6 + i) * 4 + 2];
  float a3 = cpA[((size_t)b * 6 + i) * 4 + 3];
  __syncthreads();
  float c0 = Csh[t][0], c1 = Csh[t][1], c2 = Csh[t][2], c3 = Csh[t][3];
  double acc = 0;
  for (int j = 0; j < 256; ++j) {
    float recon = a0 * Bsh[j][0] * c0 + a1 * Bsh[j][1] * c1 + a2 * Bsh[j][2] * c2 + a3 * Bsh[j][3] * c3;
    float dv = recon - T[(size_t)j * 256 + t];
    acc += (double)dv * (double)dv;
  }
  acc = blockReduceSumD(acc, red, t);
  if (t == 0) atomicAdd(&smallp[0], acc);
}

// ---------------- S-matrix regularizers (16 blocks) ----------------
__global__ __launch_bounds__(256) void sreg_kernel(const float* __restrict__ S1, const float* __restrict__ S2,
                                                   const float* __restrict__ S3, const float* __restrict__ S4,
                                                   double* __restrict__ smallp)
{
  __shared__ double red[256];
  int t = threadIdx.x, blk = blockIdx.x;
  int s = blk >> 2, part = blk & 3;
  const float* S = (s == 0) ? S1 : (s == 1) ? S2 : (s == 2) ? S3 : S4;
  double tot = 0;
  int e0 = part * 16384;
  for (int e = e0 + t; e < e0 + 16384; e += 256) {
    int i = e >> 8, j = e & 255;
    float a = S[e];
    tot += (double)fabsf(a - (i == j ? 1.0f : 0.0f));
    if (i != j) tot += (double)fabsf(a);
  }
  tot = blockReduceSumD(tot, red, t);
  if (t == 0) atomicAdd(&smallp[1], -tot / 65536.0);
}

__global__ void initk(double* smallp) { smallp[0] = 0.0; smallp[1] = 0.0; }

// ---------------- MLP heads -> logits ----------------
__global__ __launch_bounds__(64) void head_kernel(
    const float* __restrict__ seed_ic, const float* __restrict__ seed_sir,
    const float* __restrict__ seed_icc, const float* __restrict__ seed_sirc,
    const float* __restrict__ scalars,
    const float* __restrict__ cpA, const float* __restrict__ cpB, const float* __restrict__ cpC,
    const float* __restrict__ cpW1, const float* __restrict__ cpb1,
    const float* __restrict__ cpw2, const float* __restrict__ cpb2,
    const float* __restrict__ sW1, const float* __restrict__ sb1,
    const float* __restrict__ sw2, const float* __restrict__ sb2,
    const float* __restrict__ fW1, const float* __restrict__ fb1,
    const float* __restrict__ fw2, const float* __restrict__ fb2,
    float* __restrict__ out)
{
  int b = blockIdx.x, l = threadIdx.x;
  __shared__ float tri[4][3];
  __shared__ float cps[4], seds[4];
  __shared__ float hbuf[128];
  if (l < 4) {
    float s = 0;
    #pragma unroll
    for (int i = 0; i < 6; ++i) s += cpA[((size_t)b * 6 + i) * 4 + l];
    tri[l][0] = s * (1.0f / 6.0f);
  }
  float4 sB = make_float4(0,0,0,0), sC = make_float4(0,0,0,0);
  for (int j = l; j < 256; j += 64) {
    float4 v = *(const float4*)(cpB + ((size_t)b * 256 + j) * 4);
    sB.x += v.x; sB.y += v.y; sB.z += v.z; sB.w += v.w;
    float4 w = *(const float4*)(cpC + ((size_t)b * 256 + j) * 4);
    sC.x += w.x; sC.y += w.y; sC.z += w.z; sC.w += w.w;
  }
  #pragma unroll
  for (int off = 32; off > 0; off >>= 1) {
    sB.x += __shfl_down(sB.x, off); sB.y += __shfl_down(sB.y, off);
    sB.z += __shfl_down(sB.z, off); sB.w += __shfl_down(sB.w, off);
    sC.x += __shfl_down(sC.x, off); sC.y += __shfl_down(sC.y, off);
    sC.z += __shfl_down(sC.z, off); sC.w += __shfl_down(sC.w, off);
  }
  if (l == 0) {
    tri[0][1] = sB.x * (1.0f/256.0f); tri[1][1] = sB.y * (1.0f/256.0f);
    tri[2][1] = sB.z * (1.0f/256.0f); tri[3][1] = sB.w * (1.0f/256.0f);
    tri[0][2] = sC.x * (1.0f/256.0f); tri[1][2] = sC.y * (1.0f/256.0f);
    tri[2][2] = sC.z * (1.0f/256.0f); tri[3][2] = sC.w * (1.0f/256.0f);
  }
  __syncthreads();
  if (l < 4) {
    float s = 0;
    for (int hh = 0; hh < 32; ++hh) {
      float z = cpb1[l * 32 + hh];
      #pragma unroll
      for (int d = 0; d < 3; ++d) z += tri[l][d] * cpW1[(l * 32 + hh) * 3 + d];
      z = fmaxf(z, 0.0f);
      s += z * cpw2[l * 32 + hh];
    }
    cps[l] = s + cpb2[l];
  }
  for (int p = l; p < 128; p += 64) {
    int j = p >> 5, hh = p & 31;
    const float* sv = (j == 0) ? seed_ic : (j == 1) ? seed_sir : (j == 2) ? seed_icc : seed_sirc;
    sv += (size_t)b * 256;
    const float* wrow = sW1 + ((size_t)(j * 32 + hh)) * 256;
    float z = sb1[j * 32 + hh];
    for (int k = 0; k < 256; k += 4) {
      float4 a = *(const float4*)(sv + k);
      float4 w4 = *(const float4*)(wrow + k);
      z += a.x * w4.x + a.y * w4.y + a.z * w4.z + a.w * w4.w;
    }
    z = fmaxf(z, 0.0f);
    hbuf[p] = z * sw2[j * 32 + hh];
  }
  __syncthreads();
  if (l < 4) {
    float s = 0;
    #pragma unroll
    for (int hh = 0; hh < 32; ++hh) s += hbuf[l * 32 + hh];
    seds[l] = s + sb2[l];
  }
  __syncthreads();
  float av = 0.0f;
  if (l < 32) {
    float z = fb1[l];
    #pragma unroll
    for (int d = 0; d < 10; ++d) {
      float cd = (d < 4) ? cps[d] : (d < 8) ? seds[d - 4] : scalars[b * 2 + (d - 8)];
      z += cd * fW1[l * 10 + d];
    }
    z = fmaxf(z, 0.0f);
    av = z * fw2[l];
  }
  #pragma unroll
  for (int off = 16; off > 0; off >>= 1) av += __shfl_down(av, off);
  if (l == 0) out[b] = av + fb2[0];
}

// ---------------- symmetrize (Z + Z^T)/2 -> bf16 copy (JAX eigvalsh symmetrize_input) ----------------
__global__ __launch_bounds__(256) void symm_bf16(const float* __restrict__ Z1, const float* __restrict__ Z2,
                                                 ushort_t* __restrict__ Msym)
{
  int mtx = blockIdx.x >> 8;
  int i = blockIdx.x & 255;
  int j = threadIdx.x;
  const float* M = (mtx < 64) ? (Z1 + (size_t)mtx * 65536) : (Z2 + (size_t)(mtx - 64) * 65536);
  float a = M[(size_t)i * 256 + j];
  float bv = M[(size_t)j * 256 + i];
  float m = 0.5f * (a + bv);
  Msym[(size_t)mtx * 65536 + (size_t)i * 256 + j] = f2bf(m);
}

// ---------------- Lanczos (m=LM, CGS2 reortho, bf16 matvec) + Sturm bisection ----------------
__global__ __launch_bounds__(256) void lanczos_kernel(const ushort_t* __restrict__ Msym,
                                                      float* __restrict__ eig)
{
  __shared__ float V[LM][257];
  __shared__ float wsh[256];
  __shared__ float wred[8][32][9];
  __shared__ float dred[4][64];
  __shared__ float red4[4];
  __shared__ float alpha[LM];
  __shared__ float beta[LM + 1];

  int t = threadIdx.x;
  int lane = t & 63, wid = t >> 6;
  int mtx = blockIdx.x;
  const ushort_t* M = Msym + (size_t)mtx * 65536;

  // deterministic start vector
  unsigned u = (unsigned)t * 1103515245u + 12345u;
  float r0 = 0.05f + (float)((u >> 9) & 0x7FFF) * (1.0f / 32768.0f);
  float nrm2 = blockReduce256(r0 * r0, red4, lane, wid);
  V[0][t] = r0 * rsqrtf(nrm2);
  if (t == 0) beta[0] = 0.0f;
  __syncthreads();

  const int c = t & 31, s = t >> 5;          // matvec decomposition: cols 8c..8c+7, rows [32s,32s+32)
  const ushort_t* Mp0 = M + (size_t)(s * 32) * 256 + c * 8;

  float beta_prev = 0.0f;
  int meff = LM;
  for (int j = 0; j < LM; ++j) {
    // ---- w = M v_j (bf16 matrix, fp32 accum) ----
    float acc0=0,acc1=0,acc2=0,acc3=0,acc4=0,acc5=0,acc6=0,acc7=0;
    const float* vseg = &V[j][s * 32];
    #pragma unroll 4
    for (int r = 0; r < 32; ++r) {
      uint4 mu = *(const uint4*)(Mp0 + (size_t)r * 256);
      float vj = vseg[r];
      acc0 = fmaf(__uint_as_float(mu.x << 16),          vj, acc0);
      acc1 = fmaf(__uint_as_float(mu.x & 0xffff0000u),  vj, acc1);
      acc2 = fmaf(__uint_as_float(mu.y << 16),          vj, acc2);
      acc3 = fmaf(__uint_as_float(mu.y & 0xffff0000u),  vj, acc3);
      acc4 = fmaf(__uint_as_float(mu.z << 16),          vj, acc4);
      acc5 = fmaf(__uint_as_float(mu.z & 0xffff0000u),  vj, acc5);
      acc6 = fmaf(__uint_as_float(mu.w << 16),          vj, acc6);
      acc7 = fmaf(__uint_as_float(mu.w & 0xffff0000u),  vj, acc7);
    }
    wred[s][c][0] = acc0; wred[s][c][1] = acc1; wred[s][c][2] = acc2; wred[s][c][3] = acc3;
    wred[s][c][4] = acc4; wred[s][c][5] = acc5; wred[s][c][6] = acc6; wred[s][c][7] = acc7;
    __syncthreads();
    float wt = 0;
    {
      int wc = t >> 3, wq = t & 7;
      #pragma unroll
      for (int ss = 0; ss < 8; ++ss) wt += wred[ss][wc][wq];
    }
    // ---- alpha, three-term recurrence ----
    float vjt = V[j][t];
    float aj = blockReduce256(wt * vjt, red4, lane, wid);
    if (t == 0) alpha[j] = aj;
    wt -= aj * vjt;
    if (j > 0) wt -= beta_prev * V[j - 1][t];
    // ---- CGS2 full reorthogonalization, 2 passes ----
    #pragma unroll
    for (int pass = 0; pass < 2; ++pass) {
      wsh[t] = wt;
      __syncthreads();
      float p = 0.f;
      if (lane <= j) {
        const float* Vrow = &V[lane][wid * 64];
        const float* wseg = &wsh[wid * 64];
        #pragma unroll 8
        for (int k2 = 0; k2 < 64; ++k2) p = fmaf(Vrow[k2], wseg[k2], p);
      }
      dred[wid][lane] = p;
      __syncthreads();
      float corr = 0.f;
      for (int tt = 0; tt <= j; ++tt) {
        float d = dred[0][tt] + dred[1][tt] + dred[2][tt] + dred[3][tt];
        corr = fmaf(d, V[tt][t], corr);
      }
      wt -= corr;
      __syncthreads();
    }
    // ---- beta, next vector ----
    float bn = sqrtf(blockReduce256(wt * wt, red4, lane, wid));
    if (bn < 1e-6f * (fabsf(aj) + 1.0f)) { meff = j + 1; break; }
    if (t == 0) beta[j + 1] = bn;
    if (j + 1 < LM) V[j + 1][t] = wt / bn;
    beta_prev = bn;
    __syncthreads();
  }
  __syncthreads();

  // ---- Sturm bisection for T eigenvalues idx 1..4 (ascending) ----
  if (t < 4) {
    float lo = 1e30f, hi = -1e30f;
    for (int i = 0; i < meff; ++i) {
      float bl = (i > 0) ? fabsf(beta[i]) : 0.0f;
      float bu = (i + 1 < meff) ? fabsf(beta[i + 1]) : 0.0f;
      lo = fminf(lo, alpha[i] - bl - bu);
      hi = fmaxf(hi, alpha[i] + bl + bu);
    }
    int q = t + 1; if (q > meff - 1) q = meff - 1;
    for (int it = 0; it < 48; ++it) {
      float mid = 0.5f * (lo + hi);
      int cnt = 0;
      float d = alpha[0] - mid;
      if (fabsf(d) < 1e-20f) d = -1e-20f;
      cnt += (d < 0.0f);
      for (int i = 1; i < meff; ++i) {
        d = alpha[i] - mid - beta[i] * beta[i] / d;
        if (fabsf(d) < 1e-20f) d = -1e-20f;
        cnt += (d < 0.0f);
      }
      if (cnt >= q + 1) hi = mid; else lo = mid;
    }
    eig[mtx * 4 + t] = 0.5f * (lo + hi);
  }
}

// ---------------- final combine ----------------
__global__ __launch_bounds__(64) void combine_kernel(const float* __restrict__ eig,
    const double* __restrict__ diffP, const double* __restrict__ offP, const double* __restrict__ trP,
    const float* __restrict__ valo, const float* __restrict__ vali,
    const double* __restrict__ smallp, float* __restrict__ out)
{
  int l = threadIdx.x;
  float vo = valo[l], vi = vali[l];
  float el = 0, el2 = 0;
  #pragma unroll
  for (int e = 0; e < 4; ++e) {
    el  += fabsf(vo - eig[l * 4 + e]);
    el2 += fabsf(vi - eig[(64 + l) * 4 + e]);
  }
  float lo_ = el * 0.25f + 0.2f * (float)(diffP[l] * (1.0/65536.0)) - 0.1f * (float)(offP[l] * (1.0/65536.0));
  float li_ = el2 * 0.25f + 0.2f * (float)(diffP[64 + l] * (1.0/65536.0)) - 0.1f * (float)(offP[64 + l] * (1.0/65536.0));
  if (vo == 0.0f) lo_ = 0.0f;
  if (vi == 0.0f) li_ = 0.0f;
  float trb = (float)((trP[l] + trP[64 + l]) * (1.0/65536.0));
  #pragma unroll
  for (int off = 32; off > 0; off >>= 1) {
    lo_ += __shfl_down(lo_, off);
    li_ += __shfl_down(li_, off);
    trb += __shfl_down(trb, off);
  }
  if (l == 0) {
    out[64] = lo_ * (1.0f / 64.0f);
    out[65] = li_ * (1.0f / 64.0f);
    out[66] = (float)(smallp[0] / (64.0 * 6.0 * 65536.0));
    out[67] = 0.5f * (float)smallp[1] + 0.5f * (trb * (1.0f / 64.0f));
  }
}

extern "C" void kernel_launch(void* const* d_in, const int* in_sizes, int n_in,
                              void* d_out, int out_size, void* d_ws, size_t ws_size,
                              hipStream_t stream) {
  (void)in_sizes; (void)n_in; (void)out_size; (void)ws_size;
  const float* ti       = (const float*)d_in[0];
  const float* seed_ic  = (const float*)d_in[1];
  const float* seed_sir = (const float*)d_in[2];
  const float* seed_icc = (const float*)d_in[3];
  const float* seed_sirc= (const float*)d_in[4];
  const float* scalars  = (const float*)d_in[5];
  const float* valo     = (const float*)d_in[6];
  const float* vali     = (const float*)d_in[7];
  const float* S1p      = (const float*)d_in[8];
  const float* S2p      = (const float*)d_in[9];
  const float* S3p      = (const float*)d_in[10];
  const float* S4p      = (const float*)d_in[11];
  const float* cpA      = (const float*)d_in[12];
  const float* cpB      = (const float*)d_in[13];
  const float* cpC      = (const float*)d_in[14];
  const float* cpW1     = (const float*)d_in[15];
  const float* cpb1     = (const float*)d_in[16];
  const float* cpw2     = (const float*)d_in[17];
  const float* cpb2     = (const float*)d_in[18];
  const float* sW1      = (const float*)d_in[19];
  const float* sb1      = (const float*)d_in[20];
  const float* sw2      = (const float*)d_in[21];
  const float* sb2      = (const float*)d_in[22];
  const float* fW1      = (const float*)d_in[23];
  const float* fb1      = (const float*)d_in[24];
  const float* fw2      = (const float*)d_in[25];
  const float* fb2      = (const float*)d_in[26];

  char* ws = (char*)d_ws;
  float*    tmpA   = (float*)(ws + OFF_TMPA);
  ushort_t* Msym   = (ushort_t*)(ws + OFF_TMPA);   // reused after GEMMs
  float*    Z1     = (float*)(ws + OFF_Z1);
  float*    Z2     = (float*)(ws + OFF_Z2);
  float*    eig    = (float*)(ws + OFF_EIG);
  double*   diffP  = (double*)(ws + OFF_DIFFP);
  double*   offP   = (double*)(ws + OFF_OFFP);
  double*   trP    = (double*)(ws + OFF_TRP);
  double*   smallp = (double*)(ws + OFF_SMALL);
  float*    out    = (float*)d_out;

  initk<<<1, 1, 0, stream>>>(smallp);

  dim3 gg(4, 4, 64), gb(256);
  const size_t S6 = 6ull * 65536ull, S1b = 65536ull;
  // Z1 = ((ic1 @ S1) @ Z1r) @ S2 @ sir2^T
  gemmk<false,false><<<gg, gb, 0, stream>>>(ti + 0 * 65536, S6, S1p, 0, tmpA);
  gemmk<false,true ><<<gg, gb, 0, stream>>>(tmpA, S1b, ti + 4 * 65536, S6, Z1);
  gemmk<false,false><<<gg, gb, 0, stream>>>(Z1, S1b, S2p, 0, tmpA);
  gemmk<true ,true ><<<gg, gb, 0, stream>>>(tmpA, S1b, ti + 3 * 65536, S6, Z1);
  // Z2 = ((sir1 @ S3) @ Z2r) @ S4 @ ic2^T
  gemmk<false,false><<<gg, gb, 0, stream>>>(ti + 2 * 65536, S6, S3p, 0, tmpA);
  gemmk<false,true ><<<gg, gb, 0, stream>>>(tmpA, S1b, ti + 5 * 65536, S6, Z2);
  gemmk<false,false><<<gg, gb, 0, stream>>>(Z2, S1b, S4p, 0, tmpA);
  gemmk<true ,true ><<<gg, gb, 0, stream>>>(tmpA, S1b, ti + 1 * 65536, S6, Z2);

  reduce_zk<<<128, 256, 0, stream>>>(Z1, Z2, ti, diffP, offP, trP);
  cp_kernel<<<384, 256, 0, stream>>>(ti, Z1, Z2, cpA, cpB, cpC, smallp);
  sreg_kernel<<<16, 256, 0, stream>>>(S1p, S2p, S3p, S4p, smallp);
  head_kernel<<<64, 64, 0, stream>>>(seed_ic, seed_sir, seed_icc, seed_sirc, scalars,
                                     cpA, cpB, cpC, cpW1, cpb1, cpw2, cpb2,
                                     sW1, sb1, sw2, sb2, fW1, fb1, fw2, fb2, out);

  symm_bf16<<<32768, 256, 0, stream>>>(Z1, Z2, Msym);
  lanczos_kernel<<<128, 256, 0, stream>>>(Msym, eig);
  combine_kernel<<<1, 64, 0, stream>>>(eig, diffP, offP, trP, valo, vali, smallp, out);
}

// Round 4
// 692.337 us; speedup vs baseline: 1.9890x; 1.1284x over previous
//
#include <hip/hip_runtime.h>

#define LM 28

// ---------------- ws layout (bytes) ----------------
#define OFF_TMPA  0ull                   // 16MB scratch; reused as packed bf16 Msym (128*32768*4B = 16MB)
#define OFF_Z1    16777216ull
#define OFF_Z2    33554432ull
#define OFF_EIG   50331648ull            // 128*4 floats
#define OFF_DIFFP (OFF_EIG + 4096ull)    // 128 doubles
#define OFF_OFFP  (OFF_DIFFP + 1024ull)  // 128 doubles
#define OFF_TRP   (OFF_OFFP + 1024ull)   // 128 doubles
#define OFF_SMALL (OFF_TRP + 1024ull)    // [0]=cp_sum, [1]=sreg_total

typedef unsigned short ushort_t;

static __device__ __forceinline__ double blockReduceSumD(double v, double* red, int t) {
  red[t] = v; __syncthreads();
  #pragma unroll
  for (int s = 128; s > 0; s >>= 1) { if (t < s) red[t] += red[t + s]; __syncthreads(); }
  double r = red[0]; __syncthreads();
  return r;
}

// shuffle-based 256-thread reduce: 2 syncthreads
static __device__ __forceinline__ float blockReduce256(float v, float* red4, int lane, int wid) {
  #pragma unroll
  for (int off = 32; off > 0; off >>= 1) v += __shfl_down(v, off);
  if (lane == 0) red4[wid] = v;
  __syncthreads();
  float r = red4[0] + red4[1] + red4[2] + red4[3];
  __syncthreads();
  return r;
}

static __device__ __forceinline__ ushort_t f2bf(float f) {
  unsigned u = __float_as_uint(f);
  unsigned r = (u + 0x7fffu + ((u >> 16) & 1u)) >> 16;
  return (ushort_t)r;
}

// ---------------- batched GEMM: C[b] = A[b] @ op(B[b]) (all 256x256 fp32) ----------------
template<bool TRANSB, bool BATB>
__global__ __launch_bounds__(256) void gemmk(const float* __restrict__ A, size_t sA,
                                             const float* __restrict__ B, size_t sB,
                                             float* __restrict__ C)
{
  __shared__ float As[16][68];
  __shared__ float Bs[16][68];
  const int b = blockIdx.z;
  const float* Ab = A + (size_t)b * sA;
  const float* Bb = BATB ? (B + (size_t)b * sB) : B;
  float* Cb = C + (size_t)b * 65536;
  const int tile_m = blockIdx.y * 64, tile_n = blockIdx.x * 64;
  const int tid = threadIdx.x;
  const int tm = tid >> 4, tn = tid & 15;
  float acc[4][4] = {{0.f,0.f,0.f,0.f},{0.f,0.f,0.f,0.f},{0.f,0.f,0.f,0.f},{0.f,0.f,0.f,0.f}};

  for (int k0 = 0; k0 < 256; k0 += 16) {
    {
      int r = tid >> 2, c4 = (tid & 3) << 2;
      float4 av = *(const float4*)(Ab + (size_t)(tile_m + r) * 256 + k0 + c4);
      As[c4 + 0][r] = av.x; As[c4 + 1][r] = av.y; As[c4 + 2][r] = av.z; As[c4 + 3][r] = av.w;
    }
    if (!TRANSB) {
      int r = tid >> 4, c4 = (tid & 15) << 2;
      float4 bv = *(const float4*)(Bb + (size_t)(k0 + r) * 256 + tile_n + c4);
      *(float4*)&Bs[r][c4] = bv;
    } else {
      int r = tid >> 2, c4 = (tid & 3) << 2;
      float4 bv = *(const float4*)(Bb + (size_t)(tile_n + r) * 256 + k0 + c4);
      Bs[c4 + 0][r] = bv.x; Bs[c4 + 1][r] = bv.y; Bs[c4 + 2][r] = bv.z; Bs[c4 + 3][r] = bv.w;
    }
    __syncthreads();
    #pragma unroll
    for (int kk = 0; kk < 16; ++kk) {
      float4 av = *(const float4*)&As[kk][tm << 2];
      float4 bv = *(const float4*)&Bs[kk][tn << 2];
      acc[0][0] += av.x * bv.x; acc[0][1] += av.x * bv.y; acc[0][2] += av.x * bv.z; acc[0][3] += av.x * bv.w;
      acc[1][0] += av.y * bv.x; acc[1][1] += av.y * bv.y; acc[1][2] += av.y * bv.z; acc[1][3] += av.y * bv.w;
      acc[2][0] += av.z * bv.x; acc[2][1] += av.z * bv.y; acc[2][2] += av.z * bv.z; acc[2][3] += av.z * bv.w;
      acc[3][0] += av.w * bv.x; acc[3][1] += av.w * bv.y; acc[3][2] += av.w * bv.z; acc[3][3] += av.w * bv.w;
    }
    __syncthreads();
  }
  #pragma unroll
  for (int q = 0; q < 4; ++q) {
    float4 cv = make_float4(acc[q][0], acc[q][1], acc[q][2], acc[q][3]);
    *(float4*)(Cb + (size_t)(tile_m + (tm << 2) + q) * 256 + tile_n + (tn << 2)) = cv;
  }
}

// ---------------- per-(z,b) reductions: diff, offdiag, transform ----------------
__global__ __launch_bounds__(256) void reduce_zk(const float* __restrict__ Z1, const float* __restrict__ Z2,
                                                 const float* __restrict__ ti,
                                                 double* __restrict__ diffP, double* __restrict__ offP,
                                                 double* __restrict__ trP)
{
  __shared__ double red[256];
  int blk = blockIdx.x, t = threadIdx.x;
  int z = blk >> 6, b = blk & 63;
  const float* M = (z ? Z2 : Z1) + (size_t)b * 65536;
  const float* Mr = ti + ((size_t)b * 6 + (z ? 5 : 4)) * 65536;
  double d = 0, o = 0, tr = 0;
  for (int e = t; e < 65536; e += 256) {
    float a = M[e];
    int i = e >> 8, j = e & 255;
    d += (double)fabsf(a - (i == j ? 1.0f : 0.0f));
    if (i != j) o += (double)fabsf(a);
    tr += (double)fabsf(a - Mr[e]);
  }
  d = blockReduceSumD(d, red, t);
  o = blockReduceSumD(o, red, t);
  tr = blockReduceSumD(tr, red, t);
  if (t == 0) { diffP[blk] = d; offP[blk] = o; trP[blk] = tr; }
}

// ---------------- CP reconstruction loss ----------------
__global__ __launch_bounds__(256) void cp_kernel(const float* __restrict__ ti,
                                                 const float* __restrict__ Z1, const float* __restrict__ Z2,
                                                 const float* __restrict__ cpA, const float* __restrict__ cpB,
                                                 const float* __restrict__ cpC, double* __restrict__ smallp)
{
  __shared__ float Bsh[256][4];
  __shared__ float Csh[256][4];
  __shared__ double red[256];
  int blk = blockIdx.x, t = threadIdx.x;
  int b = blk / 6, i = blk - b * 6;
  const float* T = (i < 4) ? (ti + ((size_t)b * 6 + i) * 65536)
                           : ((i == 4 ? Z1 : Z2) + (size_t)b * 65536);
  *(float4*)&Bsh[t][0] = *(const float4*)(cpB + ((size_t)b * 256 + t) * 4);
  *(float4*)&Csh[t][0] = *(const float4*)(cpC + ((size_t)b * 256 + t) * 4);
  float a0 = cpA[((size_t)b * 6 + i) * 4 + 0];
  float a1 = cpA[((size_t)b * 6 + i) * 4 + 1];
  float a2 = cpA[((size_t)b * 6 + i) * 4 + 2];
  float a3 = cpA[((size_t)b * 6 + i) * 4 + 3];
  __syncthreads();
  float c0 = Csh[t][0], c1 = Csh[t][1], c2 = Csh[t][2], c3 = Csh[t][3];
  double acc = 0;
  for (int j = 0; j < 256; ++j) {
    float recon = a0 * Bsh[j][0] * c0 + a1 * Bsh[j][1] * c1 + a2 * Bsh[j][2] * c2 + a3 * Bsh[j][3] * c3;
    float dv = recon - T[(size_t)j * 256 + t];
    acc += (double)dv * (double)dv;
  }
  acc = blockReduceSumD(acc, red, t);
  if (t == 0) atomicAdd(&smallp[0], acc);
}

// ---------------- S-matrix regularizers (16 blocks) ----------------
__global__ __launch_bounds__(256) void sreg_kernel(const float* __restrict__ S1, const float* __restrict__ S2,
                                                   const float* __restrict__ S3, const float* __restrict__ S4,
                                                   double* __restrict__ smallp)
{
  __shared__ double red[256];
  int t = threadIdx.x, blk = blockIdx.x;
  int s = blk >> 2, part = blk & 3;
  const float* S = (s == 0) ? S1 : (s == 1) ? S2 : (s == 2) ? S3 : S4;
  double tot = 0;
  int e0 = part * 16384;
  for (int e = e0 + t; e < e0 + 16384; e += 256) {
    int i = e >> 8, j = e & 255;
    float a = S[e];
    tot += (double)fabsf(a - (i == j ? 1.0f : 0.0f));
    if (i != j) tot += (double)fabsf(a);
  }
  tot = blockReduceSumD(tot, red, t);
  if (t == 0) atomicAdd(&smallp[1], -tot / 65536.0);
}

__global__ void initk(double* smallp) { smallp[0] = 0.0; smallp[1] = 0.0; }

// ---------------- MLP heads -> logits ----------------
__global__ __launch_bounds__(64) void head_kernel(
    const float* __restrict__ seed_ic, const float* __restrict__ seed_sir,
    const float* __restrict__ seed_icc, const float* __restrict__ seed_sirc,
    const float* __restrict__ scalars,
    const float* __restrict__ cpA, const float* __restrict__ cpB, const float* __restrict__ cpC,
    const float* __restrict__ cpW1, const float* __restrict__ cpb1,
    const float* __restrict__ cpw2, const float* __restrict__ cpb2,
    const float* __restrict__ sW1, const float* __restrict__ sb1,
    const float* __restrict__ sw2, const float* __restrict__ sb2,
    const float* __restrict__ fW1, const float* __restrict__ fb1,
    const float* __restrict__ fw2, const float* __restrict__ fb2,
    float* __restrict__ out)
{
  int b = blockIdx.x, l = threadIdx.x;
  __shared__ float tri[4][3];
  __shared__ float cps[4], seds[4];
  __shared__ float hbuf[128];
  if (l < 4) {
    float s = 0;
    #pragma unroll
    for (int i = 0; i < 6; ++i) s += cpA[((size_t)b * 6 + i) * 4 + l];
    tri[l][0] = s * (1.0f / 6.0f);
  }
  float4 sB = make_float4(0,0,0,0), sC = make_float4(0,0,0,0);
  for (int j = l; j < 256; j += 64) {
    float4 v = *(const float4*)(cpB + ((size_t)b * 256 + j) * 4);
    sB.x += v.x; sB.y += v.y; sB.z += v.z; sB.w += v.w;
    float4 w = *(const float4*)(cpC + ((size_t)b * 256 + j) * 4);
    sC.x += w.x; sC.y += w.y; sC.z += w.z; sC.w += w.w;
  }
  #pragma unroll
  for (int off = 32; off > 0; off >>= 1) {
    sB.x += __shfl_down(sB.x, off); sB.y += __shfl_down(sB.y, off);
    sB.z += __shfl_down(sB.z, off); sB.w += __shfl_down(sB.w, off);
    sC.x += __shfl_down(sC.x, off); sC.y += __shfl_down(sC.y, off);
    sC.z += __shfl_down(sC.z, off); sC.w += __shfl_down(sC.w, off);
  }
  if (l == 0) {
    tri[0][1] = sB.x * (1.0f/256.0f); tri[1][1] = sB.y * (1.0f/256.0f);
    tri[2][1] = sB.z * (1.0f/256.0f); tri[3][1] = sB.w * (1.0f/256.0f);
    tri[0][2] = sC.x * (1.0f/256.0f); tri[1][2] = sC.y * (1.0f/256.0f);
    tri[2][2] = sC.z * (1.0f/256.0f); tri[3][2] = sC.w * (1.0f/256.0f);
  }
  __syncthreads();
  if (l < 4) {
    float s = 0;
    for (int hh = 0; hh < 32; ++hh) {
      float z = cpb1[l * 32 + hh];
      #pragma unroll
      for (int d = 0; d < 3; ++d) z += tri[l][d] * cpW1[(l * 32 + hh) * 3 + d];
      z = fmaxf(z, 0.0f);
      s += z * cpw2[l * 32 + hh];
    }
    cps[l] = s + cpb2[l];
  }
  for (int p = l; p < 128; p += 64) {
    int j = p >> 5, hh = p & 31;
    const float* sv = (j == 0) ? seed_ic : (j == 1) ? seed_sir : (j == 2) ? seed_icc : seed_sirc;
    sv += (size_t)b * 256;
    const float* wrow = sW1 + ((size_t)(j * 32 + hh)) * 256;
    float z = sb1[j * 32 + hh];
    for (int k = 0; k < 256; k += 4) {
      float4 a = *(const float4*)(sv + k);
      float4 w4 = *(const float4*)(wrow + k);
      z += a.x * w4.x + a.y * w4.y + a.z * w4.z + a.w * w4.w;
    }
    z = fmaxf(z, 0.0f);
    hbuf[p] = z * sw2[j * 32 + hh];
  }
  __syncthreads();
  if (l < 4) {
    float s = 0;
    #pragma unroll
    for (int hh = 0; hh < 32; ++hh) s += hbuf[l * 32 + hh];
    seds[l] = s + sb2[l];
  }
  __syncthreads();
  float av = 0.0f;
  if (l < 32) {
    float z = fb1[l];
    #pragma unroll
    for (int d = 0; d < 10; ++d) {
      float cd = (d < 4) ? cps[d] : (d < 8) ? seds[d - 4] : scalars[b * 2 + (d - 8)];
      z += cd * fW1[l * 10 + d];
    }
    z = fmaxf(z, 0.0f);
    av = z * fw2[l];
  }
  #pragma unroll
  for (int off = 16; off > 0; off >>= 1) av += __shfl_down(av, off);
  if (l == 0) out[b] = av + fb2[0];
}

// ---------------- symmetrize (Z + Z^T)/2 -> packed bf16x2, col-pair-major Mp[k2*256 + t] ----------------
// block = (mtx, k2); thread t = row. dword = bf16(M[t][2k2]) | bf16(M[t][2k2+1])<<16
__global__ __launch_bounds__(256) void symm_bf16(const float* __restrict__ Z1, const float* __restrict__ Z2,
                                                 unsigned* __restrict__ Mp)
{
  int mtx = blockIdx.x >> 7;
  int k2 = blockIdx.x & 127;
  int t = threadIdx.x;
  const float* M = (mtx < 64) ? (Z1 + (size_t)mtx * 65536) : (Z2 + (size_t)(mtx - 64) * 65536);
  int c0 = 2 * k2, c1 = 2 * k2 + 1;
  float2 rowpair = *(const float2*)(M + (size_t)t * 256 + c0);  // M[t][c0], M[t][c1]
  float tr0 = M[(size_t)c0 * 256 + t];                          // M[c0][t]
  float tr1 = M[(size_t)c1 * 256 + t];                          // M[c1][t]
  float m0 = 0.5f * (rowpair.x + tr0);
  float m1 = 0.5f * (rowpair.y + tr1);
  unsigned u = (unsigned)f2bf(m0) | ((unsigned)f2bf(m1) << 16);
  Mp[(size_t)mtx * 32768 + (size_t)k2 * 256 + t] = u;
}

// ---------------- Lanczos (m=LM, fused CGS2, LDS-resident bf16 matrix) + Sturm bisection ----------------
__global__ __launch_bounds__(256) void lanczos_kernel(const unsigned* __restrict__ Mp,
                                                      float* __restrict__ eig)
{
  __shared__ unsigned Mlds[32768];       // 128KB: packed bf16x2, [k2][t]
  __shared__ float V[LM][257];           // Lanczos basis
  __shared__ float vcur[256];            // current v (aligned copy for float4 broadcast)
  __shared__ float wsh[256];
  __shared__ float dred[4][32];
  __shared__ float alpha[LM];
  __shared__ float beta[LM + 1];
  __shared__ float red4[4];

  int t = threadIdx.x;
  int lane = t & 63, wid = t >> 6;
  int mtx = blockIdx.x;

  // fill matrix into LDS (coalesced uint4)
  {
    const uint4* Mg = (const uint4*)(Mp + (size_t)mtx * 32768);
    uint4* Ml4 = (uint4*)Mlds;
    #pragma unroll
    for (int i = 0; i < 32; ++i) Ml4[i * 256 + t] = Mg[i * 256 + t];
  }

  // deterministic start vector
  unsigned u0 = (unsigned)t * 1103515245u + 12345u;
  float r0 = 0.05f + (float)((u0 >> 9) & 0x7FFF) * (1.0f / 32768.0f);
  float nrm2 = blockReduce256(r0 * r0, red4, lane, wid);
  float v0 = r0 * rsqrtf(nrm2);
  V[0][t] = v0; vcur[t] = v0;
  if (t == 0) beta[0] = 0.0f;
  __syncthreads();

  int meff = LM;
  for (int j = 0; j < LM; ++j) {
    // ---- w[t] = sum_k M[t][k] * v[k]  (bf16 matrix in LDS, fp32 accum, w in register) ----
    float wt = 0.f;
    #pragma unroll 8
    for (int q = 0; q < 64; ++q) {
      float4 vq = *(const float4*)&vcur[q * 4];     // broadcast
      unsigned m0 = Mlds[(2 * q) * 256 + t];        // conflict-free (2 lanes/bank)
      unsigned m1 = Mlds[(2 * q + 1) * 256 + t];
      wt = fmaf(__uint_as_float(m0 << 16),         vq.x, wt);
      wt = fmaf(__uint_as_float(m0 & 0xffff0000u), vq.y, wt);
      wt = fmaf(__uint_as_float(m1 << 16),         vq.z, wt);
      wt = fmaf(__uint_as_float(m1 & 0xffff0000u), vq.w, wt);
    }
    // ---- CGS pass 1 (alpha = dot at tt=j, recurrence folded in) ----
    wsh[t] = wt;
    __syncthreads();                                          // B1
    if (lane <= j) {
      const float* Vrow = &V[lane][wid * 64];
      const float* wseg = &wsh[wid * 64];
      float p = 0.f;
      #pragma unroll 8
      for (int k2 = 0; k2 < 64; ++k2) p = fmaf(Vrow[k2], wseg[k2], p);
      dred[wid][lane] = p;
    }
    __syncthreads();                                          // B2
    float a_loc = 0.f, corr = 0.f;
    for (int tt = 0; tt <= j; ++tt) {
      float d = dred[0][tt] + dred[1][tt] + dred[2][tt] + dred[3][tt];
      if (tt == j) a_loc = d;
      corr = fmaf(d, V[tt][t], corr);
    }
    wt -= corr;
    if (t == 0) alpha[j] = a_loc;
    // ---- CGS pass 2 + fused norm (lane j+1 computes ||w||^2 segment) ----
    wsh[t] = wt;
    __syncthreads();                                          // B3
    if (lane <= j + 1) {
      const float* wseg = &wsh[wid * 64];
      float p = 0.f;
      if (lane == j + 1) {
        #pragma unroll 8
        for (int k2 = 0; k2 < 64; ++k2) p = fmaf(wseg[k2], wseg[k2], p);
      } else {
        const float* Vrow = &V[lane][wid * 64];
        #pragma unroll 8
        for (int k2 = 0; k2 < 64; ++k2) p = fmaf(Vrow[k2], wseg[k2], p);
      }
      dred[wid][lane] = p;
    }
    __syncthreads();                                          // B4
    float corr2 = 0.f, d2sum = 0.f;
    for (int tt = 0; tt <= j; ++tt) {
      float d = dred[0][tt] + dred[1][tt] + dred[2][tt] + dred[3][tt];
      corr2 = fmaf(d, V[tt][t], corr2);
      d2sum = fmaf(d, d, d2sum);
    }
    wt -= corr2;
    float nrm_raw = dred[0][j + 1] + dred[1][j + 1] + dred[2][j + 1] + dred[3][j + 1];
    float bn2 = fmaxf(nrm_raw - d2sum, 1e-30f);
    float bn = sqrtf(bn2);
    if (t == 0) beta[j + 1] = bn;
    if (bn < 1e-6f * (fabsf(a_loc) + 1.0f)) { meff = j + 1; break; }
    if (j + 1 < LM) {
      float nv = wt / bn;
      V[j + 1][t] = nv; vcur[t] = nv;
    }
    __syncthreads();                                          // B5
  }
  __syncthreads();

  // ---- Sturm bisection for T eigenvalues idx 1..4 (ascending) ----
  if (t < 4) {
    float lo = 1e30f, hi = -1e30f;
    for (int i = 0; i < meff; ++i) {
      float bl = (i > 0) ? fabsf(beta[i]) : 0.0f;
      float bu = (i + 1 < meff) ? fabsf(beta[i + 1]) : 0.0f;
      lo = fminf(lo, alpha[i] - bl - bu);
      hi = fmaxf(hi, alpha[i] + bl + bu);
    }
    int q = t + 1; if (q > meff - 1) q = meff - 1;
    for (int it = 0; it < 48; ++it) {
      float mid = 0.5f * (lo + hi);
      int cnt = 0;
      float d = alpha[0] - mid;
      if (fabsf(d) < 1e-20f) d = -1e-20f;
      cnt += (d < 0.0f);
      for (int i = 1; i < meff; ++i) {
        d = alpha[i] - mid - beta[i] * beta[i] / d;
        if (fabsf(d) < 1e-20f) d = -1e-20f;
        cnt += (d < 0.0f);
      }
      if (cnt >= q + 1) hi = mid; else lo = mid;
    }
    eig[mtx * 4 + t] = 0.5f * (lo + hi);
  }
}

// ---------------- final combine ----------------
__global__ __launch_bounds__(64) void combine_kernel(const float* __restrict__ eig,
    const double* __restrict__ diffP, const double* __restrict__ offP, const double* __restrict__ trP,
    const float* __restrict__ valo, const float* __restrict__ vali,
    const double* __restrict__ smallp, float* __restrict__ out)
{
  int l = threadIdx.x;
  float vo = valo[l], vi = vali[l];
  float el = 0, el2 = 0;
  #pragma unroll
  for (int e = 0; e < 4; ++e) {
    el  += fabsf(vo - eig[l * 4 + e]);
    el2 += fabsf(vi - eig[(64 + l) * 4 + e]);
  }
  float lo_ = el * 0.25f + 0.2f * (float)(diffP[l] * (1.0/65536.0)) - 0.1f * (float)(offP[l] * (1.0/65536.0));
  float li_ = el2 * 0.25f + 0.2f * (float)(diffP[64 + l] * (1.0/65536.0)) - 0.1f * (float)(offP[64 + l] * (1.0/65536.0));
  if (vo == 0.0f) lo_ = 0.0f;
  if (vi == 0.0f) li_ = 0.0f;
  float trb = (float)((trP[l] + trP[64 + l]) * (1.0/65536.0));
  #pragma unroll
  for (int off = 32; off > 0; off >>= 1) {
    lo_ += __shfl_down(lo_, off);
    li_ += __shfl_down(li_, off);
    trb += __shfl_down(trb, off);
  }
  if (l == 0) {
    out[64] = lo_ * (1.0f / 64.0f);
    out[65] = li_ * (1.0f / 64.0f);
    out[66] = (float)(smallp[0] / (64.0 * 6.0 * 65536.0));
    out[67] = 0.5f * (float)smallp[1] + 0.5f * (trb * (1.0f / 64.0f));
  }
}

extern "C" void kernel_launch(void* const* d_in, const int* in_sizes, int n_in,
                              void* d_out, int out_size, void* d_ws, size_t ws_size,
                              hipStream_t stream) {
  (void)in_sizes; (void)n_in; (void)out_size; (void)ws_size;
  const float* ti       = (const float*)d_in[0];
  const float* seed_ic  = (const float*)d_in[1];
  const float* seed_sir = (const float*)d_in[2];
  const float* seed_icc = (const float*)d_in[3];
  const float* seed_sirc= (const float*)d_in[4];
  const float* scalars  = (const float*)d_in[5];
  const float* valo     = (const float*)d_in[6];
  const float* vali     = (const float*)d_in[7];
  const float* S1p      = (const float*)d_in[8];
  const float* S2p      = (const float*)d_in[9];
  const float* S3p      = (const float*)d_in[10];
  const float* S4p      = (const float*)d_in[11];
  const float* cpA      = (const float*)d_in[12];
  const float* cpB      = (const float*)d_in[13];
  const float* cpC      = (const float*)d_in[14];
  const float* cpW1     = (const float*)d_in[15];
  const float* cpb1     = (const float*)d_in[16];
  const float* cpw2     = (const float*)d_in[17];
  const float* cpb2     = (const float*)d_in[18];
  const float* sW1      = (const float*)d_in[19];
  const float* sb1      = (const float*)d_in[20];
  const float* sw2      = (const float*)d_in[21];
  const float* sb2      = (const float*)d_in[22];
  const float* fW1      = (const float*)d_in[23];
  const float* fb1      = (const float*)d_in[24];
  const float* fw2      = (const float*)d_in[25];
  const float* fb2      = (const float*)d_in[26];

  char* ws = (char*)d_ws;
  float*    tmpA   = (float*)(ws + OFF_TMPA);
  unsigned* Mp     = (unsigned*)(ws + OFF_TMPA);   // reused after GEMMs
  float*    Z1     = (float*)(ws + OFF_Z1);
  float*    Z2     = (float*)(ws + OFF_Z2);
  float*    eig    = (float*)(ws + OFF_EIG);
  double*   diffP  = (double*)(ws + OFF_DIFFP);
  double*   offP   = (double*)(ws + OFF_OFFP);
  double*   trP    = (double*)(ws + OFF_TRP);
  double*   smallp = (double*)(ws + OFF_SMALL);
  float*    out    = (float*)d_out;

  initk<<<1, 1, 0, stream>>>(smallp);

  dim3 gg(4, 4, 64), gb(256);
  const size_t S6 = 6ull * 65536ull, S1b = 65536ull;
  // Z1 = ((ic1 @ S1) @ Z1r) @ S2 @ sir2^T
  gemmk<false,false><<<gg, gb, 0, stream>>>(ti + 0 * 65536, S6, S1p, 0, tmpA);
  gemmk<false,true ><<<gg, gb, 0, stream>>>(tmpA, S1b, ti + 4 * 65536, S6, Z1);
  gemmk<false,false><<<gg, gb, 0, stream>>>(Z1, S1b, S2p, 0, tmpA);
  gemmk<true ,true ><<<gg, gb, 0, stream>>>(tmpA, S1b, ti + 3 * 65536, S6, Z1);
  // Z2 = ((sir1 @ S3) @ Z2r) @ S4 @ ic2^T
  gemmk<false,false><<<gg, gb, 0, stream>>>(ti + 2 * 65536, S6, S3p, 0, tmpA);
  gemmk<false,true ><<<gg, gb, 0, stream>>>(tmpA, S1b, ti + 5 * 65536, S6, Z2);
  gemmk<false,false><<<gg, gb, 0, stream>>>(Z2, S1b, S4p, 0, tmpA);
  gemmk<true ,true ><<<gg, gb, 0, stream>>>(tmpA, S1b, ti + 1 * 65536, S6, Z2);

  reduce_zk<<<128, 256, 0, stream>>>(Z1, Z2, ti, diffP, offP, trP);
  cp_kernel<<<384, 256, 0, stream>>>(ti, Z1, Z2, cpA, cpB, cpC, smallp);
  sreg_kernel<<<16, 256, 0, stream>>>(S1p, S2p, S3p, S4p, smallp);
  head_kernel<<<64, 64, 0, stream>>>(seed_ic, seed_sir, seed_icc, seed_sirc, scalars,
                                     cpA, cpB, cpC, cpW1, cpb1, cpw2, cpb2,
                                     sW1, sb1, sw2, sb2, fW1, fb1, fw2, fb2, out);

  symm_bf16<<<16384, 256, 0, stream>>>(Z1, Z2, Mp);
  lanczos_kernel<<<128, 256, 0, stream>>>(Mp, eig);
  combine_kernel<<<1, 64, 0, stream>>>(eig, diffP, offP, trP, valo, vali, smallp, out);
}

// Round 5
// 586.720 us; speedup vs baseline: 2.3471x; 1.1800x over previous
//
#include <hip/hip_runtime.h>

#define LM 30

// ---------------- ws layout (bytes) ----------------
#define OFF_TMPA  0ull                   // 16MB scratch; reused as packed bf16 Msym (128*32768*4B = 16MB)
#define OFF_Z1    16777216ull
#define OFF_Z2    33554432ull
#define OFF_EIG   50331648ull            // 128*4 floats
#define OFF_DIFFP (OFF_EIG + 4096ull)    // 128 doubles
#define OFF_OFFP  (OFF_DIFFP + 1024ull)  // 128 doubles
#define OFF_TRP   (OFF_OFFP + 1024ull)   // 128 doubles
#define OFF_SMALL (OFF_TRP + 1024ull)    // [0]=cp_sum, [1]=sreg_total

typedef unsigned short ushort_t;

static __device__ __forceinline__ double blockReduceSumD(double v, double* red, int t) {
  red[t] = v; __syncthreads();
  #pragma unroll
  for (int s = 128; s > 0; s >>= 1) { if (t < s) red[t] += red[t + s]; __syncthreads(); }
  double r = red[0]; __syncthreads();
  return r;
}

// shuffle-based 256-thread reduce: 2 syncthreads
static __device__ __forceinline__ float blockReduce256(float v, float* red4, int lane, int wid) {
  #pragma unroll
  for (int off = 32; off > 0; off >>= 1) v += __shfl_down(v, off);
  if (lane == 0) red4[wid] = v;
  __syncthreads();
  float r = red4[0] + red4[1] + red4[2] + red4[3];
  __syncthreads();
  return r;
}

static __device__ __forceinline__ ushort_t f2bf(float f) {
  unsigned u = __float_as_uint(f);
  unsigned r = (u + 0x7fffu + ((u >> 16) & 1u)) >> 16;
  return (ushort_t)r;
}

static __device__ __forceinline__ float bflo(unsigned u) { return __uint_as_float(u << 16); }
static __device__ __forceinline__ float bfhi(unsigned u) { return __uint_as_float(u & 0xffff0000u); }

// ---------------- batched GEMM: C[b] = A[b] @ op(B[b]) (all 256x256 fp32) ----------------
template<bool TRANSB, bool BATB>
__global__ __launch_bounds__(256) void gemmk(const float* __restrict__ A, size_t sA,
                                             const float* __restrict__ B, size_t sB,
                                             float* __restrict__ C)
{
  __shared__ float As[16][68];
  __shared__ float Bs[16][68];
  const int b = blockIdx.z;
  const float* Ab = A + (size_t)b * sA;
  const float* Bb = BATB ? (B + (size_t)b * sB) : B;
  float* Cb = C + (size_t)b * 65536;
  const int tile_m = blockIdx.y * 64, tile_n = blockIdx.x * 64;
  const int tid = threadIdx.x;
  const int tm = tid >> 4, tn = tid & 15;
  float acc[4][4] = {{0.f,0.f,0.f,0.f},{0.f,0.f,0.f,0.f},{0.f,0.f,0.f,0.f},{0.f,0.f,0.f,0.f}};

  for (int k0 = 0; k0 < 256; k0 += 16) {
    {
      int r = tid >> 2, c4 = (tid & 3) << 2;
      float4 av = *(const float4*)(Ab + (size_t)(tile_m + r) * 256 + k0 + c4);
      As[c4 + 0][r] = av.x; As[c4 + 1][r] = av.y; As[c4 + 2][r] = av.z; As[c4 + 3][r] = av.w;
    }
    if (!TRANSB) {
      int r = tid >> 4, c4 = (tid & 15) << 2;
      float4 bv = *(const float4*)(Bb + (size_t)(k0 + r) * 256 + tile_n + c4);
      *(float4*)&Bs[r][c4] = bv;
    } else {
      int r = tid >> 2, c4 = (tid & 3) << 2;
      float4 bv = *(const float4*)(Bb + (size_t)(tile_n + r) * 256 + k0 + c4);
      Bs[c4 + 0][r] = bv.x; Bs[c4 + 1][r] = bv.y; Bs[c4 + 2][r] = bv.z; Bs[c4 + 3][r] = bv.w;
    }
    __syncthreads();
    #pragma unroll
    for (int kk = 0; kk < 16; ++kk) {
      float4 av = *(const float4*)&As[kk][tm << 2];
      float4 bv = *(const float4*)&Bs[kk][tn << 2];
      acc[0][0] += av.x * bv.x; acc[0][1] += av.x * bv.y; acc[0][2] += av.x * bv.z; acc[0][3] += av.x * bv.w;
      acc[1][0] += av.y * bv.x; acc[1][1] += av.y * bv.y; acc[1][2] += av.y * bv.z; acc[1][3] += av.y * bv.w;
      acc[2][0] += av.z * bv.x; acc[2][1] += av.z * bv.y; acc[2][2] += av.z * bv.z; acc[2][3] += av.z * bv.w;
      acc[3][0] += av.w * bv.x; acc[3][1] += av.w * bv.y; acc[3][2] += av.w * bv.z; acc[3][3] += av.w * bv.w;
    }
    __syncthreads();
  }
  #pragma unroll
  for (int q = 0; q < 4; ++q) {
    float4 cv = make_float4(acc[q][0], acc[q][1], acc[q][2], acc[q][3]);
    *(float4*)(Cb + (size_t)(tile_m + (tm << 2) + q) * 256 + tile_n + (tn << 2)) = cv;
  }
}

// ---------------- per-(z,b) reductions: diff, offdiag, transform ----------------
__global__ __launch_bounds__(256) void reduce_zk(const float* __restrict__ Z1, const float* __restrict__ Z2,
                                                 const float* __restrict__ ti,
                                                 double* __restrict__ diffP, double* __restrict__ offP,
                                                 double* __restrict__ trP)
{
  __shared__ double red[256];
  int blk = blockIdx.x, t = threadIdx.x;
  int z = blk >> 6, b = blk & 63;
  const float* M = (z ? Z2 : Z1) + (size_t)b * 65536;
  const float* Mr = ti + ((size_t)b * 6 + (z ? 5 : 4)) * 65536;
  double d = 0, o = 0, tr = 0;
  for (int e = t; e < 65536; e += 256) {
    float a = M[e];
    int i = e >> 8, j = e & 255;
    d += (double)fabsf(a - (i == j ? 1.0f : 0.0f));
    if (i != j) o += (double)fabsf(a);
    tr += (double)fabsf(a - Mr[e]);
  }
  d = blockReduceSumD(d, red, t);
  o = blockReduceSumD(o, red, t);
  tr = blockReduceSumD(tr, red, t);
  if (t == 0) { diffP[blk] = d; offP[blk] = o; trP[blk] = tr; }
}

// ---------------- CP reconstruction loss ----------------
__global__ __launch_bounds__(256) void cp_kernel(const float* __restrict__ ti,
                                                 const float* __restrict__ Z1, const float* __restrict__ Z2,
                                                 const float* __restrict__ cpA, const float* __restrict__ cpB,
                                                 const float* __restrict__ cpC, double* __restrict__ smallp)
{
  __shared__ float Bsh[256][4];
  __shared__ float Csh[256][4];
  __shared__ double red[256];
  int blk = blockIdx.x, t = threadIdx.x;
  int b = blk / 6, i = blk - b * 6;
  const float* T = (i < 4) ? (ti + ((size_t)b * 6 + i) * 65536)
                           : ((i == 4 ? Z1 : Z2) + (size_t)b * 65536);
  *(float4*)&Bsh[t][0] = *(const float4*)(cpB + ((size_t)b * 256 + t) * 4);
  *(float4*)&Csh[t][0] = *(const float4*)(cpC + ((size_t)b * 256 + t) * 4);
  float a0 = cpA[((size_t)b * 6 + i) * 4 + 0];
  float a1 = cpA[((size_t)b * 6 + i) * 4 + 1];
  float a2 = cpA[((size_t)b * 6 + i) * 4 + 2];
  float a3 = cpA[((size_t)b * 6 + i) * 4 + 3];
  __syncthreads();
  float c0 = Csh[t][0], c1 = Csh[t][1], c2 = Csh[t][2], c3 = Csh[t][3];
  double acc = 0;
  for (int j = 0; j < 256; ++j) {
    float recon = a0 * Bsh[j][0] * c0 + a1 * Bsh[j][1] * c1 + a2 * Bsh[j][2] * c2 + a3 * Bsh[j][3] * c3;
    float dv = recon - T[(size_t)j * 256 + t];
    acc += (double)dv * (double)dv;
  }
  acc = blockReduceSumD(acc, red, t);
  if (t == 0) atomicAdd(&smallp[0], acc);
}

// ---------------- S-matrix regularizers (16 blocks) ----------------
__global__ __launch_bounds__(256) void sreg_kernel(const float* __restrict__ S1, const float* __restrict__ S2,
                                                   const float* __restrict__ S3, const float* __restrict__ S4,
                                                   double* __restrict__ smallp)
{
  __shared__ double red[256];
  int t = threadIdx.x, blk = blockIdx.x;
  int s = blk >> 2, part = blk & 3;
  const float* S = (s == 0) ? S1 : (s == 1) ? S2 : (s == 2) ? S3 : S4;
  double tot = 0;
  int e0 = part * 16384;
  for (int e = e0 + t; e < e0 + 16384; e += 256) {
    int i = e >> 8, j = e & 255;
    float a = S[e];
    tot += (double)fabsf(a - (i == j ? 1.0f : 0.0f));
    if (i != j) tot += (double)fabsf(a);
  }
  tot = blockReduceSumD(tot, red, t);
  if (t == 0) atomicAdd(&smallp[1], -tot / 65536.0);
}

__global__ void initk(double* smallp) { smallp[0] = 0.0; smallp[1] = 0.0; }

// ---------------- MLP heads -> logits ----------------
__global__ __launch_bounds__(64) void head_kernel(
    const float* __restrict__ seed_ic, const float* __restrict__ seed_sir,
    const float* __restrict__ seed_icc, const float* __restrict__ seed_sirc,
    const float* __restrict__ scalars,
    const float* __restrict__ cpA, const float* __restrict__ cpB, const float* __restrict__ cpC,
    const float* __restrict__ cpW1, const float* __restrict__ cpb1,
    const float* __restrict__ cpw2, const float* __restrict__ cpb2,
    const float* __restrict__ sW1, const float* __restrict__ sb1,
    const float* __restrict__ sw2, const float* __restrict__ sb2,
    const float* __restrict__ fW1, const float* __restrict__ fb1,
    const float* __restrict__ fw2, const float* __restrict__ fb2,
    float* __restrict__ out)
{
  int b = blockIdx.x, l = threadIdx.x;
  __shared__ float tri[4][3];
  __shared__ float cps[4], seds[4];
  __shared__ float hbuf[128];
  if (l < 4) {
    float s = 0;
    #pragma unroll
    for (int i = 0; i < 6; ++i) s += cpA[((size_t)b * 6 + i) * 4 + l];
    tri[l][0] = s * (1.0f / 6.0f);
  }
  float4 sB = make_float4(0,0,0,0), sC = make_float4(0,0,0,0);
  for (int j = l; j < 256; j += 64) {
    float4 v = *(const float4*)(cpB + ((size_t)b * 256 + j) * 4);
    sB.x += v.x; sB.y += v.y; sB.z += v.z; sB.w += v.w;
    float4 w = *(const float4*)(cpC + ((size_t)b * 256 + j) * 4);
    sC.x += w.x; sC.y += w.y; sC.z += w.z; sC.w += w.w;
  }
  #pragma unroll
  for (int off = 32; off > 0; off >>= 1) {
    sB.x += __shfl_down(sB.x, off); sB.y += __shfl_down(sB.y, off);
    sB.z += __shfl_down(sB.z, off); sB.w += __shfl_down(sB.w, off);
    sC.x += __shfl_down(sC.x, off); sC.y += __shfl_down(sC.y, off);
    sC.z += __shfl_down(sC.z, off); sC.w += __shfl_down(sC.w, off);
  }
  if (l == 0) {
    tri[0][1] = sB.x * (1.0f/256.0f); tri[1][1] = sB.y * (1.0f/256.0f);
    tri[2][1] = sB.z * (1.0f/256.0f); tri[3][1] = sB.w * (1.0f/256.0f);
    tri[0][2] = sC.x * (1.0f/256.0f); tri[1][2] = sC.y * (1.0f/256.0f);
    tri[2][2] = sC.z * (1.0f/256.0f); tri[3][2] = sC.w * (1.0f/256.0f);
  }
  __syncthreads();
  if (l < 4) {
    float s = 0;
    for (int hh = 0; hh < 32; ++hh) {
      float z = cpb1[l * 32 + hh];
      #pragma unroll
      for (int d = 0; d < 3; ++d) z += tri[l][d] * cpW1[(l * 32 + hh) * 3 + d];
      z = fmaxf(z, 0.0f);
      s += z * cpw2[l * 32 + hh];
    }
    cps[l] = s + cpb2[l];
  }
  for (int p = l; p < 128; p += 64) {
    int j = p >> 5, hh = p & 31;
    const float* sv = (j == 0) ? seed_ic : (j == 1) ? seed_sir : (j == 2) ? seed_icc : seed_sirc;
    sv += (size_t)b * 256;
    const float* wrow = sW1 + ((size_t)(j * 32 + hh)) * 256;
    float z = sb1[j * 32 + hh];
    for (int k = 0; k < 256; k += 4) {
      float4 a = *(const float4*)(sv + k);
      float4 w4 = *(const float4*)(wrow + k);
      z += a.x * w4.x + a.y * w4.y + a.z * w4.z + a.w * w4.w;
    }
    z = fmaxf(z, 0.0f);
    hbuf[p] = z * sw2[j * 32 + hh];
  }
  __syncthreads();
  if (l < 4) {
    float s = 0;
    #pragma unroll
    for (int hh = 0; hh < 32; ++hh) s += hbuf[l * 32 + hh];
    seds[l] = s + sb2[l];
  }
  __syncthreads();
  float av = 0.0f;
  if (l < 32) {
    float z = fb1[l];
    #pragma unroll
    for (int d = 0; d < 10; ++d) {
      float cd = (d < 4) ? cps[d] : (d < 8) ? seds[d - 4] : scalars[b * 2 + (d - 8)];
      z += cd * fW1[l * 10 + d];
    }
    z = fmaxf(z, 0.0f);
    av = z * fw2[l];
  }
  #pragma unroll
  for (int off = 16; off > 0; off >>= 1) av += __shfl_down(av, off);
  if (l == 0) out[b] = av + fb2[0];
}

// ---------------- symmetrize (Z + Z^T)/2 -> packed bf16x2, col-pair-major Mp[k2*256 + t] ----------------
// block = (mtx, k2); thread t = row. dword = bf16(M[t][2k2]) | bf16(M[t][2k2+1])<<16
__global__ __launch_bounds__(256) void symm_bf16(const float* __restrict__ Z1, const float* __restrict__ Z2,
                                                 unsigned* __restrict__ Mp)
{
  int mtx = blockIdx.x >> 7;
  int k2 = blockIdx.x & 127;
  int t = threadIdx.x;
  const float* M = (mtx < 64) ? (Z1 + (size_t)mtx * 65536) : (Z2 + (size_t)(mtx - 64) * 65536);
  int c0 = 2 * k2, c1 = 2 * k2 + 1;
  float2 rowpair = *(const float2*)(M + (size_t)t * 256 + c0);  // M[t][c0], M[t][c1]
  float tr0 = M[(size_t)c0 * 256 + t];                          // M[c0][t]
  float tr1 = M[(size_t)c1 * 256 + t];                          // M[c1][t]
  float m0 = 0.5f * (rowpair.x + tr0);
  float m1 = 0.5f * (rowpair.y + tr1);
  unsigned u = (unsigned)f2bf(m0) | ((unsigned)f2bf(m1) << 16);
  Mp[(size_t)mtx * 32768 + (size_t)k2 * 256 + t] = u;
}

// ---------------- Lanczos (plain 3-term, m=LM, bf16 matrix+vector, swizzled LDS) + Sturm bisection ----------------
__global__ __launch_bounds__(256) void lanczos_kernel(const unsigned* __restrict__ Mp,
                                                      float* __restrict__ eig)
{
  __shared__ unsigned Mlds[32768];   // 128KB: swizzled row-major packed bf16x2
  __shared__ unsigned vpack[128];    // current v, packed bf16x2
  __shared__ float red[4][4];        // [wave][S1,S2,S3]
  __shared__ float alpha[LM];
  __shared__ float beta[LM + 1];
  __shared__ float red4[4];

  int t = threadIdx.x;
  int lane = t & 63, wid = t >> 6;
  int mtx = blockIdx.x;

  // ---- fill: global [k2][row] -> LDS swizzled row-major [row][slot^(row&31)] ----
  // global uint4 m = it*256+t holds dwords (k2 = 4*it + (t>>6), rows 4*(t&63)..+3)
  {
    const uint4* Mg4 = (const uint4*)(Mp + (size_t)mtx * 32768);
    #pragma unroll 4
    for (int it = 0; it < 32; ++it) {
      uint4 g = Mg4[it * 256 + t];
      int rb = (t & 63) << 2;
      int c = t >> 6;
      int r0 = rb + 0, r1 = rb + 1, r2 = rb + 2, r3 = rb + 3;
      Mlds[r0 * 128 + ((it ^ (r0 & 31)) << 2) + c] = g.x;
      Mlds[r1 * 128 + ((it ^ (r1 & 31)) << 2) + c] = g.y;
      Mlds[r2 * 128 + ((it ^ (r2 & 31)) << 2) + c] = g.z;
      Mlds[r3 * 128 + ((it ^ (r3 & 31)) << 2) + c] = g.w;
    }
  }

  // ---- deterministic start vector ----
  unsigned u0 = (unsigned)t * 1103515245u + 12345u;
  float r0v = 0.05f + (float)((u0 >> 9) & 0x7FFF) * (1.0f / 32768.0f);
  float nrm2 = blockReduce256(r0v * r0v, red4, lane, wid);
  float vt = r0v * rsqrtf(nrm2);
  float vprev = 0.0f;
  {
    float vo = __shfl_down(vt, 1);
    if ((lane & 1) == 0) vpack[t >> 1] = (unsigned)f2bf(vt) | ((unsigned)f2bf(vo) << 16);
    if (t == 0) beta[0] = 0.0f;
  }
  __syncthreads();

  const unsigned* Mrow = Mlds + t * 128;
  const int rx = t & 31;

  int meff = LM;
  for (int j = 0; j < LM; ++j) {
    // ---- w[t] = sum_k M[t][k] * v[k] : 32x (1 matrix b128 + 1 broadcast v b128) ----
    float wt = 0.f;
    #pragma unroll 8
    for (int q = 0; q < 32; ++q) {
      uint4 mu = *(const uint4*)(Mrow + ((q ^ rx) << 2));
      uint4 vu = *(const uint4*)(vpack + (q << 2));
      wt = fmaf(bflo(mu.x), bflo(vu.x), wt);
      wt = fmaf(bfhi(mu.x), bfhi(vu.x), wt);
      wt = fmaf(bflo(mu.y), bflo(vu.y), wt);
      wt = fmaf(bfhi(mu.y), bfhi(vu.y), wt);
      wt = fmaf(bflo(mu.z), bflo(vu.z), wt);
      wt = fmaf(bfhi(mu.z), bfhi(vu.z), wt);
      wt = fmaf(bflo(mu.w), bflo(vu.w), wt);
      wt = fmaf(bfhi(mu.w), bfhi(vu.w), wt);
    }
    // ---- fused 3-dot reduce: S1=<w,v> S2=<w,vprev> S3=<w,w> ----
    float s1 = wt * vt, s2 = wt * vprev, s3 = wt * wt;
    #pragma unroll
    for (int off = 32; off > 0; off >>= 1) {
      s1 += __shfl_down(s1, off);
      s2 += __shfl_down(s2, off);
      s3 += __shfl_down(s3, off);
    }
    if (lane == 0) { red[wid][0] = s1; red[wid][1] = s2; red[wid][2] = s3; }
    __syncthreads();                                           // B1
    float S1 = red[0][0] + red[1][0] + red[2][0] + red[3][0];
    float S2 = red[0][1] + red[1][1] + red[2][1] + red[3][1];
    float S3 = red[0][2] + red[1][2] + red[2][2] + red[3][2];
    float bn2 = S3 - S1 * S1 - S2 * S2;
    float bn = sqrtf(fmaxf(bn2, 1e-30f));
    if (t == 0) { alpha[j] = S1; beta[j + 1] = bn; }
    if (bn < 1e-6f * (fabsf(S1) + 1.0f)) { meff = j + 1; break; }
    float wn = (wt - S1 * vt - S2 * vprev) / bn;
    vprev = vt; vt = wn;
    float vo = __shfl_down(vt, 1);
    if ((lane & 1) == 0) vpack[t >> 1] = (unsigned)f2bf(vt) | ((unsigned)f2bf(vo) << 16);
    __syncthreads();                                           // B2
  }
  __syncthreads();

  // ---- Sturm bisection for T eigenvalues idx 1..4 (ascending) ----
  if (t < 4) {
    float lo = 1e30f, hi = -1e30f;
    for (int i = 0; i < meff; ++i) {
      float bl = (i > 0) ? fabsf(beta[i]) : 0.0f;
      float bu = (i + 1 < meff) ? fabsf(beta[i + 1]) : 0.0f;
      lo = fminf(lo, alpha[i] - bl - bu);
      hi = fmaxf(hi, alpha[i] + bl + bu);
    }
    int q = t + 1; if (q > meff - 1) q = meff - 1;
    for (int it = 0; it < 32; ++it) {
      float mid = 0.5f * (lo + hi);
      int cnt = 0;
      float d = alpha[0] - mid;
      if (fabsf(d) < 1e-20f) d = -1e-20f;
      cnt += (d < 0.0f);
      for (int i = 1; i < meff; ++i) {
        d = alpha[i] - mid - beta[i] * beta[i] / d;
        if (fabsf(d) < 1e-20f) d = -1e-20f;
        cnt += (d < 0.0f);
      }
      if (cnt >= q + 1) hi = mid; else lo = mid;
    }
    eig[mtx * 4 + t] = 0.5f * (lo + hi);
  }
}

// ---------------- final combine ----------------
__global__ __launch_bounds__(64) void combine_kernel(const float* __restrict__ eig,
    const double* __restrict__ diffP, const double* __restrict__ offP, const double* __restrict__ trP,
    const float* __restrict__ valo, const float* __restrict__ vali,
    const double* __restrict__ smallp, float* __restrict__ out)
{
  int l = threadIdx.x;
  float vo = valo[l], vi = vali[l];
  float el = 0, el2 = 0;
  #pragma unroll
  for (int e = 0; e < 4; ++e) {
    el  += fabsf(vo - eig[l * 4 + e]);
    el2 += fabsf(vi - eig[(64 + l) * 4 + e]);
  }
  float lo_ = el * 0.25f + 0.2f * (float)(diffP[l] * (1.0/65536.0)) - 0.1f * (float)(offP[l] * (1.0/65536.0));
  float li_ = el2 * 0.25f + 0.2f * (float)(diffP[64 + l] * (1.0/65536.0)) - 0.1f * (float)(offP[64 + l] * (1.0/65536.0));
  if (vo == 0.0f) lo_ = 0.0f;
  if (vi == 0.0f) li_ = 0.0f;
  float trb = (float)((trP[l] + trP[64 + l]) * (1.0/65536.0));
  #pragma unroll
  for (int off = 32; off > 0; off >>= 1) {
    lo_ += __shfl_down(lo_, off);
    li_ += __shfl_down(li_, off);
    trb += __shfl_down(trb, off);
  }
  if (l == 0) {
    out[64] = lo_ * (1.0f / 64.0f);
    out[65] = li_ * (1.0f / 64.0f);
    out[66] = (float)(smallp[0] / (64.0 * 6.0 * 65536.0));
    out[67] = 0.5f * (float)smallp[1] + 0.5f * (trb * (1.0f / 64.0f));
  }
}

extern "C" void kernel_launch(void* const* d_in, const int* in_sizes, int n_in,
                              void* d_out, int out_size, void* d_ws, size_t ws_size,
                              hipStream_t stream) {
  (void)in_sizes; (void)n_in; (void)out_size; (void)ws_size;
  const float* ti       = (const float*)d_in[0];
  const float* seed_ic  = (const float*)d_in[1];
  const float* seed_sir = (const float*)d_in[2];
  const float* seed_icc = (const float*)d_in[3];
  const float* seed_sirc= (const float*)d_in[4];
  const float* scalars  = (const float*)d_in[5];
  const float* valo     = (const float*)d_in[6];
  const float* vali     = (const float*)d_in[7];
  const float* S1p      = (const float*)d_in[8];
  const float* S2p      = (const float*)d_in[9];
  const float* S3p      = (const float*)d_in[10];
  const float* S4p      = (const float*)d_in[11];
  const float* cpA      = (const float*)d_in[12];
  const float* cpB      = (const float*)d_in[13];
  const float* cpC      = (const float*)d_in[14];
  const float* cpW1     = (const float*)d_in[15];
  const float* cpb1     = (const float*)d_in[16];
  const float* cpw2     = (const float*)d_in[17];
  const float* cpb2     = (const float*)d_in[18];
  const float* sW1      = (const float*)d_in[19];
  const float* sb1      = (const float*)d_in[20];
  const float* sw2      = (const float*)d_in[21];
  const float* sb2      = (const float*)d_in[22];
  const float* fW1      = (const float*)d_in[23];
  const float* fb1      = (const float*)d_in[24];
  const float* fw2      = (const float*)d_in[25];
  const float* fb2      = (const float*)d_in[26];

  char* ws = (char*)d_ws;
  float*    tmpA   = (float*)(ws + OFF_TMPA);
  unsigned* Mp     = (unsigned*)(ws + OFF_TMPA);   // reused after GEMMs
  float*    Z1     = (float*)(ws + OFF_Z1);
  float*    Z2     = (float*)(ws + OFF_Z2);
  float*    eig    = (float*)(ws + OFF_EIG);
  double*   diffP  = (double*)(ws + OFF_DIFFP);
  double*   offP   = (double*)(ws + OFF_OFFP);
  double*   trP    = (double*)(ws + OFF_TRP);
  double*   smallp = (double*)(ws + OFF_SMALL);
  float*    out    = (float*)d_out;

  initk<<<1, 1, 0, stream>>>(smallp);

  dim3 gg(4, 4, 64), gb(256);
  const size_t S6 = 6ull * 65536ull, S1b = 65536ull;
  // Z1 = ((ic1 @ S1) @ Z1r) @ S2 @ sir2^T
  gemmk<false,false><<<gg, gb, 0, stream>>>(ti + 0 * 65536, S6, S1p, 0, tmpA);
  gemmk<false,true ><<<gg, gb, 0, stream>>>(tmpA, S1b, ti + 4 * 65536, S6, Z1);
  gemmk<false,false><<<gg, gb, 0, stream>>>(Z1, S1b, S2p, 0, tmpA);
  gemmk<true ,true ><<<gg, gb, 0, stream>>>(tmpA, S1b, ti + 3 * 65536, S6, Z1);
  // Z2 = ((sir1 @ S3) @ Z2r) @ S4 @ ic2^T
  gemmk<false,false><<<gg, gb, 0, stream>>>(ti + 2 * 65536, S6, S3p, 0, tmpA);
  gemmk<false,true ><<<gg, gb, 0, stream>>>(tmpA, S1b, ti + 5 * 65536, S6, Z2);
  gemmk<false,false><<<gg, gb, 0, stream>>>(Z2, S1b, S4p, 0, tmpA);
  gemmk<true ,true ><<<gg, gb, 0, stream>>>(tmpA, S1b, ti + 1 * 65536, S6, Z2);

  reduce_zk<<<128, 256, 0, stream>>>(Z1, Z2, ti, diffP, offP, trP);
  cp_kernel<<<384, 256, 0, stream>>>(ti, Z1, Z2, cpA, cpB, cpC, smallp);
  sreg_kernel<<<16, 256, 0, stream>>>(S1p, S2p, S3p, S4p, smallp);
  head_kernel<<<64, 64, 0, stream>>>(seed_ic, seed_sir, seed_icc, seed_sirc, scalars,
                                     cpA, cpB, cpC, cpW1, cpb1, cpw2, cpb2,
                                     sW1, sb1, sw2, sb2, fW1, fb1, fw2, fb2, out);

  symm_bf16<<<16384, 256, 0, stream>>>(Z1, Z2, Mp);
  lanczos_kernel<<<128, 256, 0, stream>>>(Mp, eig);
  combine_kernel<<<1, 64, 0, stream>>>(eig, diffP, offP, trP, valo, vali, smallp, out);
}

// Round 6
// 369.152 us; speedup vs baseline: 3.7303x; 1.5894x over previous
//
#include <hip/hip_runtime.h>

#define LM 30

// ---------------- ws layout (bytes) ----------------
#define OFF_R0    0ull                   // Z1rT bf16 (8MB); later chain2 temps; later Mp (16MB with R1)
#define OFF_R1    8388608ull             // Z2rT bf16 (8MB)
#define OFF_Z1    16777216ull            // Z1 fp32 (16MB)
#define OFF_Z2    33554432ull            // Z2 fp32 (16MB); first Pa/Pb bf16 temps
#define OFF_PA    33554432ull            // Pa bf16 (8MB)
#define OFF_PB    41943040ull            // Pb bf16 (8MB)
#define OFF_MP    0ull                   // packed bf16 sym matrices (16MB, after gemms)
#define OFF_EIG   50331648ull            // 128*4 floats
#define OFF_DIFFP (OFF_EIG + 4096ull)
#define OFF_OFFP  (OFF_DIFFP + 1024ull)
#define OFF_TRP   (OFF_OFFP + 1024ull)
#define OFF_SMALL (OFF_TRP + 1024ull)
#define OFF_ST    (OFF_SMALL + 4096ull)  // S1T..S4T bf16, 4 * 131072B

typedef unsigned short ushort_t;
typedef short bf16x8 __attribute__((ext_vector_type(8)));
typedef float f32x4 __attribute__((ext_vector_type(4)));

static __device__ __forceinline__ double blockReduceSumD(double v, double* red, int t) {
  red[t] = v; __syncthreads();
  #pragma unroll
  for (int s = 128; s > 0; s >>= 1) { if (t < s) red[t] += red[t + s]; __syncthreads(); }
  double r = red[0]; __syncthreads();
  return r;
}

static __device__ __forceinline__ float blockReduce256(float v, float* red4, int lane, int wid) {
  #pragma unroll
  for (int off = 32; off > 0; off >>= 1) v += __shfl_down(v, off);
  if (lane == 0) red4[wid] = v;
  __syncthreads();
  float r = red4[0] + red4[1] + red4[2] + red4[3];
  __syncthreads();
  return r;
}

static __device__ __forceinline__ ushort_t f2bf(float f) {
  unsigned u = __float_as_uint(f);
  unsigned r = (u + 0x7fffu + ((u >> 16) & 1u)) >> 16;
  return (ushort_t)r;
}

static __device__ __forceinline__ float bflo(unsigned u) { return __uint_as_float(u << 16); }
static __device__ __forceinline__ float bfhi(unsigned u) { return __uint_as_float(u & 0xffff0000u); }

// ---------------- transpose-convert: fp32 [R][C] -> bf16 [C][R] ----------------
__global__ __launch_bounds__(256) void tconv_s(const float* __restrict__ S1, const float* __restrict__ S2,
                                               const float* __restrict__ S3, const float* __restrict__ S4,
                                               ushort_t* __restrict__ dst)
{
  __shared__ float tl[32][33];
  int z = blockIdx.z;
  const float* S = (z == 0) ? S1 : (z == 1) ? S2 : (z == 2) ? S3 : S4;
  int r0 = blockIdx.y * 32, c0 = blockIdx.x * 32;
  int tx = threadIdx.x & 31, ty = threadIdx.x >> 5;
  #pragma unroll
  for (int k = 0; k < 4; ++k) tl[ty + 8 * k][tx] = S[(size_t)(r0 + ty + 8 * k) * 256 + c0 + tx];
  __syncthreads();
  ushort_t* d = dst + (size_t)z * 65536;
  #pragma unroll
  for (int k = 0; k < 4; ++k) d[(size_t)(c0 + ty + 8 * k) * 256 + r0 + tx] = f2bf(tl[tx][ty + 8 * k]);
}

__global__ __launch_bounds__(256) void tconv_z(const float* __restrict__ ti,
                                               ushort_t* __restrict__ d0, ushort_t* __restrict__ d1)
{
  __shared__ float tl[32][33];
  int z = blockIdx.z;
  int which = z >> 6, b = z & 63;
  const float* S = ti + ((size_t)b * 6 + 4 + which) * 65536;
  ushort_t* d = (which ? d1 : d0) + (size_t)b * 65536;
  int r0 = blockIdx.y * 32, c0 = blockIdx.x * 32;
  int tx = threadIdx.x & 31, ty = threadIdx.x >> 5;
  #pragma unroll
  for (int k = 0; k < 4; ++k) tl[ty + 8 * k][tx] = S[(size_t)(r0 + ty + 8 * k) * 256 + c0 + tx];
  __syncthreads();
  #pragma unroll
  for (int k = 0; k < 4; ++k) d[(size_t)(c0 + ty + 8 * k) * 256 + r0 + tx] = f2bf(tl[tx][ty + 8 * k]);
}

// ---------------- MFMA GEMM: C[b] = A[b] (256xK) * Bstored[b]^T (Bstored is [N][K]) ----------------
template<bool ABF, bool BBF, bool CBF>
__global__ __launch_bounds__(256) void gemm_mfma(const void* __restrict__ Abase, size_t sA,
                                                 const void* __restrict__ Bbase, size_t sB,
                                                 void* __restrict__ Cbase, size_t sC)
{
  __shared__ ushort_t At[64][40];
  __shared__ ushort_t Bt[64][40];
  const int t = threadIdx.x;
  const int b = blockIdx.z;
  const int tm = blockIdx.y * 64, tn = blockIdx.x * 64;
  const int w = t >> 6, l = t & 63;
  const int srow = t >> 2, scg = (t & 3) << 3;
  const int arow = (w << 4) + (l & 15);
  const int kc = (l >> 4) << 3;
  const int brow0 = l & 15;

  f32x4 acc0 = {0.f,0.f,0.f,0.f}, acc1 = {0.f,0.f,0.f,0.f}, acc2 = {0.f,0.f,0.f,0.f}, acc3 = {0.f,0.f,0.f,0.f};

  for (int s8 = 0; s8 < 8; ++s8) {
    const int k0 = s8 << 5;
    if (ABF) {
      const ushort_t* Ap = (const ushort_t*)Abase + (size_t)b * sA + (size_t)(tm + srow) * 256 + k0 + scg;
      *(uint4*)&At[srow][scg] = *(const uint4*)Ap;
    } else {
      const float* Ap = (const float*)Abase + (size_t)b * sA + (size_t)(tm + srow) * 256 + k0 + scg;
      float4 f0 = *(const float4*)Ap, f1 = *(const float4*)(Ap + 4);
      uint4 u;
      u.x = (unsigned)f2bf(f0.x) | ((unsigned)f2bf(f0.y) << 16);
      u.y = (unsigned)f2bf(f0.z) | ((unsigned)f2bf(f0.w) << 16);
      u.z = (unsigned)f2bf(f1.x) | ((unsigned)f2bf(f1.y) << 16);
      u.w = (unsigned)f2bf(f1.z) | ((unsigned)f2bf(f1.w) << 16);
      *(uint4*)&At[srow][scg] = u;
    }
    if (BBF) {
      const ushort_t* Bp = (const ushort_t*)Bbase + (size_t)b * sB + (size_t)(tn + srow) * 256 + k0 + scg;
      *(uint4*)&Bt[srow][scg] = *(const uint4*)Bp;
    } else {
      const float* Bp = (const float*)Bbase + (size_t)b * sB + (size_t)(tn + srow) * 256 + k0 + scg;
      float4 f0 = *(const float4*)Bp, f1 = *(const float4*)(Bp + 4);
      uint4 u;
      u.x = (unsigned)f2bf(f0.x) | ((unsigned)f2bf(f0.y) << 16);
      u.y = (unsigned)f2bf(f0.z) | ((unsigned)f2bf(f0.w) << 16);
      u.z = (unsigned)f2bf(f1.x) | ((unsigned)f2bf(f1.y) << 16);
      u.w = (unsigned)f2bf(f1.z) | ((unsigned)f2bf(f1.w) << 16);
      *(uint4*)&Bt[srow][scg] = u;
    }
    __syncthreads();
    bf16x8 av  = *(const bf16x8*)&At[arow][kc];
    bf16x8 bv0 = *(const bf16x8*)&Bt[ 0 + brow0][kc];
    bf16x8 bv1 = *(const bf16x8*)&Bt[16 + brow0][kc];
    bf16x8 bv2 = *(const bf16x8*)&Bt[32 + brow0][kc];
    bf16x8 bv3 = *(const bf16x8*)&Bt[48 + brow0][kc];
    acc0 = __builtin_amdgcn_mfma_f32_16x16x32_bf16(av, bv0, acc0, 0, 0, 0);
    acc1 = __builtin_amdgcn_mfma_f32_16x16x32_bf16(av, bv1, acc1, 0, 0, 0);
    acc2 = __builtin_amdgcn_mfma_f32_16x16x32_bf16(av, bv2, acc2, 0, 0, 0);
    acc3 = __builtin_amdgcn_mfma_f32_16x16x32_bf16(av, bv3, acc3, 0, 0, 0);
    __syncthreads();
  }

  const int m0 = tm + (w << 4) + ((l >> 4) << 2);
  if (CBF) {
    ushort_t* Cp = (ushort_t*)Cbase + (size_t)b * sC;
    #pragma unroll
    for (int q = 0; q < 4; ++q) {
      size_t r = (size_t)(m0 + q) * 256;
      Cp[r + tn +  0 + brow0] = f2bf(acc0[q]);
      Cp[r + tn + 16 + brow0] = f2bf(acc1[q]);
      Cp[r + tn + 32 + brow0] = f2bf(acc2[q]);
      Cp[r + tn + 48 + brow0] = f2bf(acc3[q]);
    }
  } else {
    float* Cp = (float*)Cbase + (size_t)b * sC;
    #pragma unroll
    for (int q = 0; q < 4; ++q) {
      size_t r = (size_t)(m0 + q) * 256;
      Cp[r + tn +  0 + brow0] = acc0[q];
      Cp[r + tn + 16 + brow0] = acc1[q];
      Cp[r + tn + 32 + brow0] = acc2[q];
      Cp[r + tn + 48 + brow0] = acc3[q];
    }
  }
}

// ---------------- per-(z,b) reductions: diff, offdiag, transform ----------------
__global__ __launch_bounds__(256) void reduce_zk(const float* __restrict__ Z1, const float* __restrict__ Z2,
                                                 const float* __restrict__ ti,
                                                 double* __restrict__ diffP, double* __restrict__ offP,
                                                 double* __restrict__ trP)
{
  __shared__ double red[256];
  int blk = blockIdx.x, t = threadIdx.x;
  int z = blk >> 6, b = blk & 63;
  const float* M = (z ? Z2 : Z1) + (size_t)b * 65536;
  const float* Mr = ti + ((size_t)b * 6 + (z ? 5 : 4)) * 65536;
  double d = 0, o = 0, tr = 0;
  for (int e = t; e < 65536; e += 256) {
    float a = M[e];
    int i = e >> 8, j = e & 255;
    d += (double)fabsf(a - (i == j ? 1.0f : 0.0f));
    if (i != j) o += (double)fabsf(a);
    tr += (double)fabsf(a - Mr[e]);
  }
  d = blockReduceSumD(d, red, t);
  o = blockReduceSumD(o, red, t);
  tr = blockReduceSumD(tr, red, t);
  if (t == 0) { diffP[blk] = d; offP[blk] = o; trP[blk] = tr; }
}

// ---------------- CP reconstruction loss ----------------
__global__ __launch_bounds__(256) void cp_kernel(const float* __restrict__ ti,
                                                 const float* __restrict__ Z1, const float* __restrict__ Z2,
                                                 const float* __restrict__ cpA, const float* __restrict__ cpB,
                                                 const float* __restrict__ cpC, double* __restrict__ smallp)
{
  __shared__ float Bsh[256][4];
  __shared__ float Csh[256][4];
  __shared__ double red[256];
  int blk = blockIdx.x, t = threadIdx.x;
  int b = blk / 6, i = blk - b * 6;
  const float* T = (i < 4) ? (ti + ((size_t)b * 6 + i) * 65536)
                           : ((i == 4 ? Z1 : Z2) + (size_t)b * 65536);
  *(float4*)&Bsh[t][0] = *(const float4*)(cpB + ((size_t)b * 256 + t) * 4);
  *(float4*)&Csh[t][0] = *(const float4*)(cpC + ((size_t)b * 256 + t) * 4);
  float a0 = cpA[((size_t)b * 6 + i) * 4 + 0];
  float a1 = cpA[((size_t)b * 6 + i) * 4 + 1];
  float a2 = cpA[((size_t)b * 6 + i) * 4 + 2];
  float a3 = cpA[((size_t)b * 6 + i) * 4 + 3];
  __syncthreads();
  float c0 = Csh[t][0], c1 = Csh[t][1], c2 = Csh[t][2], c3 = Csh[t][3];
  double acc = 0;
  for (int j = 0; j < 256; ++j) {
    float recon = a0 * Bsh[j][0] * c0 + a1 * Bsh[j][1] * c1 + a2 * Bsh[j][2] * c2 + a3 * Bsh[j][3] * c3;
    float dv = recon - T[(size_t)j * 256 + t];
    acc += (double)dv * (double)dv;
  }
  acc = blockReduceSumD(acc, red, t);
  if (t == 0) atomicAdd(&smallp[0], acc);
}

// ---------------- S-matrix regularizers (16 blocks) ----------------
__global__ __launch_bounds__(256) void sreg_kernel(const float* __restrict__ S1, const float* __restrict__ S2,
                                                   const float* __restrict__ S3, const float* __restrict__ S4,
                                                   double* __restrict__ smallp)
{
  __shared__ double red[256];
  int t = threadIdx.x, blk = blockIdx.x;
  int s = blk >> 2, part = blk & 3;
  const float* S = (s == 0) ? S1 : (s == 1) ? S2 : (s == 2) ? S3 : S4;
  double tot = 0;
  int e0 = part * 16384;
  for (int e = e0 + t; e < e0 + 16384; e += 256) {
    int i = e >> 8, j = e & 255;
    float a = S[e];
    tot += (double)fabsf(a - (i == j ? 1.0f : 0.0f));
    if (i != j) tot += (double)fabsf(a);
  }
  tot = blockReduceSumD(tot, red, t);
  if (t == 0) atomicAdd(&smallp[1], -tot / 65536.0);
}

__global__ void initk(double* smallp) { smallp[0] = 0.0; smallp[1] = 0.0; }

// ---------------- MLP heads -> logits ----------------
__global__ __launch_bounds__(64) void head_kernel(
    const float* __restrict__ seed_ic, const float* __restrict__ seed_sir,
    const float* __restrict__ seed_icc, const float* __restrict__ seed_sirc,
    const float* __restrict__ scalars,
    const float* __restrict__ cpA, const float* __restrict__ cpB, const float* __restrict__ cpC,
    const float* __restrict__ cpW1, const float* __restrict__ cpb1,
    const float* __restrict__ cpw2, const float* __restrict__ cpb2,
    const float* __restrict__ sW1, const float* __restrict__ sb1,
    const float* __restrict__ sw2, const float* __restrict__ sb2,
    const float* __restrict__ fW1, const float* __restrict__ fb1,
    const float* __restrict__ fw2, const float* __restrict__ fb2,
    float* __restrict__ out)
{
  int b = blockIdx.x, l = threadIdx.x;
  __shared__ float tri[4][3];
  __shared__ float cps[4], seds[4];
  __shared__ float hbuf[128];
  if (l < 4) {
    float s = 0;
    #pragma unroll
    for (int i = 0; i < 6; ++i) s += cpA[((size_t)b * 6 + i) * 4 + l];
    tri[l][0] = s * (1.0f / 6.0f);
  }
  float4 sB = make_float4(0,0,0,0), sC = make_float4(0,0,0,0);
  for (int j = l; j < 256; j += 64) {
    float4 v = *(const float4*)(cpB + ((size_t)b * 256 + j) * 4);
    sB.x += v.x; sB.y += v.y; sB.z += v.z; sB.w += v.w;
    float4 w = *(const float4*)(cpC + ((size_t)b * 256 + j) * 4);
    sC.x += w.x; sC.y += w.y; sC.z += w.z; sC.w += w.w;
  }
  #pragma unroll
  for (int off = 32; off > 0; off >>= 1) {
    sB.x += __shfl_down(sB.x, off); sB.y += __shfl_down(sB.y, off);
    sB.z += __shfl_down(sB.z, off); sB.w += __shfl_down(sB.w, off);
    sC.x += __shfl_down(sC.x, off); sC.y += __shfl_down(sC.y, off);
    sC.z += __shfl_down(sC.z, off); sC.w += __shfl_down(sC.w, off);
  }
  if (l == 0) {
    tri[0][1] = sB.x * (1.0f/256.0f); tri[1][1] = sB.y * (1.0f/256.0f);
    tri[2][1] = sB.z * (1.0f/256.0f); tri[3][1] = sB.w * (1.0f/256.0f);
    tri[0][2] = sC.x * (1.0f/256.0f); tri[1][2] = sC.y * (1.0f/256.0f);
    tri[2][2] = sC.z * (1.0f/256.0f); tri[3][2] = sC.w * (1.0f/256.0f);
  }
  __syncthreads();
  if (l < 4) {
    float s = 0;
    for (int hh = 0; hh < 32; ++hh) {
      float z = cpb1[l * 32 + hh];
      #pragma unroll
      for (int d = 0; d < 3; ++d) z += tri[l][d] * cpW1[(l * 32 + hh) * 3 + d];
      z = fmaxf(z, 0.0f);
      s += z * cpw2[l * 32 + hh];
    }
    cps[l] = s + cpb2[l];
  }
  for (int p = l; p < 128; p += 64) {
    int j = p >> 5, hh = p & 31;
    const float* sv = (j == 0) ? seed_ic : (j == 1) ? seed_sir : (j == 2) ? seed_icc : seed_sirc;
    sv += (size_t)b * 256;
    const float* wrow = sW1 + ((size_t)(j * 32 + hh)) * 256;
    float z = sb1[j * 32 + hh];
    for (int k = 0; k < 256; k += 4) {
      float4 a = *(const float4*)(sv + k);
      float4 w4 = *(const float4*)(wrow + k);
      z += a.x * w4.x + a.y * w4.y + a.z * w4.z + a.w * w4.w;
    }
    z = fmaxf(z, 0.0f);
    hbuf[p] = z * sw2[j * 32 + hh];
  }
  __syncthreads();
  if (l < 4) {
    float s = 0;
    #pragma unroll
    for (int hh = 0; hh < 32; ++hh) s += hbuf[l * 32 + hh];
    seds[l] = s + sb2[l];
  }
  __syncthreads();
  float av = 0.0f;
  if (l < 32) {
    float z = fb1[l];
    #pragma unroll
    for (int d = 0; d < 10; ++d) {
      float cd = (d < 4) ? cps[d] : (d < 8) ? seds[d - 4] : scalars[b * 2 + (d - 8)];
      z += cd * fW1[l * 10 + d];
    }
    z = fmaxf(z, 0.0f);
    av = z * fw2[l];
  }
  #pragma unroll
  for (int off = 16; off > 0; off >>= 1) av += __shfl_down(av, off);
  if (l == 0) out[b] = av + fb2[0];
}

// ---------------- symmetrize (Z + Z^T)/2 -> packed bf16x2, Mp[mtx][k2*256 + row] ----------------
__global__ __launch_bounds__(256) void symm_bf16(const float* __restrict__ Z1, const float* __restrict__ Z2,
                                                 unsigned* __restrict__ Mp)
{
  int mtx = blockIdx.x >> 7;
  int k2 = blockIdx.x & 127;
  int t = threadIdx.x;
  const float* M = (mtx < 64) ? (Z1 + (size_t)mtx * 65536) : (Z2 + (size_t)(mtx - 64) * 65536);
  int c0 = 2 * k2, c1 = 2 * k2 + 1;
  float2 rowpair = *(const float2*)(M + (size_t)t * 256 + c0);
  float tr0 = M[(size_t)c0 * 256 + t];
  float tr1 = M[(size_t)c1 * 256 + t];
  float m0 = 0.5f * (rowpair.x + tr0);
  float m1 = 0.5f * (rowpair.y + tr1);
  unsigned u = (unsigned)f2bf(m0) | ((unsigned)f2bf(m1) << 16);
  Mp[(size_t)mtx * 32768 + (size_t)k2 * 256 + t] = u;
}

// ---------------- Lanczos (3-term, register-resident bf16 matrix) + ballot Sturm scan ----------------
__global__ __launch_bounds__(256, 1) void lanczos_kernel(const unsigned* __restrict__ Mp,
                                                         float* __restrict__ eig)
{
  __shared__ unsigned vpack[128];
  __shared__ float red[4][4];
  __shared__ float alpha[LM];
  __shared__ float betaArr[LM + 1];
  __shared__ float beta2arr[LM + 1];
  __shared__ float red4[4];

  int t = threadIdx.x;
  int lane = t & 63, wid = t >> 6;
  int mtx = blockIdx.x;

  // matrix row t -> registers: m[k2] = packed bf16 pair (cols 2k2, 2k2+1)
  const unsigned* Mb = Mp + (size_t)mtx * 32768 + t;
  unsigned m[128];
  #pragma unroll
  for (int k2 = 0; k2 < 128; ++k2) m[k2] = Mb[(size_t)k2 * 256];

  // deterministic start vector
  unsigned u0 = (unsigned)t * 1103515245u + 12345u;
  float r0v = 0.05f + (float)((u0 >> 9) & 0x7FFF) * (1.0f / 32768.0f);
  float nrm2 = blockReduce256(r0v * r0v, red4, lane, wid);
  float vt = r0v * rsqrtf(nrm2);
  float vprev = 0.0f;
  {
    float vo = __shfl_down(vt, 1);
    if ((lane & 1) == 0) vpack[t >> 1] = (unsigned)f2bf(vt) | ((unsigned)f2bf(vo) << 16);
  }
  __syncthreads();

  int meff = LM;
  for (int j = 0; j < LM; ++j) {
    // w[t] = sum_k M[t][k] v[k] — 4 independent FMA chains, v broadcast from LDS
    float w0 = 0.f, w1 = 0.f, w2 = 0.f, w3 = 0.f;
    #pragma unroll
    for (int q = 0; q < 32; ++q) {
      uint4 vu = *(const uint4*)&vpack[q << 2];
      w0 = fmaf(bflo(m[(q << 2) + 0]), bflo(vu.x), w0);
      w0 = fmaf(bfhi(m[(q << 2) + 0]), bfhi(vu.x), w0);
      w1 = fmaf(bflo(m[(q << 2) + 1]), bflo(vu.y), w1);
      w1 = fmaf(bfhi(m[(q << 2) + 1]), bfhi(vu.y), w1);
      w2 = fmaf(bflo(m[(q << 2) + 2]), bflo(vu.z), w2);
      w2 = fmaf(bfhi(m[(q << 2) + 2]), bfhi(vu.z), w2);
      w3 = fmaf(bflo(m[(q << 2) + 3]), bflo(vu.w), w3);
      w3 = fmaf(bfhi(m[(q << 2) + 3]), bfhi(vu.w), w3);
    }
    float wt = (w0 + w1) + (w2 + w3);
    // fused 3-dot reduce: S1=<w,v> S2=<w,vprev> S3=<w,w>
    float s1 = wt * vt, s2 = wt * vprev, s3 = wt * wt;
    #pragma unroll
    for (int off = 32; off > 0; off >>= 1) {
      s1 += __shfl_down(s1, off);
      s2 += __shfl_down(s2, off);
      s3 += __shfl_down(s3, off);
    }
    if (lane == 0) { red[wid][0] = s1; red[wid][1] = s2; red[wid][2] = s3; }
    __syncthreads();                                           // B1
    float S1 = red[0][0] + red[1][0] + red[2][0] + red[3][0];
    float S2 = red[0][1] + red[1][1] + red[2][1] + red[3][1];
    float S3 = red[0][2] + red[1][2] + red[2][2] + red[3][2];
    float bn2 = S3 - S1 * S1 - S2 * S2;
    float bn = sqrtf(fmaxf(bn2, 1e-30f));
    if (t == 0) { alpha[j] = S1; betaArr[j + 1] = bn; beta2arr[j + 1] = bn * bn; }
    if (bn < 1e-6f * (fabsf(S1) + 1.0f)) { meff = j + 1; break; }
    float wn = (wt - S1 * vt - S2 * vprev) / bn;
    vprev = vt; vt = wn;
    float vo = __shfl_down(vt, 1);
    if ((lane & 1) == 0) vpack[t >> 1] = (unsigned)f2bf(vt) | ((unsigned)f2bf(vo) << 16);
    __syncthreads();                                           // B2
  }
  __syncthreads();

  // ---- ballot-parallel Sturm scan: wave `wid` finds eigenvalue index q=wid+1 (ascending) ----
  float lo = 1e30f, hi = -1e30f;
  for (int i = 0; i < meff; ++i) {
    float bl = (i > 0) ? betaArr[i] : 0.0f;
    float bu = (i + 1 < meff) ? betaArr[i + 1] : 0.0f;
    lo = fminf(lo, alpha[i] - bl - bu);
    hi = fmaxf(hi, alpha[i] + bl + bu);
  }
  int q = wid + 1; if (q > meff - 1) q = meff - 1;
  #pragma unroll
  for (int r = 0; r < 3; ++r) {
    float step = (hi - lo) * (1.0f / 65.0f);
    float mid = lo + step * (float)(lane + 1);
    int cnt = 0;
    float d = alpha[0] - mid;
    if (fabsf(d) < 1e-20f) d = -1e-20f;
    cnt += (d < 0.0f);
    for (int i = 1; i < meff; ++i) {
      d = alpha[i] - mid - beta2arr[i] / d;
      if (fabsf(d) < 1e-20f) d = -1e-20f;
      cnt += (d < 0.0f);
    }
    unsigned long long mask = __ballot(cnt >= q + 1);
    if (mask == 0ULL) {
      lo = lo + step * 64.0f;
    } else {
      int idx = __ffsll(mask) - 1;
      float nlo = lo + step * (float)idx;
      hi = lo + step * (float)(idx + 1);
      lo = nlo;
    }
  }
  if (lane == 0) eig[mtx * 4 + wid] = 0.5f * (lo + hi);
}

// ---------------- final combine ----------------
__global__ __launch_bounds__(64) void combine_kernel(const float* __restrict__ eig,
    const double* __restrict__ diffP, const double* __restrict__ offP, const double* __restrict__ trP,
    const float* __restrict__ valo, const float* __restrict__ vali,
    const double* __restrict__ smallp, float* __restrict__ out)
{
  int l = threadIdx.x;
  float vo = valo[l], vi = vali[l];
  float el = 0, el2 = 0;
  #pragma unroll
  for (int e = 0; e < 4; ++e) {
    el  += fabsf(vo - eig[l * 4 + e]);
    el2 += fabsf(vi - eig[(64 + l) * 4 + e]);
  }
  float lo_ = el * 0.25f + 0.2f * (float)(diffP[l] * (1.0/65536.0)) - 0.1f * (float)(offP[l] * (1.0/65536.0));
  float li_ = el2 * 0.25f + 0.2f * (float)(diffP[64 + l] * (1.0/65536.0)) - 0.1f * (float)(offP[64 + l] * (1.0/65536.0));
  if (vo == 0.0f) lo_ = 0.0f;
  if (vi == 0.0f) li_ = 0.0f;
  float trb = (float)((trP[l] + trP[64 + l]) * (1.0/65536.0));
  #pragma unroll
  for (int off = 32; off > 0; off >>= 1) {
    lo_ += __shfl_down(lo_, off);
    li_ += __shfl_down(li_, off);
    trb += __shfl_down(trb, off);
  }
  if (l == 0) {
    out[64] = lo_ * (1.0f / 64.0f);
    out[65] = li_ * (1.0f / 64.0f);
    out[66] = (float)(smallp[0] / (64.0 * 6.0 * 65536.0));
    out[67] = 0.5f * (float)smallp[1] + 0.5f * (trb * (1.0f / 64.0f));
  }
}

extern "C" void kernel_launch(void* const* d_in, const int* in_sizes, int n_in,
                              void* d_out, int out_size, void* d_ws, size_t ws_size,
                              hipStream_t stream) {
  (void)in_sizes; (void)n_in; (void)out_size; (void)ws_size;
  const float* ti       = (const float*)d_in[0];
  const float* seed_ic  = (const float*)d_in[1];
  const float* seed_sir = (const float*)d_in[2];
  const float* seed_icc = (const float*)d_in[3];
  const float* seed_sirc= (const float*)d_in[4];
  const float* scalars  = (const float*)d_in[5];
  const float* valo     = (const float*)d_in[6];
  const float* vali     = (const float*)d_in[7];
  const float* S1p      = (const float*)d_in[8];
  const float* S2p      = (const float*)d_in[9];
  const float* S3p      = (const float*)d_in[10];
  const float* S4p      = (const float*)d_in[11];
  const float* cpA      = (const float*)d_in[12];
  const float* cpB      = (const float*)d_in[13];
  const float* cpC      = (const float*)d_in[14];
  const float* cpW1     = (const float*)d_in[15];
  const float* cpb1     = (const float*)d_in[16];
  const float* cpw2     = (const float*)d_in[17];
  const float* cpb2     = (const float*)d_in[18];
  const float* sW1      = (const float*)d_in[19];
  const float* sb1      = (const float*)d_in[20];
  const float* sw2      = (const float*)d_in[21];
  const float* sb2      = (const float*)d_in[22];
  const float* fW1      = (const float*)d_in[23];
  const float* fb1      = (const float*)d_in[24];
  const float* fw2      = (const float*)d_in[25];
  const float* fb2      = (const float*)d_in[26];

  char* ws = (char*)d_ws;
  ushort_t* R0     = (ushort_t*)(ws + OFF_R0);   // Z1rT; later chain2 temps
  ushort_t* R1     = (ushort_t*)(ws + OFF_R1);   // Z2rT
  float*    Z1     = (float*)(ws + OFF_Z1);
  float*    Z2     = (float*)(ws + OFF_Z2);
  ushort_t* Pa     = (ushort_t*)(ws + OFF_PA);
  ushort_t* Pb     = (ushort_t*)(ws + OFF_PB);
  unsigned* Mp     = (unsigned*)(ws + OFF_MP);
  ushort_t* ST     = (ushort_t*)(ws + OFF_ST);
  float*    eig    = (float*)(ws + OFF_EIG);
  double*   diffP  = (double*)(ws + OFF_DIFFP);
  double*   offP   = (double*)(ws + OFF_OFFP);
  double*   trP    = (double*)(ws + OFF_TRP);
  double*   smallp = (double*)(ws + OFF_SMALL);
  float*    out    = (float*)d_out;

  initk<<<1, 1, 0, stream>>>(smallp);
  tconv_s<<<dim3(8, 8, 4), 256, 0, stream>>>(S1p, S2p, S3p, S4p, ST);
  tconv_z<<<dim3(8, 8, 128), 256, 0, stream>>>(ti, R0, R1);

  dim3 gg(4, 4, 64), gb(256);
  const size_t S6 = 6ull * 65536ull, S1b = 65536ull;
  // chain1: Z1 = ic1 @ S1 @ Z1r @ S2 @ sir2^T
  gemm_mfma<false, true, true ><<<gg, gb, 0, stream>>>(ti + 0 * 65536, S6, ST + 0 * 65536, 0,   Pa, S1b);
  gemm_mfma<true,  true, true ><<<gg, gb, 0, stream>>>(Pa, S1b,             R0, S1b,            Pb, S1b);
  gemm_mfma<true,  true, true ><<<gg, gb, 0, stream>>>(Pb, S1b,             ST + 1 * 65536, 0,  Pa, S1b);
  gemm_mfma<true,  false, false><<<gg, gb, 0, stream>>>(Pa, S1b,            ti + 3 * 65536, S6, Z1, S1b);
  // chain2: Z2 = sir1 @ S3 @ Z2r @ S4 @ ic2^T
  gemm_mfma<false, true, true ><<<gg, gb, 0, stream>>>(ti + 2 * 65536, S6,  ST + 2 * 65536, 0,  R0, S1b);
  gemm_mfma<true,  true, true ><<<gg, gb, 0, stream>>>(R0, S1b,             R1, S1b,            Pa, S1b);
  gemm_mfma<true,  true, true ><<<gg, gb, 0, stream>>>(Pa, S1b,             ST + 3 * 65536, 0,  R0, S1b);
  gemm_mfma<true,  false, false><<<gg, gb, 0, stream>>>(R0, S1b,            ti + 1 * 65536, S6, Z2, S1b);

  reduce_zk<<<128, 256, 0, stream>>>(Z1, Z2, ti, diffP, offP, trP);
  cp_kernel<<<384, 256, 0, stream>>>(ti, Z1, Z2, cpA, cpB, cpC, smallp);
  sreg_kernel<<<16, 256, 0, stream>>>(S1p, S2p, S3p, S4p, smallp);
  head_kernel<<<64, 64, 0, stream>>>(seed_ic, seed_sir, seed_icc, seed_sirc, scalars,
                                     cpA, cpB, cpC, cpW1, cpb1, cpw2, cpb2,
                                     sW1, sb1, sw2, sb2, fW1, fb1, fw2, fb2, out);

  symm_bf16<<<16384, 256, 0, stream>>>(Z1, Z2, Mp);
  lanczos_kernel<<<128, 256, 0, stream>>>(Mp, eig);
  combine_kernel<<<1, 64, 0, stream>>>(eig, diffP, offP, trP, valo, vali, smallp, out);
}

// Round 7
// 291.856 us; speedup vs baseline: 4.7183x; 1.2648x over previous
//
#include <hip/hip_runtime.h>

#define LM 30

// ---------------- ws layout (bytes) ----------------
// [0,16M):   RT = Z1rT|Z2rT bf16 (tconv_z out, G2 in) -> then Mp (symm out, lanczos in)
// [16M,32M): Q0 bf16 (G1 out / G2 in / G3 out / G4 in)
// [32M,48M): Q1 bf16 (G2 out / G3 in) -> then Zb bf16 (G4 out; reduce/cp/symm in)
// [48M,...): ST (4x 128KB bf16), eig, partials
#define OFF_RT    0ull
#define OFF_MP    0ull
#define OFF_Q0    16777216ull
#define OFF_Q1    33554432ull
#define OFF_ZB    33554432ull
#define OFF_ST    50331648ull
#define OFF_EIG   (OFF_ST + 524288ull)
#define OFF_DIFFP (OFF_EIG + 4096ull)
#define OFF_OFFP  (OFF_DIFFP + 1024ull)
#define OFF_TRP   (OFF_OFFP + 1024ull)
#define OFF_SMALL (OFF_TRP + 1024ull)

typedef unsigned short ushort_t;
typedef short bf16x8 __attribute__((ext_vector_type(8)));
typedef float f32x4 __attribute__((ext_vector_type(4)));

static __device__ __forceinline__ double blockReduceSumD(double v, double* red, int t) {
  red[t] = v; __syncthreads();
  #pragma unroll
  for (int s = 128; s > 0; s >>= 1) { if (t < s) red[t] += red[t + s]; __syncthreads(); }
  double r = red[0]; __syncthreads();
  return r;
}

static __device__ __forceinline__ float blockReduce256(float v, float* red4, int lane, int wid) {
  #pragma unroll
  for (int off = 32; off > 0; off >>= 1) v += __shfl_down(v, off);
  if (lane == 0) red4[wid] = v;
  __syncthreads();
  float r = red4[0] + red4[1] + red4[2] + red4[3];
  __syncthreads();
  return r;
}

static __device__ __forceinline__ ushort_t f2bf(float f) {
  unsigned u = __float_as_uint(f);
  unsigned r = (u + 0x7fffu + ((u >> 16) & 1u)) >> 16;
  return (ushort_t)r;
}

static __device__ __forceinline__ float bflo(unsigned u) { return __uint_as_float(u << 16); }
static __device__ __forceinline__ float bfhi(unsigned u) { return __uint_as_float(u & 0xffff0000u); }
static __device__ __forceinline__ float b2f(ushort_t u) { return __uint_as_float(((unsigned)u) << 16); }

// ---------------- transpose-convert: fp32 [R][C] -> bf16 [C][R] ----------------
__global__ __launch_bounds__(256) void tconv_s(const float* __restrict__ S1, const float* __restrict__ S2,
                                               const float* __restrict__ S3, const float* __restrict__ S4,
                                               ushort_t* __restrict__ dst)
{
  __shared__ float tl[32][33];
  int z = blockIdx.z;
  const float* S = (z == 0) ? S1 : (z == 1) ? S2 : (z == 2) ? S3 : S4;
  int r0 = blockIdx.y * 32, c0 = blockIdx.x * 32;
  int tx = threadIdx.x & 31, ty = threadIdx.x >> 5;
  #pragma unroll
  for (int k = 0; k < 4; ++k) tl[ty + 8 * k][tx] = S[(size_t)(r0 + ty + 8 * k) * 256 + c0 + tx];
  __syncthreads();
  ushort_t* d = dst + (size_t)z * 65536;
  #pragma unroll
  for (int k = 0; k < 4; ++k) d[(size_t)(c0 + ty + 8 * k) * 256 + r0 + tx] = f2bf(tl[tx][ty + 8 * k]);
}

__global__ __launch_bounds__(256) void tconv_z(const float* __restrict__ ti,
                                               ushort_t* __restrict__ d0, ushort_t* __restrict__ d1)
{
  __shared__ float tl[32][33];
  int z = blockIdx.z;
  int which = z >> 6, b = z & 63;
  const float* S = ti + ((size_t)b * 6 + 4 + which) * 65536;
  ushort_t* d = (which ? d1 : d0) + (size_t)b * 65536;
  int r0 = blockIdx.y * 32, c0 = blockIdx.x * 32;
  int tx = threadIdx.x & 31, ty = threadIdx.x >> 5;
  #pragma unroll
  for (int k = 0; k < 4; ++k) tl[ty + 8 * k][tx] = S[(size_t)(r0 + ty + 8 * k) * 256 + c0 + tx];
  __syncthreads();
  #pragma unroll
  for (int k = 0; k < 4; ++k) d[(size_t)(c0 + ty + 8 * k) * 256 + r0 + tx] = f2bf(tl[tx][ty + 8 * k]);
}

// ---------------- MFMA GEMM, 128 batches, split bases at b=64: C[b] = A @ Bstored^T ----------------
template<bool ABF, bool BBF, bool CBF>
__global__ __launch_bounds__(256) void gemm_mfma(
    const void* __restrict__ A0, const void* __restrict__ A1, size_t sA,
    const void* __restrict__ B0, const void* __restrict__ B1, size_t sB,
    void* __restrict__ Cbase, size_t sC)
{
  __shared__ ushort_t At[64][40];
  __shared__ ushort_t Bt[64][40];
  const int t = threadIdx.x;
  const int b = blockIdx.z;
  const int bl = (b < 64) ? b : b - 64;
  const void* Ab_ = (b < 64) ? A0 : A1;
  const void* Bb_ = (b < 64) ? B0 : B1;
  const int tm = blockIdx.y * 64, tn = blockIdx.x * 64;
  const int w = t >> 6, l = t & 63;
  const int srow = t >> 2, scg = (t & 3) << 3;
  const int arow = (w << 4) + (l & 15);
  const int kc = (l >> 4) << 3;
  const int brow0 = l & 15;

  f32x4 acc0 = {0.f,0.f,0.f,0.f}, acc1 = {0.f,0.f,0.f,0.f}, acc2 = {0.f,0.f,0.f,0.f}, acc3 = {0.f,0.f,0.f,0.f};

  for (int s8 = 0; s8 < 8; ++s8) {
    const int k0 = s8 << 5;
    if (ABF) {
      const ushort_t* Ap = (const ushort_t*)Ab_ + (size_t)bl * sA + (size_t)(tm + srow) * 256 + k0 + scg;
      *(uint4*)&At[srow][scg] = *(const uint4*)Ap;
    } else {
      const float* Ap = (const float*)Ab_ + (size_t)bl * sA + (size_t)(tm + srow) * 256 + k0 + scg;
      float4 f0 = *(const float4*)Ap, f1 = *(const float4*)(Ap + 4);
      uint4 u;
      u.x = (unsigned)f2bf(f0.x) | ((unsigned)f2bf(f0.y) << 16);
      u.y = (unsigned)f2bf(f0.z) | ((unsigned)f2bf(f0.w) << 16);
      u.z = (unsigned)f2bf(f1.x) | ((unsigned)f2bf(f1.y) << 16);
      u.w = (unsigned)f2bf(f1.z) | ((unsigned)f2bf(f1.w) << 16);
      *(uint4*)&At[srow][scg] = u;
    }
    if (BBF) {
      const ushort_t* Bp = (const ushort_t*)Bb_ + (size_t)bl * sB + (size_t)(tn + srow) * 256 + k0 + scg;
      *(uint4*)&Bt[srow][scg] = *(const uint4*)Bp;
    } else {
      const float* Bp = (const float*)Bb_ + (size_t)bl * sB + (size_t)(tn + srow) * 256 + k0 + scg;
      float4 f0 = *(const float4*)Bp, f1 = *(const float4*)(Bp + 4);
      uint4 u;
      u.x = (unsigned)f2bf(f0.x) | ((unsigned)f2bf(f0.y) << 16);
      u.y = (unsigned)f2bf(f0.z) | ((unsigned)f2bf(f0.w) << 16);
      u.z = (unsigned)f2bf(f1.x) | ((unsigned)f2bf(f1.y) << 16);
      u.w = (unsigned)f2bf(f1.z) | ((unsigned)f2bf(f1.w) << 16);
      *(uint4*)&Bt[srow][scg] = u;
    }
    __syncthreads();
    bf16x8 av  = *(const bf16x8*)&At[arow][kc];
    bf16x8 bv0 = *(const bf16x8*)&Bt[ 0 + brow0][kc];
    bf16x8 bv1 = *(const bf16x8*)&Bt[16 + brow0][kc];
    bf16x8 bv2 = *(const bf16x8*)&Bt[32 + brow0][kc];
    bf16x8 bv3 = *(const bf16x8*)&Bt[48 + brow0][kc];
    acc0 = __builtin_amdgcn_mfma_f32_16x16x32_bf16(av, bv0, acc0, 0, 0, 0);
    acc1 = __builtin_amdgcn_mfma_f32_16x16x32_bf16(av, bv1, acc1, 0, 0, 0);
    acc2 = __builtin_amdgcn_mfma_f32_16x16x32_bf16(av, bv2, acc2, 0, 0, 0);
    acc3 = __builtin_amdgcn_mfma_f32_16x16x32_bf16(av, bv3, acc3, 0, 0, 0);
    __syncthreads();
  }

  const int m0 = tm + (w << 4) + ((l >> 4) << 2);
  if (CBF) {
    ushort_t* Cp = (ushort_t*)Cbase + (size_t)b * sC;
    #pragma unroll
    for (int q = 0; q < 4; ++q) {
      size_t r = (size_t)(m0 + q) * 256;
      Cp[r + tn +  0 + brow0] = f2bf(acc0[q]);
      Cp[r + tn + 16 + brow0] = f2bf(acc1[q]);
      Cp[r + tn + 32 + brow0] = f2bf(acc2[q]);
      Cp[r + tn + 48 + brow0] = f2bf(acc3[q]);
    }
  } else {
    float* Cp = (float*)Cbase + (size_t)b * sC;
    #pragma unroll
    for (int q = 0; q < 4; ++q) {
      size_t r = (size_t)(m0 + q) * 256;
      Cp[r + tn +  0 + brow0] = acc0[q];
      Cp[r + tn + 16 + brow0] = acc1[q];
      Cp[r + tn + 32 + brow0] = acc2[q];
      Cp[r + tn + 48 + brow0] = acc3[q];
    }
  }
}

// ---------------- per-(z,b) reductions on bf16 Z: diff, offdiag, transform ----------------
__global__ __launch_bounds__(256) void reduce_zk(const ushort_t* __restrict__ Zb,
                                                 const float* __restrict__ ti,
                                                 double* __restrict__ diffP, double* __restrict__ offP,
                                                 double* __restrict__ trP)
{
  __shared__ double red[256];
  int blk = blockIdx.x, t = threadIdx.x;
  int z = blk >> 6, b = blk & 63;
  const ushort_t* M = Zb + (size_t)blk * 65536;
  const float* Mr = ti + ((size_t)b * 6 + (z ? 5 : 4)) * 65536;
  double d = 0, o = 0, tr = 0;
  for (int it = 0; it < 32; ++it) {
    int e = (it * 256 + t) * 8;
    uint4 mv = *(const uint4*)(M + e);
    float4 f0 = *(const float4*)(Mr + e);
    float4 f1 = *(const float4*)(Mr + e + 4);
    int i = e >> 8, j0 = e & 255;
    float a[8] = {bflo(mv.x),bfhi(mv.x),bflo(mv.y),bfhi(mv.y),bflo(mv.z),bfhi(mv.z),bflo(mv.w),bfhi(mv.w)};
    float mr[8] = {f0.x,f0.y,f0.z,f0.w,f1.x,f1.y,f1.z,f1.w};
    float pd = 0.f, po = 0.f, ptr = 0.f;
    #pragma unroll
    for (int q = 0; q < 8; ++q) {
      bool diag = (j0 + q) == i;
      float av = a[q];
      pd += fabsf(av - (diag ? 1.0f : 0.0f));
      po += diag ? 0.0f : fabsf(av);
      ptr += fabsf(av - mr[q]);
    }
    d += (double)pd; o += (double)po; tr += (double)ptr;
  }
  d = blockReduceSumD(d, red, t);
  o = blockReduceSumD(o, red, t);
  tr = blockReduceSumD(tr, red, t);
  if (t == 0) { diffP[blk] = d; offP[blk] = o; trP[blk] = tr; }
}

// ---------------- CP reconstruction loss ----------------
__global__ __launch_bounds__(256) void cp_kernel(const float* __restrict__ ti,
                                                 const ushort_t* __restrict__ Zb,
                                                 const float* __restrict__ cpA, const float* __restrict__ cpB,
                                                 const float* __restrict__ cpC, double* __restrict__ smallp)
{
  __shared__ float Bsh[256][4];
  __shared__ float Csh[256][4];
  __shared__ double red[256];
  int blk = blockIdx.x, t = threadIdx.x;
  int b = blk / 6, i = blk - b * 6;
  *(float4*)&Bsh[t][0] = *(const float4*)(cpB + ((size_t)b * 256 + t) * 4);
  *(float4*)&Csh[t][0] = *(const float4*)(cpC + ((size_t)b * 256 + t) * 4);
  float a0 = cpA[((size_t)b * 6 + i) * 4 + 0];
  float a1 = cpA[((size_t)b * 6 + i) * 4 + 1];
  float a2 = cpA[((size_t)b * 6 + i) * 4 + 2];
  float a3 = cpA[((size_t)b * 6 + i) * 4 + 3];
  __syncthreads();
  float c0 = Csh[t][0], c1 = Csh[t][1], c2 = Csh[t][2], c3 = Csh[t][3];
  double acc = 0;
  if (i < 4) {
    const float* T = ti + ((size_t)b * 6 + i) * 65536;
    for (int j = 0; j < 256; ++j) {
      float recon = a0 * Bsh[j][0] * c0 + a1 * Bsh[j][1] * c1 + a2 * Bsh[j][2] * c2 + a3 * Bsh[j][3] * c3;
      float dv = recon - T[(size_t)j * 256 + t];
      acc += (double)dv * (double)dv;
    }
  } else {
    const ushort_t* T = Zb + (size_t)((i == 4) ? b : 64 + b) * 65536;
    for (int j = 0; j < 256; ++j) {
      float recon = a0 * Bsh[j][0] * c0 + a1 * Bsh[j][1] * c1 + a2 * Bsh[j][2] * c2 + a3 * Bsh[j][3] * c3;
      float dv = recon - b2f(T[(size_t)j * 256 + t]);
      acc += (double)dv * (double)dv;
    }
  }
  acc = blockReduceSumD(acc, red, t);
  if (t == 0) atomicAdd(&smallp[0], acc);
}

// ---------------- S-matrix regularizers (16 blocks) ----------------
__global__ __launch_bounds__(256) void sreg_kernel(const float* __restrict__ S1, const float* __restrict__ S2,
                                                   const float* __restrict__ S3, const float* __restrict__ S4,
                                                   double* __restrict__ smallp)
{
  __shared__ double red[256];
  int t = threadIdx.x, blk = blockIdx.x;
  int s = blk >> 2, part = blk & 3;
  const float* S = (s == 0) ? S1 : (s == 1) ? S2 : (s == 2) ? S3 : S4;
  double tot = 0;
  int e0 = part * 16384;
  for (int e = e0 + t; e < e0 + 16384; e += 256) {
    int i = e >> 8, j = e & 255;
    float a = S[e];
    tot += (double)fabsf(a - (i == j ? 1.0f : 0.0f));
    if (i != j) tot += (double)fabsf(a);
  }
  tot = blockReduceSumD(tot, red, t);
  if (t == 0) atomicAdd(&smallp[1], -tot / 65536.0);
}

__global__ void initk(double* smallp) { smallp[0] = 0.0; smallp[1] = 0.0; }

// ---------------- MLP heads -> logits ----------------
__global__ __launch_bounds__(64) void head_kernel(
    const float* __restrict__ seed_ic, const float* __restrict__ seed_sir,
    const float* __restrict__ seed_icc, const float* __restrict__ seed_sirc,
    const float* __restrict__ scalars,
    const float* __restrict__ cpA, const float* __restrict__ cpB, const float* __restrict__ cpC,
    const float* __restrict__ cpW1, const float* __restrict__ cpb1,
    const float* __restrict__ cpw2, const float* __restrict__ cpb2,
    const float* __restrict__ sW1, const float* __restrict__ sb1,
    const float* __restrict__ sw2, const float* __restrict__ sb2,
    const float* __restrict__ fW1, const float* __restrict__ fb1,
    const float* __restrict__ fw2, const float* __restrict__ fb2,
    float* __restrict__ out)
{
  int b = blockIdx.x, l = threadIdx.x;
  __shared__ float tri[4][3];
  __shared__ float cps[4], seds[4];
  __shared__ float hbuf[128];
  if (l < 4) {
    float s = 0;
    #pragma unroll
    for (int i = 0; i < 6; ++i) s += cpA[((size_t)b * 6 + i) * 4 + l];
    tri[l][0] = s * (1.0f / 6.0f);
  }
  float4 sB = make_float4(0,0,0,0), sC = make_float4(0,0,0,0);
  for (int j = l; j < 256; j += 64) {
    float4 v = *(const float4*)(cpB + ((size_t)b * 256 + j) * 4);
    sB.x += v.x; sB.y += v.y; sB.z += v.z; sB.w += v.w;
    float4 w = *(const float4*)(cpC + ((size_t)b * 256 + j) * 4);
    sC.x += w.x; sC.y += w.y; sC.z += w.z; sC.w += w.w;
  }
  #pragma unroll
  for (int off = 32; off > 0; off >>= 1) {
    sB.x += __shfl_down(sB.x, off); sB.y += __shfl_down(sB.y, off);
    sB.z += __shfl_down(sB.z, off); sB.w += __shfl_down(sB.w, off);
    sC.x += __shfl_down(sC.x, off); sC.y += __shfl_down(sC.y, off);
    sC.z += __shfl_down(sC.z, off); sC.w += __shfl_down(sC.w, off);
  }
  if (l == 0) {
    tri[0][1] = sB.x * (1.0f/256.0f); tri[1][1] = sB.y * (1.0f/256.0f);
    tri[2][1] = sB.z * (1.0f/256.0f); tri[3][1] = sB.w * (1.0f/256.0f);
    tri[0][2] = sC.x * (1.0f/256.0f); tri[1][2] = sC.y * (1.0f/256.0f);
    tri[2][2] = sC.z * (1.0f/256.0f); tri[3][2] = sC.w * (1.0f/256.0f);
  }
  __syncthreads();
  if (l < 4) {
    float s = 0;
    for (int hh = 0; hh < 32; ++hh) {
      float z = cpb1[l * 32 + hh];
      #pragma unroll
      for (int d = 0; d < 3; ++d) z += tri[l][d] * cpW1[(l * 32 + hh) * 3 + d];
      z = fmaxf(z, 0.0f);
      s += z * cpw2[l * 32 + hh];
    }
    cps[l] = s + cpb2[l];
  }
  for (int p = l; p < 128; p += 64) {
    int j = p >> 5, hh = p & 31;
    const float* sv = (j == 0) ? seed_ic : (j == 1) ? seed_sir : (j == 2) ? seed_icc : seed_sirc;
    sv += (size_t)b * 256;
    const float* wrow = sW1 + ((size_t)(j * 32 + hh)) * 256;
    float z = sb1[j * 32 + hh];
    for (int k = 0; k < 256; k += 4) {
      float4 a = *(const float4*)(sv + k);
      float4 w4 = *(const float4*)(wrow + k);
      z += a.x * w4.x + a.y * w4.y + a.z * w4.z + a.w * w4.w;
    }
    z = fmaxf(z, 0.0f);
    hbuf[p] = z * sw2[j * 32 + hh];
  }
  __syncthreads();
  if (l < 4) {
    float s = 0;
    #pragma unroll
    for (int hh = 0; hh < 32; ++hh) s += hbuf[l * 32 + hh];
    seds[l] = s + sb2[l];
  }
  __syncthreads();
  float av = 0.0f;
  if (l < 32) {
    float z = fb1[l];
    #pragma unroll
    for (int d = 0; d < 10; ++d) {
      float cd = (d < 4) ? cps[d] : (d < 8) ? seds[d - 4] : scalars[b * 2 + (d - 8)];
      z += cd * fW1[l * 10 + d];
    }
    z = fmaxf(z, 0.0f);
    av = z * fw2[l];
  }
  #pragma unroll
  for (int off = 16; off > 0; off >>= 1) av += __shfl_down(av, off);
  if (l == 0) out[b] = av + fb2[0];
}

// ---------------- symmetrize bf16 Z -> packed bf16x2 Mp[mtx][k2*256+row], 16-col strips ----------------
__global__ __launch_bounds__(256) void symm_bf16(const ushort_t* __restrict__ Zb,
                                                 unsigned* __restrict__ Mp)
{
  int mtx = blockIdx.x >> 4;
  int s = blockIdx.x & 15;
  int t = threadIdx.x;
  const ushort_t* M = Zb + (size_t)mtx * 65536;
  int c0 = s << 4;
  uint4 r0 = *(const uint4*)(M + (size_t)t * 256 + c0);       // row side: M[t][c0..c0+7]
  uint4 r1 = *(const uint4*)(M + (size_t)t * 256 + c0 + 8);   // M[t][c0+8..c0+15]
  float rj[16] = {bflo(r0.x),bfhi(r0.x),bflo(r0.y),bfhi(r0.y),bflo(r0.z),bfhi(r0.z),bflo(r0.w),bfhi(r0.w),
                  bflo(r1.x),bfhi(r1.x),bflo(r1.y),bfhi(r1.y),bflo(r1.z),bfhi(r1.z),bflo(r1.w),bfhi(r1.w)};
  float cv[16];
  #pragma unroll
  for (int q = 0; q < 16; ++q) cv[q] = b2f(M[(size_t)(c0 + q) * 256 + t]);  // col side, coalesced
  unsigned* Mo = Mp + (size_t)mtx * 32768;
  #pragma unroll
  for (int p = 0; p < 8; ++p) {
    float m0 = 0.5f * (rj[2 * p]     + cv[2 * p]);
    float m1 = 0.5f * (rj[2 * p + 1] + cv[2 * p + 1]);
    Mo[(size_t)((s << 3) + p) * 256 + t] = (unsigned)f2bf(m0) | ((unsigned)f2bf(m1) << 16);
  }
}

// ---------------- Lanczos (3-term, register matrix, pipelined v-broadcast) + ballot Sturm ----------------
#define FMAQ(v, base) { \
  w0 = fmaf(bflo(m[(base)+0]), bflo((v).x), w0); w0 = fmaf(bfhi(m[(base)+0]), bfhi((v).x), w0); \
  w1 = fmaf(bflo(m[(base)+1]), bflo((v).y), w1); w1 = fmaf(bfhi(m[(base)+1]), bfhi((v).y), w1); \
  w2 = fmaf(bflo(m[(base)+2]), bflo((v).z), w2); w2 = fmaf(bfhi(m[(base)+2]), bfhi((v).z), w2); \
  w3 = fmaf(bflo(m[(base)+3]), bflo((v).w), w3); w3 = fmaf(bfhi(m[(base)+3]), bfhi((v).w), w3); }

__global__ __launch_bounds__(256, 1) void lanczos_kernel(const unsigned* __restrict__ Mp,
                                                         float* __restrict__ eig)
{
  __shared__ unsigned vpack[128];
  __shared__ float red[4][4];
  __shared__ float alpha[LM];
  __shared__ float betaArr[LM + 1];
  __shared__ float beta2arr[LM + 1];
  __shared__ float red4[4];

  int t = threadIdx.x;
  int lane = t & 63, wid = t >> 6;
  int mtx = blockIdx.x;

  const unsigned* Mb = Mp + (size_t)mtx * 32768 + t;
  unsigned m[128];
  #pragma unroll
  for (int k2 = 0; k2 < 128; ++k2) m[k2] = Mb[(size_t)k2 * 256];

  unsigned u0 = (unsigned)t * 1103515245u + 12345u;
  float r0v = 0.05f + (float)((u0 >> 9) & 0x7FFF) * (1.0f / 32768.0f);
  float nrm2 = blockReduce256(r0v * r0v, red4, lane, wid);
  float vt = r0v * rsqrtf(nrm2);
  float vprev = 0.0f;
  {
    float vo = __shfl_down(vt, 1);
    if ((lane & 1) == 0) vpack[t >> 1] = (unsigned)f2bf(vt) | ((unsigned)f2bf(vo) << 16);
  }
  __syncthreads();

  const uint4* vp4 = (const uint4*)vpack;

  int meff = LM;
  for (int j = 0; j < LM; ++j) {
    // pipelined matvec: two 8xuint4 buffers, load group g+1 while FMA-ing group g
    float w0 = 0.f, w1 = 0.f, w2 = 0.f, w3 = 0.f;
    uint4 a0,a1,a2,a3,a4,a5,a6,a7, b0,b1,b2,b3,b4,b5,b6,b7;
    a0=vp4[0]; a1=vp4[1]; a2=vp4[2]; a3=vp4[3]; a4=vp4[4]; a5=vp4[5]; a6=vp4[6]; a7=vp4[7];
    b0=vp4[8]; b1=vp4[9]; b2=vp4[10]; b3=vp4[11]; b4=vp4[12]; b5=vp4[13]; b6=vp4[14]; b7=vp4[15];
    FMAQ(a0,0) FMAQ(a1,4) FMAQ(a2,8) FMAQ(a3,12) FMAQ(a4,16) FMAQ(a5,20) FMAQ(a6,24) FMAQ(a7,28)
    a0=vp4[16]; a1=vp4[17]; a2=vp4[18]; a3=vp4[19]; a4=vp4[20]; a5=vp4[21]; a6=vp4[22]; a7=vp4[23];
    FMAQ(b0,32) FMAQ(b1,36) FMAQ(b2,40) FMAQ(b3,44) FMAQ(b4,48) FMAQ(b5,52) FMAQ(b6,56) FMAQ(b7,60)
    b0=vp4[24]; b1=vp4[25]; b2=vp4[26]; b3=vp4[27]; b4=vp4[28]; b5=vp4[29]; b6=vp4[30]; b7=vp4[31];
    FMAQ(a0,64) FMAQ(a1,68) FMAQ(a2,72) FMAQ(a3,76) FMAQ(a4,80) FMAQ(a5,84) FMAQ(a6,88) FMAQ(a7,92)
    FMAQ(b0,96) FMAQ(b1,100) FMAQ(b2,104) FMAQ(b3,108) FMAQ(b4,112) FMAQ(b5,116) FMAQ(b6,120) FMAQ(b7,124)
    float wt = (w0 + w1) + (w2 + w3);

    float s1 = wt * vt, s2 = wt * vprev, s3 = wt * wt;
    #pragma unroll
    for (int off = 32; off > 0; off >>= 1) {
      s1 += __shfl_down(s1, off);
      s2 += __shfl_down(s2, off);
      s3 += __shfl_down(s3, off);
    }
    if (lane == 0) { red[wid][0] = s1; red[wid][1] = s2; red[wid][2] = s3; }
    __syncthreads();                                           // B1
    float S1 = red[0][0] + red[1][0] + red[2][0] + red[3][0];
    float S2 = red[0][1] + red[1][1] + red[2][1] + red[3][1];
    float S3 = red[0][2] + red[1][2] + red[2][2] + red[3][2];
    float bn2 = S3 - S1 * S1 - S2 * S2;
    float bn = sqrtf(fmaxf(bn2, 1e-30f));
    if (t == 0) { alpha[j] = S1; betaArr[j + 1] = bn; beta2arr[j + 1] = bn * bn; }
    if (bn < 1e-6f * (fabsf(S1) + 1.0f)) { meff = j + 1; break; }
    float wn = (wt - S1 * vt - S2 * vprev) / bn;
    vprev = vt; vt = wn;
    float vo = __shfl_down(vt, 1);
    if ((lane & 1) == 0) vpack[t >> 1] = (unsigned)f2bf(vt) | ((unsigned)f2bf(vo) << 16);
    __syncthreads();                                           // B2
  }
  __syncthreads();

  // ballot-parallel Sturm scan: wave wid finds eigenvalue index q=wid+1 (ascending)
  float lo = 1e30f, hi = -1e30f;
  for (int i = 0; i < meff; ++i) {
    float bl = (i > 0) ? betaArr[i] : 0.0f;
    float bu = (i + 1 < meff) ? betaArr[i + 1] : 0.0f;
    lo = fminf(lo, alpha[i] - bl - bu);
    hi = fmaxf(hi, alpha[i] + bl + bu);
  }
  int q = wid + 1; if (q > meff - 1) q = meff - 1;
  #pragma unroll
  for (int r = 0; r < 3; ++r) {
    float step = (hi - lo) * (1.0f / 65.0f);
    float mid = lo + step * (float)(lane + 1);
    int cnt = 0;
    float d = alpha[0] - mid;
    if (fabsf(d) < 1e-20f) d = -1e-20f;
    cnt += (d < 0.0f);
    for (int i = 1; i < meff; ++i) {
      d = alpha[i] - mid - beta2arr[i] / d;
      if (fabsf(d) < 1e-20f) d = -1e-20f;
      cnt += (d < 0.0f);
    }
    unsigned long long mask = __ballot(cnt >= q + 1);
    if (mask == 0ULL) {
      lo = lo + step * 64.0f;
    } else {
      int idx = __ffsll(mask) - 1;
      float nlo = lo + step * (float)idx;
      hi = lo + step * (float)(idx + 1);
      lo = nlo;
    }
  }
  if (lane == 0) eig[mtx * 4 + wid] = 0.5f * (lo + hi);
}

// ---------------- final combine ----------------
__global__ __launch_bounds__(64) void combine_kernel(const float* __restrict__ eig,
    const double* __restrict__ diffP, const double* __restrict__ offP, const double* __restrict__ trP,
    const float* __restrict__ valo, const float* __restrict__ vali,
    const double* __restrict__ smallp, float* __restrict__ out)
{
  int l = threadIdx.x;
  float vo = valo[l], vi = vali[l];
  float el = 0, el2 = 0;
  #pragma unroll
  for (int e = 0; e < 4; ++e) {
    el  += fabsf(vo - eig[l * 4 + e]);
    el2 += fabsf(vi - eig[(64 + l) * 4 + e]);
  }
  float lo_ = el * 0.25f + 0.2f * (float)(diffP[l] * (1.0/65536.0)) - 0.1f * (float)(offP[l] * (1.0/65536.0));
  float li_ = el2 * 0.25f + 0.2f * (float)(diffP[64 + l] * (1.0/65536.0)) - 0.1f * (float)(offP[64 + l] * (1.0/65536.0));
  if (vo == 0.0f) lo_ = 0.0f;
  if (vi == 0.0f) li_ = 0.0f;
  float trb = (float)((trP[l] + trP[64 + l]) * (1.0/65536.0));
  #pragma unroll
  for (int off = 32; off > 0; off >>= 1) {
    lo_ += __shfl_down(lo_, off);
    li_ += __shfl_down(li_, off);
    trb += __shfl_down(trb, off);
  }
  if (l == 0) {
    out[64] = lo_ * (1.0f / 64.0f);
    out[65] = li_ * (1.0f / 64.0f);
    out[66] = (float)(smallp[0] / (64.0 * 6.0 * 65536.0));
    out[67] = 0.5f * (float)smallp[1] + 0.5f * (trb * (1.0f / 64.0f));
  }
}

extern "C" void kernel_launch(void* const* d_in, const int* in_sizes, int n_in,
                              void* d_out, int out_size, void* d_ws, size_t ws_size,
                              hipStream_t stream) {
  (void)in_sizes; (void)n_in; (void)out_size; (void)ws_size;
  const float* ti       = (const float*)d_in[0];
  const float* seed_ic  = (const float*)d_in[1];
  const float* seed_sir = (const float*)d_in[2];
  const float* seed_icc = (const float*)d_in[3];
  const float* seed_sirc= (const float*)d_in[4];
  const float* scalars  = (const float*)d_in[5];
  const float* valo     = (const float*)d_in[6];
  const float* vali     = (const float*)d_in[7];
  const float* S1p      = (const float*)d_in[8];
  const float* S2p      = (const float*)d_in[9];
  const float* S3p      = (const float*)d_in[10];
  const float* S4p      = (const float*)d_in[11];
  const float* cpA      = (const float*)d_in[12];
  const float* cpB      = (const float*)d_in[13];
  const float* cpC      = (const float*)d_in[14];
  const float* cpW1     = (const float*)d_in[15];
  const float* cpb1     = (const float*)d_in[16];
  const float* cpw2     = (const float*)d_in[17];
  const float* cpb2     = (const float*)d_in[18];
  const float* sW1      = (const float*)d_in[19];
  const float* sb1      = (const float*)d_in[20];
  const float* sw2      = (const float*)d_in[21];
  const float* sb2      = (const float*)d_in[22];
  const float* fW1      = (const float*)d_in[23];
  const float* fb1      = (const float*)d_in[24];
  const float* fw2      = (const float*)d_in[25];
  const float* fb2      = (const float*)d_in[26];

  char* ws = (char*)d_ws;
  ushort_t* RT     = (ushort_t*)(ws + OFF_RT);
  ushort_t* Q0     = (ushort_t*)(ws + OFF_Q0);
  ushort_t* Q1     = (ushort_t*)(ws + OFF_Q1);
  ushort_t* Zb     = (ushort_t*)(ws + OFF_ZB);
  unsigned* Mp     = (unsigned*)(ws + OFF_MP);
  ushort_t* ST     = (ushort_t*)(ws + OFF_ST);
  float*    eig    = (float*)(ws + OFF_EIG);
  double*   diffP  = (double*)(ws + OFF_DIFFP);
  double*   offP   = (double*)(ws + OFF_OFFP);
  double*   trP    = (double*)(ws + OFF_TRP);
  double*   smallp = (double*)(ws + OFF_SMALL);
  float*    out    = (float*)d_out;

  initk<<<1, 1, 0, stream>>>(smallp);
  tconv_s<<<dim3(8, 8, 4), 256, 0, stream>>>(S1p, S2p, S3p, S4p, ST);
  tconv_z<<<dim3(8, 8, 128), 256, 0, stream>>>(ti, RT, RT + 64 * 65536);

  dim3 gg(4, 4, 128), gb(256);
  const size_t S6 = 6ull * 65536ull, S1b = 65536ull;
  // G1: Q0[b] = toBF(ti[b][0 or 2]) @ S{1,3}
  gemm_mfma<false, true, true ><<<gg, gb, 0, stream>>>(
      (const void*)(ti + 0 * 65536), (const void*)(ti + 2 * 65536), S6,
      (const void*)(ST + 0 * 65536), (const void*)(ST + 2 * 65536), 0,
      (void*)Q0, S1b);
  // G2: Q1[b] = Q0[b] @ Z{1,2}r
  gemm_mfma<true, true, true ><<<gg, gb, 0, stream>>>(
      (const void*)Q0, (const void*)(Q0 + 64 * 65536), S1b,
      (const void*)RT, (const void*)(RT + 64 * 65536), S1b,
      (void*)Q1, S1b);
  // G3: Q0[b] = Q1[b] @ S{2,4}
  gemm_mfma<true, true, true ><<<gg, gb, 0, stream>>>(
      (const void*)Q1, (const void*)(Q1 + 64 * 65536), S1b,
      (const void*)(ST + 1 * 65536), (const void*)(ST + 3 * 65536), 0,
      (void*)Q0, S1b);
  // G4: Zb[b] = Q0[b] @ (sir2 or ic2)^T  (bf16 out)
  gemm_mfma<true, false, true ><<<gg, gb, 0, stream>>>(
      (const void*)Q0, (const void*)(Q0 + 64 * 65536), S1b,
      (const void*)(ti + 3 * 65536), (const void*)(ti + 1 * 65536), S6,
      (void*)Zb, S1b);

  reduce_zk<<<128, 256, 0, stream>>>(Zb, ti, diffP, offP, trP);
  cp_kernel<<<384, 256, 0, stream>>>(ti, Zb, cpA, cpB, cpC, smallp);
  sreg_kernel<<<16, 256, 0, stream>>>(S1p, S2p, S3p, S4p, smallp);
  head_kernel<<<64, 64, 0, stream>>>(seed_ic, seed_sir, seed_icc, seed_sirc, scalars,
                                     cpA, cpB, cpC, cpW1, cpb1, cpw2, cpb2,
                                     sW1, sb1, sw2, sb2, fW1, fb1, fw2, fb2, out);

  symm_bf16<<<2048, 256, 0, stream>>>(Zb, Mp);
  lanczos_kernel<<<128, 256, 0, stream>>>(Mp, eig);
  combine_kernel<<<1, 64, 0, stream>>>(eig, diffP, offP, trP, valo, vali, smallp, out);
}

// Round 8
// 269.278 us; speedup vs baseline: 5.1139x; 1.0838x over previous
//
#include <hip/hip_runtime.h>

#define LM 30

// ---------------- ws layout (bytes) ----------------
#define OFF_RT    0ull
#define OFF_MP    0ull
#define OFF_Q0    16777216ull
#define OFF_Q1    33554432ull
#define OFF_ZB    33554432ull
#define OFF_ST    50331648ull
#define OFF_EIG   (OFF_ST + 524288ull)
#define OFF_DIFFP (OFF_EIG + 4096ull)
#define OFF_OFFP  (OFF_DIFFP + 1024ull)
#define OFF_TRP   (OFF_OFFP + 1024ull)
#define OFF_SMALL (OFF_TRP + 1024ull)

typedef unsigned short ushort_t;
typedef short bf16x8 __attribute__((ext_vector_type(8)));
typedef float f32x4 __attribute__((ext_vector_type(4)));

static __device__ __forceinline__ double blockReduceSumD(double v, double* red, int t) {
  red[t] = v; __syncthreads();
  #pragma unroll
  for (int s = 128; s > 0; s >>= 1) { if (t < s) red[t] += red[t + s]; __syncthreads(); }
  double r = red[0]; __syncthreads();
  return r;
}

static __device__ __forceinline__ ushort_t f2bf(float f) {
  unsigned u = __float_as_uint(f);
  unsigned r = (u + 0x7fffu + ((u >> 16) & 1u)) >> 16;
  return (ushort_t)r;
}

static __device__ __forceinline__ float bflo(unsigned u) { return __uint_as_float(u << 16); }
static __device__ __forceinline__ float bfhi(unsigned u) { return __uint_as_float(u & 0xffff0000u); }
static __device__ __forceinline__ float b2f(ushort_t u) { return __uint_as_float(((unsigned)u) << 16); }

// ---------------- transpose-convert: fp32 [R][C] -> bf16 [C][R] ----------------
__global__ __launch_bounds__(256) void tconv_s(const float* __restrict__ S1, const float* __restrict__ S2,
                                               const float* __restrict__ S3, const float* __restrict__ S4,
                                               ushort_t* __restrict__ dst)
{
  __shared__ float tl[32][33];
  int z = blockIdx.z;
  const float* S = (z == 0) ? S1 : (z == 1) ? S2 : (z == 2) ? S3 : S4;
  int r0 = blockIdx.y * 32, c0 = blockIdx.x * 32;
  int tx = threadIdx.x & 31, ty = threadIdx.x >> 5;
  #pragma unroll
  for (int k = 0; k < 4; ++k) tl[ty + 8 * k][tx] = S[(size_t)(r0 + ty + 8 * k) * 256 + c0 + tx];
  __syncthreads();
  ushort_t* d = dst + (size_t)z * 65536;
  #pragma unroll
  for (int k = 0; k < 4; ++k) d[(size_t)(c0 + ty + 8 * k) * 256 + r0 + tx] = f2bf(tl[tx][ty + 8 * k]);
}

__global__ __launch_bounds__(256) void tconv_z(const float* __restrict__ ti,
                                               ushort_t* __restrict__ d0, ushort_t* __restrict__ d1)
{
  __shared__ float tl[32][33];
  int z = blockIdx.z;
  int which = z >> 6, b = z & 63;
  const float* S = ti + ((size_t)b * 6 + 4 + which) * 65536;
  ushort_t* d = (which ? d1 : d0) + (size_t)b * 65536;
  int r0 = blockIdx.y * 32, c0 = blockIdx.x * 32;
  int tx = threadIdx.x & 31, ty = threadIdx.x >> 5;
  #pragma unroll
  for (int k = 0; k < 4; ++k) tl[ty + 8 * k][tx] = S[(size_t)(r0 + ty + 8 * k) * 256 + c0 + tx];
  __syncthreads();
  #pragma unroll
  for (int k = 0; k < 4; ++k) d[(size_t)(c0 + ty + 8 * k) * 256 + r0 + tx] = f2bf(tl[tx][ty + 8 * k]);
}

// ---------------- MFMA GEMM, 128 batches, split bases at b=64: C[b] = A @ Bstored^T ----------------
template<bool ABF, bool BBF, bool CBF>
__global__ __launch_bounds__(256) void gemm_mfma(
    const void* __restrict__ A0, const void* __restrict__ A1, size_t sA,
    const void* __restrict__ B0, const void* __restrict__ B1, size_t sB,
    void* __restrict__ Cbase, size_t sC)
{
  __shared__ ushort_t At[64][40];
  __shared__ ushort_t Bt[64][40];
  const int t = threadIdx.x;
  const int b = blockIdx.z;
  const int bl = (b < 64) ? b : b - 64;
  const void* Ab_ = (b < 64) ? A0 : A1;
  const void* Bb_ = (b < 64) ? B0 : B1;
  const int tm = blockIdx.y * 64, tn = blockIdx.x * 64;
  const int w = t >> 6, l = t & 63;
  const int srow = t >> 2, scg = (t & 3) << 3;
  const int arow = (w << 4) + (l & 15);
  const int kc = (l >> 4) << 3;
  const int brow0 = l & 15;

  f32x4 acc0 = {0.f,0.f,0.f,0.f}, acc1 = {0.f,0.f,0.f,0.f}, acc2 = {0.f,0.f,0.f,0.f}, acc3 = {0.f,0.f,0.f,0.f};

  for (int s8 = 0; s8 < 8; ++s8) {
    const int k0 = s8 << 5;
    if (ABF) {
      const ushort_t* Ap = (const ushort_t*)Ab_ + (size_t)bl * sA + (size_t)(tm + srow) * 256 + k0 + scg;
      *(uint4*)&At[srow][scg] = *(const uint4*)Ap;
    } else {
      const float* Ap = (const float*)Ab_ + (size_t)bl * sA + (size_t)(tm + srow) * 256 + k0 + scg;
      float4 f0 = *(const float4*)Ap, f1 = *(const float4*)(Ap + 4);
      uint4 u;
      u.x = (unsigned)f2bf(f0.x) | ((unsigned)f2bf(f0.y) << 16);
      u.y = (unsigned)f2bf(f0.z) | ((unsigned)f2bf(f0.w) << 16);
      u.z = (unsigned)f2bf(f1.x) | ((unsigned)f2bf(f1.y) << 16);
      u.w = (unsigned)f2bf(f1.z) | ((unsigned)f2bf(f1.w) << 16);
      *(uint4*)&At[srow][scg] = u;
    }
    if (BBF) {
      const ushort_t* Bp = (const ushort_t*)Bb_ + (size_t)bl * sB + (size_t)(tn + srow) * 256 + k0 + scg;
      *(uint4*)&Bt[srow][scg] = *(const uint4*)Bp;
    } else {
      const float* Bp = (const float*)Bb_ + (size_t)bl * sB + (size_t)(tn + srow) * 256 + k0 + scg;
      float4 f0 = *(const float4*)Bp, f1 = *(const float4*)(Bp + 4);
      uint4 u;
      u.x = (unsigned)f2bf(f0.x) | ((unsigned)f2bf(f0.y) << 16);
      u.y = (unsigned)f2bf(f0.z) | ((unsigned)f2bf(f0.w) << 16);
      u.z = (unsigned)f2bf(f1.x) | ((unsigned)f2bf(f1.y) << 16);
      u.w = (unsigned)f2bf(f1.z) | ((unsigned)f2bf(f1.w) << 16);
      *(uint4*)&Bt[srow][scg] = u;
    }
    __syncthreads();
    bf16x8 av  = *(const bf16x8*)&At[arow][kc];
    bf16x8 bv0 = *(const bf16x8*)&Bt[ 0 + brow0][kc];
    bf16x8 bv1 = *(const bf16x8*)&Bt[16 + brow0][kc];
    bf16x8 bv2 = *(const bf16x8*)&Bt[32 + brow0][kc];
    bf16x8 bv3 = *(const bf16x8*)&Bt[48 + brow0][kc];
    acc0 = __builtin_amdgcn_mfma_f32_16x16x32_bf16(av, bv0, acc0, 0, 0, 0);
    acc1 = __builtin_amdgcn_mfma_f32_16x16x32_bf16(av, bv1, acc1, 0, 0, 0);
    acc2 = __builtin_amdgcn_mfma_f32_16x16x32_bf16(av, bv2, acc2, 0, 0, 0);
    acc3 = __builtin_amdgcn_mfma_f32_16x16x32_bf16(av, bv3, acc3, 0, 0, 0);
    __syncthreads();
  }

  const int m0 = tm + (w << 4) + ((l >> 4) << 2);
  if (CBF) {
    ushort_t* Cp = (ushort_t*)Cbase + (size_t)b * sC;
    #pragma unroll
    for (int q = 0; q < 4; ++q) {
      size_t r = (size_t)(m0 + q) * 256;
      Cp[r + tn +  0 + brow0] = f2bf(acc0[q]);
      Cp[r + tn + 16 + brow0] = f2bf(acc1[q]);
      Cp[r + tn + 32 + brow0] = f2bf(acc2[q]);
      Cp[r + tn + 48 + brow0] = f2bf(acc3[q]);
    }
  } else {
    float* Cp = (float*)Cbase + (size_t)b * sC;
    #pragma unroll
    for (int q = 0; q < 4; ++q) {
      size_t r = (size_t)(m0 + q) * 256;
      Cp[r + tn +  0 + brow0] = acc0[q];
      Cp[r + tn + 16 + brow0] = acc1[q];
      Cp[r + tn + 32 + brow0] = acc2[q];
      Cp[r + tn + 48 + brow0] = acc3[q];
    }
  }
}

// ---------------- CP reconstruction loss ----------------
__global__ __launch_bounds__(256) void cp_kernel(const float* __restrict__ ti,
                                                 const ushort_t* __restrict__ Zb,
                                                 const float* __restrict__ cpA, const float* __restrict__ cpB,
                                                 const float* __restrict__ cpC, double* __restrict__ smallp)
{
  __shared__ float Bsh[256][4];
  __shared__ float Csh[256][4];
  __shared__ double red[256];
  int blk = blockIdx.x, t = threadIdx.x;
  int b = blk / 6, i = blk - b * 6;
  *(float4*)&Bsh[t][0] = *(const float4*)(cpB + ((size_t)b * 256 + t) * 4);
  *(float4*)&Csh[t][0] = *(const float4*)(cpC + ((size_t)b * 256 + t) * 4);
  float a0 = cpA[((size_t)b * 6 + i) * 4 + 0];
  float a1 = cpA[((size_t)b * 6 + i) * 4 + 1];
  float a2 = cpA[((size_t)b * 6 + i) * 4 + 2];
  float a3 = cpA[((size_t)b * 6 + i) * 4 + 3];
  __syncthreads();
  float c0 = Csh[t][0], c1 = Csh[t][1], c2 = Csh[t][2], c3 = Csh[t][3];
  double acc = 0;
  if (i < 4) {
    const float* T = ti + ((size_t)b * 6 + i) * 65536;
    #pragma unroll 4
    for (int j = 0; j < 256; ++j) {
      float recon = a0 * Bsh[j][0] * c0 + a1 * Bsh[j][1] * c1 + a2 * Bsh[j][2] * c2 + a3 * Bsh[j][3] * c3;
      float dv = recon - T[(size_t)j * 256 + t];
      acc += (double)dv * (double)dv;
    }
  } else {
    const ushort_t* T = Zb + (size_t)((i == 4) ? b : 64 + b) * 65536;
    #pragma unroll 4
    for (int j = 0; j < 256; ++j) {
      float recon = a0 * Bsh[j][0] * c0 + a1 * Bsh[j][1] * c1 + a2 * Bsh[j][2] * c2 + a3 * Bsh[j][3] * c3;
      float dv = recon - b2f(T[(size_t)j * 256 + t]);
      acc += (double)dv * (double)dv;
    }
  }
  acc = blockReduceSumD(acc, red, t);
  if (t == 0) atomicAdd(&smallp[0], acc);
}

// ---------------- S-matrix regularizers (16 blocks) ----------------
__global__ __launch_bounds__(256) void sreg_kernel(const float* __restrict__ S1, const float* __restrict__ S2,
                                                   const float* __restrict__ S3, const float* __restrict__ S4,
                                                   double* __restrict__ smallp)
{
  __shared__ double red[256];
  int t = threadIdx.x, blk = blockIdx.x;
  int s = blk >> 2, part = blk & 3;
  const float* S = (s == 0) ? S1 : (s == 1) ? S2 : (s == 2) ? S3 : S4;
  double tot = 0;
  int e0 = part * 16384;
  for (int e = e0 + t; e < e0 + 16384; e += 256) {
    int i = e >> 8, j = e & 255;
    float a = S[e];
    tot += (double)fabsf(a - (i == j ? 1.0f : 0.0f));
    if (i != j) tot += (double)fabsf(a);
  }
  tot = blockReduceSumD(tot, red, t);
  if (t == 0) atomicAdd(&smallp[1], -tot / 65536.0);
}

__global__ __launch_bounds__(256) void initk(double* smallp, double* diffP, double* offP, double* trP) {
  int t = threadIdx.x;
  if (t < 2) smallp[t] = 0.0;
  if (t < 128) { diffP[t] = 0.0; offP[t] = 0.0; trP[t] = 0.0; }
}

// ---------------- MLP heads -> logits ----------------
__global__ __launch_bounds__(64) void head_kernel(
    const float* __restrict__ seed_ic, const float* __restrict__ seed_sir,
    const float* __restrict__ seed_icc, const float* __restrict__ seed_sirc,
    const float* __restrict__ scalars,
    const float* __restrict__ cpA, const float* __restrict__ cpB, const float* __restrict__ cpC,
    const float* __restrict__ cpW1, const float* __restrict__ cpb1,
    const float* __restrict__ cpw2, const float* __restrict__ cpb2,
    const float* __restrict__ sW1, const float* __restrict__ sb1,
    const float* __restrict__ sw2, const float* __restrict__ sb2,
    const float* __restrict__ fW1, const float* __restrict__ fb1,
    const float* __restrict__ fw2, const float* __restrict__ fb2,
    float* __restrict__ out)
{
  int b = blockIdx.x, l = threadIdx.x;
  __shared__ float tri[4][3];
  __shared__ float cps[4], seds[4];
  __shared__ float hbuf[128];
  if (l < 4) {
    float s = 0;
    #pragma unroll
    for (int i = 0; i < 6; ++i) s += cpA[((size_t)b * 6 + i) * 4 + l];
    tri[l][0] = s * (1.0f / 6.0f);
  }
  float4 sB = make_float4(0,0,0,0), sC = make_float4(0,0,0,0);
  for (int j = l; j < 256; j += 64) {
    float4 v = *(const float4*)(cpB + ((size_t)b * 256 + j) * 4);
    sB.x += v.x; sB.y += v.y; sB.z += v.z; sB.w += v.w;
    float4 w = *(const float4*)(cpC + ((size_t)b * 256 + j) * 4);
    sC.x += w.x; sC.y += w.y; sC.z += w.z; sC.w += w.w;
  }
  #pragma unroll
  for (int off = 32; off > 0; off >>= 1) {
    sB.x += __shfl_down(sB.x, off); sB.y += __shfl_down(sB.y, off);
    sB.z += __shfl_down(sB.z, off); sB.w += __shfl_down(sB.w, off);
    sC.x += __shfl_down(sC.x, off); sC.y += __shfl_down(sC.y, off);
    sC.z += __shfl_down(sC.z, off); sC.w += __shfl_down(sC.w, off);
  }
  if (l == 0) {
    tri[0][1] = sB.x * (1.0f/256.0f); tri[1][1] = sB.y * (1.0f/256.0f);
    tri[2][1] = sB.z * (1.0f/256.0f); tri[3][1] = sB.w * (1.0f/256.0f);
    tri[0][2] = sC.x * (1.0f/256.0f); tri[1][2] = sC.y * (1.0f/256.0f);
    tri[2][2] = sC.z * (1.0f/256.0f); tri[3][2] = sC.w * (1.0f/256.0f);
  }
  __syncthreads();
  if (l < 4) {
    float s = 0;
    for (int hh = 0; hh < 32; ++hh) {
      float z = cpb1[l * 32 + hh];
      #pragma unroll
      for (int d = 0; d < 3; ++d) z += tri[l][d] * cpW1[(l * 32 + hh) * 3 + d];
      z = fmaxf(z, 0.0f);
      s += z * cpw2[l * 32 + hh];
    }
    cps[l] = s + cpb2[l];
  }
  for (int p = l; p < 128; p += 64) {
    int j = p >> 5, hh = p & 31;
    const float* sv = (j == 0) ? seed_ic : (j == 1) ? seed_sir : (j == 2) ? seed_icc : seed_sirc;
    sv += (size_t)b * 256;
    const float* wrow = sW1 + ((size_t)(j * 32 + hh)) * 256;
    float z = sb1[j * 32 + hh];
    for (int k = 0; k < 256; k += 4) {
      float4 a = *(const float4*)(sv + k);
      float4 w4 = *(const float4*)(wrow + k);
      z += a.x * w4.x + a.y * w4.y + a.z * w4.z + a.w * w4.w;
    }
    z = fmaxf(z, 0.0f);
    hbuf[p] = z * sw2[j * 32 + hh];
  }
  __syncthreads();
  if (l < 4) {
    float s = 0;
    #pragma unroll
    for (int hh = 0; hh < 32; ++hh) s += hbuf[l * 32 + hh];
    seds[l] = s + sb2[l];
  }
  __syncthreads();
  float av = 0.0f;
  if (l < 32) {
    float z = fb1[l];
    #pragma unroll
    for (int d = 0; d < 10; ++d) {
      float cd = (d < 4) ? cps[d] : (d < 8) ? seds[d - 4] : scalars[b * 2 + (d - 8)];
      z += cd * fW1[l * 10 + d];
    }
    z = fmaxf(z, 0.0f);
    av = z * fw2[l];
  }
  #pragma unroll
  for (int off = 16; off > 0; off >>= 1) av += __shfl_down(av, off);
  if (l == 0) out[b] = av + fb2[0];
}

// ---------------- fused symmetrize + Z reductions (diff/off/transform) ----------------
__global__ __launch_bounds__(256) void symm_reduce(const ushort_t* __restrict__ Zb,
                                                   const float* __restrict__ ti,
                                                   unsigned* __restrict__ Mp,
                                                   double* __restrict__ diffP, double* __restrict__ offP,
                                                   double* __restrict__ trP)
{
  __shared__ double dres[4][3];
  int mtx = blockIdx.x >> 4;
  int s = blockIdx.x & 15;
  int t = threadIdx.x;
  int lane = t & 63, wid = t >> 6;
  int z = mtx >> 6, b = mtx & 63;
  const ushort_t* M = Zb + (size_t)mtx * 65536;
  const float* Mr = ti + ((size_t)b * 6 + (z ? 5 : 4)) * 65536;
  int c0 = s << 4;
  uint4 r0 = *(const uint4*)(M + (size_t)t * 256 + c0);       // row side: M[t][c0..c0+7]
  uint4 r1 = *(const uint4*)(M + (size_t)t * 256 + c0 + 8);   // M[t][c0+8..c0+15]
  float rj[16] = {bflo(r0.x),bfhi(r0.x),bflo(r0.y),bfhi(r0.y),bflo(r0.z),bfhi(r0.z),bflo(r0.w),bfhi(r0.w),
                  bflo(r1.x),bfhi(r1.x),bflo(r1.y),bfhi(r1.y),bflo(r1.z),bfhi(r1.z),bflo(r1.w),bfhi(r1.w)};
  float cv[16];
  double pd = 0.0, po = 0.0, ptr = 0.0;
  #pragma unroll
  for (int q = 0; q < 16; ++q) {
    int row = c0 + q;
    float av = b2f(M[(size_t)row * 256 + t]);   // element (i=row, j=t), coalesced
    cv[q] = av;
    float mrv = Mr[(size_t)row * 256 + t];
    bool diag = (t == row);
    pd += (double)fabsf(av - (diag ? 1.0f : 0.0f));
    po += diag ? 0.0 : (double)fabsf(av);
    ptr += (double)fabsf(av - mrv);
  }
  unsigned* Mo = Mp + (size_t)mtx * 32768;
  #pragma unroll
  for (int p = 0; p < 8; ++p) {
    float m0 = 0.5f * (rj[2 * p]     + cv[2 * p]);
    float m1 = 0.5f * (rj[2 * p + 1] + cv[2 * p + 1]);
    Mo[(size_t)((s << 3) + p) * 256 + t] = (unsigned)f2bf(m0) | ((unsigned)f2bf(m1) << 16);
  }
  #pragma unroll
  for (int off = 32; off > 0; off >>= 1) {
    pd += __shfl_down(pd, off);
    po += __shfl_down(po, off);
    ptr += __shfl_down(ptr, off);
  }
  if (lane == 0) { dres[wid][0] = pd; dres[wid][1] = po; dres[wid][2] = ptr; }
  __syncthreads();
  if (t == 0) {
    atomicAdd(&diffP[mtx], dres[0][0] + dres[1][0] + dres[2][0] + dres[3][0]);
    atomicAdd(&offP[mtx],  dres[0][1] + dres[1][1] + dres[2][1] + dres[3][1]);
    atomicAdd(&trP[mtx],   dres[0][2] + dres[1][2] + dres[2][2] + dres[3][2]);
  }
}

// ---------------- Lanczos: 1024 threads (4 waves/SIMD), quarter-row partials ----------------
__global__ __launch_bounds__(1024, 1) void lanczos_kernel(const unsigned* __restrict__ Mp,
                                                          float* __restrict__ eig)
{
  __shared__ unsigned vpack[128];
  __shared__ float wtmp[4][256];
  __shared__ float red[16][3];
  __shared__ float red1[16];
  __shared__ float alpha[LM];
  __shared__ float betaArr[LM + 1];
  __shared__ float beta2arr[LM + 1];

  int t = threadIdx.x;
  int lane = t & 63, w16 = t >> 6;
  int r = t & 255, h = t >> 8;        // row, column-quarter
  int mtx = blockIdx.x;

  // load this thread's quarter-row: 32 packed bf16x2 dwords (cols 64h .. 64h+63)
  const unsigned* Mb = Mp + (size_t)mtx * 32768 + r;
  unsigned m[32];
  #pragma unroll
  for (int q = 0; q < 32; ++q) m[q] = Mb[(size_t)(h * 32 + q) * 256];

  // deterministic start vector (keyed by r; replicas across h identical)
  unsigned u0 = (unsigned)r * 1103515245u + 12345u;
  float r0v = 0.05f + (float)((u0 >> 9) & 0x7FFF) * (1.0f / 32768.0f);
  float nv = r0v * r0v;
  #pragma unroll
  for (int off = 32; off > 0; off >>= 1) nv += __shfl_down(nv, off);
  if (lane == 0) red1[w16] = nv;
  __syncthreads();
  float nrm2 = 0.f;
  #pragma unroll
  for (int k = 0; k < 16; ++k) nrm2 += red1[k];
  nrm2 *= 0.25f;
  float vt = r0v * rsqrtf(nrm2);
  float vprev = 0.0f;
  if (t < 256) {
    float vo = __shfl_down(vt, 1);
    if ((lane & 1) == 0) vpack[t >> 1] = (unsigned)f2bf(vt) | ((unsigned)f2bf(vo) << 16);
  }
  __syncthreads();

  const uint4* vp4 = (const uint4*)vpack;   // quarter h uses vp4[8h .. 8h+7]

  int meff = LM;
  for (int j = 0; j < LM; ++j) {
    float w0 = 0.f, w1 = 0.f, w2 = 0.f, w3 = 0.f;
    #pragma unroll
    for (int q = 0; q < 8; ++q) {
      uint4 vu = vp4[h * 8 + q];
      w0 = fmaf(bflo(m[4 * q + 0]), bflo(vu.x), w0); w0 = fmaf(bfhi(m[4 * q + 0]), bfhi(vu.x), w0);
      w1 = fmaf(bflo(m[4 * q + 1]), bflo(vu.y), w1); w1 = fmaf(bfhi(m[4 * q + 1]), bfhi(vu.y), w1);
      w2 = fmaf(bflo(m[4 * q + 2]), bflo(vu.z), w2); w2 = fmaf(bfhi(m[4 * q + 2]), bfhi(vu.z), w2);
      w3 = fmaf(bflo(m[4 * q + 3]), bflo(vu.w), w3); w3 = fmaf(bfhi(m[4 * q + 3]), bfhi(vu.w), w3);
    }
    wtmp[h][r] = (w0 + w1) + (w2 + w3);
    __syncthreads();                                         // B1
    float wt = wtmp[0][r] + wtmp[1][r] + wtmp[2][r] + wtmp[3][r];
    float s1 = wt * vt, s2 = wt * vprev, s3 = wt * wt;
    #pragma unroll
    for (int off = 32; off > 0; off >>= 1) {
      s1 += __shfl_down(s1, off);
      s2 += __shfl_down(s2, off);
      s3 += __shfl_down(s3, off);
    }
    if (lane == 0) { red[w16][0] = s1; red[w16][1] = s2; red[w16][2] = s3; }
    __syncthreads();                                         // B2
    float S1 = 0.f, S2 = 0.f, S3 = 0.f;
    #pragma unroll
    for (int k = 0; k < 16; ++k) { S1 += red[k][0]; S2 += red[k][1]; S3 += red[k][2]; }
    S1 *= 0.25f; S2 *= 0.25f; S3 *= 0.25f;
    float bn2 = S3 - S1 * S1 - S2 * S2;
    float bn = sqrtf(fmaxf(bn2, 1e-30f));
    if (t == 0) { alpha[j] = S1; betaArr[j + 1] = bn; beta2arr[j + 1] = bn * bn; }
    if (bn < 1e-6f * (fabsf(S1) + 1.0f)) { meff = j + 1; break; }
    float wn = (wt - S1 * vt - S2 * vprev) / bn;
    vprev = vt; vt = wn;
    if (t < 256) {
      float vo = __shfl_down(vt, 1);
      if ((lane & 1) == 0) vpack[t >> 1] = (unsigned)f2bf(vt) | ((unsigned)f2bf(vo) << 16);
    }
    __syncthreads();                                         // B3
  }
  __syncthreads();

  // ballot-parallel Sturm scan: waves 0..3 find eigenvalue index q=w16+1 (ascending)
  if (w16 < 4) {
    float lo = 1e30f, hi = -1e30f;
    for (int i = 0; i < meff; ++i) {
      float bl = (i > 0) ? betaArr[i] : 0.0f;
      float bu = (i + 1 < meff) ? betaArr[i + 1] : 0.0f;
      lo = fminf(lo, alpha[i] - bl - bu);
      hi = fmaxf(hi, alpha[i] + bl + bu);
    }
    int q = w16 + 1; if (q > meff - 1) q = meff - 1;
    #pragma unroll
    for (int rr = 0; rr < 3; ++rr) {
      float step = (hi - lo) * (1.0f / 65.0f);
      float mid = lo + step * (float)(lane + 1);
      int cnt = 0;
      float d = alpha[0] - mid;
      if (fabsf(d) < 1e-20f) d = -1e-20f;
      cnt += (d < 0.0f);
      for (int i = 1; i < meff; ++i) {
        d = alpha[i] - mid - beta2arr[i] / d;
        if (fabsf(d) < 1e-20f) d = -1e-20f;
        cnt += (d < 0.0f);
      }
      unsigned long long mask = __ballot(cnt >= q + 1);
      if (mask == 0ULL) {
        lo = lo + step * 64.0f;
      } else {
        int idx = __ffsll(mask) - 1;
        float nlo = lo + step * (float)idx;
        hi = lo + step * (float)(idx + 1);
        lo = nlo;
      }
    }
    if (lane == 0) eig[mtx * 4 + w16] = 0.5f * (lo + hi);
  }
}

// ---------------- final combine ----------------
__global__ __launch_bounds__(64) void combine_kernel(const float* __restrict__ eig,
    const double* __restrict__ diffP, const double* __restrict__ offP, const double* __restrict__ trP,
    const float* __restrict__ valo, const float* __restrict__ vali,
    const double* __restrict__ smallp, float* __restrict__ out)
{
  int l = threadIdx.x;
  float vo = valo[l], vi = vali[l];
  float el = 0, el2 = 0;
  #pragma unroll
  for (int e = 0; e < 4; ++e) {
    el  += fabsf(vo - eig[l * 4 + e]);
    el2 += fabsf(vi - eig[(64 + l) * 4 + e]);
  }
  float lo_ = el * 0.25f + 0.2f * (float)(diffP[l] * (1.0/65536.0)) - 0.1f * (float)(offP[l] * (1.0/65536.0));
  float li_ = el2 * 0.25f + 0.2f * (float)(diffP[64 + l] * (1.0/65536.0)) - 0.1f * (float)(offP[64 + l] * (1.0/65536.0));
  if (vo == 0.0f) lo_ = 0.0f;
  if (vi == 0.0f) li_ = 0.0f;
  float trb = (float)((trP[l] + trP[64 + l]) * (1.0/65536.0));
  #pragma unroll
  for (int off = 32; off > 0; off >>= 1) {
    lo_ += __shfl_down(lo_, off);
    li_ += __shfl_down(li_, off);
    trb += __shfl_down(trb, off);
  }
  if (l == 0) {
    out[64] = lo_ * (1.0f / 64.0f);
    out[65] = li_ * (1.0f / 64.0f);
    out[66] = (float)(smallp[0] / (64.0 * 6.0 * 65536.0));
    out[67] = 0.5f * (float)smallp[1] + 0.5f * (trb * (1.0f / 64.0f));
  }
}

extern "C" void kernel_launch(void* const* d_in, const int* in_sizes, int n_in,
                              void* d_out, int out_size, void* d_ws, size_t ws_size,
                              hipStream_t stream) {
  (void)in_sizes; (void)n_in; (void)out_size; (void)ws_size;
  const float* ti       = (const float*)d_in[0];
  const float* seed_ic  = (const float*)d_in[1];
  const float* seed_sir = (const float*)d_in[2];
  const float* seed_icc = (const float*)d_in[3];
  const float* seed_sirc= (const float*)d_in[4];
  const float* scalars  = (const float*)d_in[5];
  const float* valo     = (const float*)d_in[6];
  const float* vali     = (const float*)d_in[7];
  const float* S1p      = (const float*)d_in[8];
  const float* S2p      = (const float*)d_in[9];
  const float* S3p      = (const float*)d_in[10];
  const float* S4p      = (const float*)d_in[11];
  const float* cpA      = (const float*)d_in[12];
  const float* cpB      = (const float*)d_in[13];
  const float* cpC      = (const float*)d_in[14];
  const float* cpW1     = (const float*)d_in[15];
  const float* cpb1     = (const float*)d_in[16];
  const float* cpw2     = (const float*)d_in[17];
  const float* cpb2     = (const float*)d_in[18];
  const float* sW1      = (const float*)d_in[19];
  const float* sb1      = (const float*)d_in[20];
  const float* sw2      = (const float*)d_in[21];
  const float* sb2      = (const float*)d_in[22];
  const float* fW1      = (const float*)d_in[23];
  const float* fb1      = (const float*)d_in[24];
  const float* fw2      = (const float*)d_in[25];
  const float* fb2      = (const float*)d_in[26];

  char* ws = (char*)d_ws;
  ushort_t* RT     = (ushort_t*)(ws + OFF_RT);
  ushort_t* Q0     = (ushort_t*)(ws + OFF_Q0);
  ushort_t* Q1     = (ushort_t*)(ws + OFF_Q1);
  ushort_t* Zb     = (ushort_t*)(ws + OFF_ZB);
  unsigned* Mp     = (unsigned*)(ws + OFF_MP);
  ushort_t* ST     = (ushort_t*)(ws + OFF_ST);
  float*    eig    = (float*)(ws + OFF_EIG);
  double*   diffP  = (double*)(ws + OFF_DIFFP);
  double*   offP   = (double*)(ws + OFF_OFFP);
  double*   trP    = (double*)(ws + OFF_TRP);
  double*   smallp = (double*)(ws + OFF_SMALL);
  float*    out    = (float*)d_out;

  initk<<<1, 256, 0, stream>>>(smallp, diffP, offP, trP);
  tconv_s<<<dim3(8, 8, 4), 256, 0, stream>>>(S1p, S2p, S3p, S4p, ST);
  tconv_z<<<dim3(8, 8, 128), 256, 0, stream>>>(ti, RT, RT + 64 * 65536);

  dim3 gg(4, 4, 128), gb(256);
  const size_t S6 = 6ull * 65536ull, S1b = 65536ull;
  gemm_mfma<false, true, true ><<<gg, gb, 0, stream>>>(
      (const void*)(ti + 0 * 65536), (const void*)(ti + 2 * 65536), S6,
      (const void*)(ST + 0 * 65536), (const void*)(ST + 2 * 65536), 0,
      (void*)Q0, S1b);
  gemm_mfma<true, true, true ><<<gg, gb, 0, stream>>>(
      (const void*)Q0, (const void*)(Q0 + 64 * 65536), S1b,
      (const void*)RT, (const void*)(RT + 64 * 65536), S1b,
      (void*)Q1, S1b);
  gemm_mfma<true, true, true ><<<gg, gb, 0, stream>>>(
      (const void*)Q1, (const void*)(Q1 + 64 * 65536), S1b,
      (const void*)(ST + 1 * 65536), (const void*)(ST + 3 * 65536), 0,
      (void*)Q0, S1b);
  gemm_mfma<true, false, true ><<<gg, gb, 0, stream>>>(
      (const void*)Q0, (const void*)(Q0 + 64 * 65536), S1b,
      (const void*)(ti + 3 * 65536), (const void*)(ti + 1 * 65536), S6,
      (void*)Zb, S1b);

  cp_kernel<<<384, 256, 0, stream>>>(ti, Zb, cpA, cpB, cpC, smallp);
  sreg_kernel<<<16, 256, 0, stream>>>(S1p, S2p, S3p, S4p, smallp);
  head_kernel<<<64, 64, 0, stream>>>(seed_ic, seed_sir, seed_icc, seed_sirc, scalars,
                                     cpA, cpB, cpC, cpW1, cpb1, cpw2, cpb2,
                                     sW1, sb1, sw2, sb2, fW1, fb1, fw2, fb2, out);

  symm_reduce<<<2048, 256, 0, stream>>>(Zb, ti, Mp, diffP, offP, trP);
  lanczos_kernel<<<128, 1024, 0, stream>>>(Mp, eig);
  combine_kernel<<<1, 64, 0, stream>>>(eig, diffP, offP, trP, valo, vali, smallp, out);
}

// Round 9
// 211.604 us; speedup vs baseline: 6.5077x; 1.2726x over previous
//
#include <hip/hip_runtime.h>

#define LM 26

// ---------------- ws layout (bytes) ----------------
#define OFF_RT    0ull
#define OFF_MP    0ull
#define OFF_Q0    16777216ull
#define OFF_Q1    33554432ull
#define OFF_ZB    33554432ull
#define OFF_ST    50331648ull
#define OFF_EIG   (OFF_ST + 524288ull)
#define OFF_DIFFP (OFF_EIG + 4096ull)
#define OFF_OFFP  (OFF_DIFFP + 1024ull)
#define OFF_TRP   (OFF_OFFP + 1024ull)
#define OFF_SMALL (OFF_TRP + 1024ull)

typedef unsigned short ushort_t;
typedef short bf16x8 __attribute__((ext_vector_type(8)));
typedef float f32x4 __attribute__((ext_vector_type(4)));

static __device__ __forceinline__ ushort_t f2bf(float f) {
  unsigned u = __float_as_uint(f);
  unsigned r = (u + 0x7fffu + ((u >> 16) & 1u)) >> 16;
  return (ushort_t)r;
}
static __device__ __forceinline__ float bflo(unsigned u) { return __uint_as_float(u << 16); }
static __device__ __forceinline__ float bfhi(unsigned u) { return __uint_as_float(u & 0xffff0000u); }
static __device__ __forceinline__ float b2f(ushort_t u) { return __uint_as_float(((unsigned)u) << 16); }

// ---------------- transpose-convert: fp32 [R][C] -> bf16 [C][R]; block0 inits partials ----------------
__global__ __launch_bounds__(256) void tconv_s(const float* __restrict__ S1, const float* __restrict__ S2,
                                               const float* __restrict__ S3, const float* __restrict__ S4,
                                               ushort_t* __restrict__ dst,
                                               double* __restrict__ smallp, double* __restrict__ diffP,
                                               double* __restrict__ offP, double* __restrict__ trP)
{
  __shared__ float tl[32][33];
  if (blockIdx.x == 0 && blockIdx.y == 0 && blockIdx.z == 0) {
    int t = threadIdx.x;
    if (t < 2) smallp[t] = 0.0;
    if (t < 128) { diffP[t] = 0.0; offP[t] = 0.0; trP[t] = 0.0; }
  }
  int z = blockIdx.z;
  const float* S = (z == 0) ? S1 : (z == 1) ? S2 : (z == 2) ? S3 : S4;
  int r0 = blockIdx.y * 32, c0 = blockIdx.x * 32;
  int tx = threadIdx.x & 31, ty = threadIdx.x >> 5;
  #pragma unroll
  for (int k = 0; k < 4; ++k) tl[ty + 8 * k][tx] = S[(size_t)(r0 + ty + 8 * k) * 256 + c0 + tx];
  __syncthreads();
  ushort_t* d = dst + (size_t)z * 65536;
  #pragma unroll
  for (int k = 0; k < 4; ++k) d[(size_t)(c0 + ty + 8 * k) * 256 + r0 + tx] = f2bf(tl[tx][ty + 8 * k]);
}

__global__ __launch_bounds__(256) void tconv_z(const float* __restrict__ ti,
                                               ushort_t* __restrict__ d0, ushort_t* __restrict__ d1)
{
  __shared__ float tl[32][33];
  int z = blockIdx.z;
  int which = z >> 6, b = z & 63;
  const float* S = ti + ((size_t)b * 6 + 4 + which) * 65536;
  ushort_t* d = (which ? d1 : d0) + (size_t)b * 65536;
  int r0 = blockIdx.y * 32, c0 = blockIdx.x * 32;
  int tx = threadIdx.x & 31, ty = threadIdx.x >> 5;
  #pragma unroll
  for (int k = 0; k < 4; ++k) tl[ty + 8 * k][tx] = S[(size_t)(r0 + ty + 8 * k) * 256 + c0 + tx];
  __syncthreads();
  #pragma unroll
  for (int k = 0; k < 4; ++k) d[(size_t)(c0 + ty + 8 * k) * 256 + r0 + tx] = f2bf(tl[tx][ty + 8 * k]);
}

// ---------------- MFMA GEMM, 128 batches, split bases at b=64: C[b] = A @ Bstored^T ----------------
template<bool ABF, bool BBF, bool CBF>
__global__ __launch_bounds__(256) void gemm_mfma(
    const void* __restrict__ A0, const void* __restrict__ A1, size_t sA,
    const void* __restrict__ B0, const void* __restrict__ B1, size_t sB,
    void* __restrict__ Cbase, size_t sC)
{
  __shared__ ushort_t At[64][40];
  __shared__ ushort_t Bt[64][40];
  const int t = threadIdx.x;
  const int b = blockIdx.z;
  const int bl = (b < 64) ? b : b - 64;
  const void* Ab_ = (b < 64) ? A0 : A1;
  const void* Bb_ = (b < 64) ? B0 : B1;
  const int tm = blockIdx.y * 64, tn = blockIdx.x * 64;
  const int w = t >> 6, l = t & 63;
  const int srow = t >> 2, scg = (t & 3) << 3;
  const int arow = (w << 4) + (l & 15);
  const int kc = (l >> 4) << 3;
  const int brow0 = l & 15;

  f32x4 acc0 = {0.f,0.f,0.f,0.f}, acc1 = {0.f,0.f,0.f,0.f}, acc2 = {0.f,0.f,0.f,0.f}, acc3 = {0.f,0.f,0.f,0.f};

  for (int s8 = 0; s8 < 8; ++s8) {
    const int k0 = s8 << 5;
    if (ABF) {
      const ushort_t* Ap = (const ushort_t*)Ab_ + (size_t)bl * sA + (size_t)(tm + srow) * 256 + k0 + scg;
      *(uint4*)&At[srow][scg] = *(const uint4*)Ap;
    } else {
      const float* Ap = (const float*)Ab_ + (size_t)bl * sA + (size_t)(tm + srow) * 256 + k0 + scg;
      float4 f0 = *(const float4*)Ap, f1 = *(const float4*)(Ap + 4);
      uint4 u;
      u.x = (unsigned)f2bf(f0.x) | ((unsigned)f2bf(f0.y) << 16);
      u.y = (unsigned)f2bf(f0.z) | ((unsigned)f2bf(f0.w) << 16);
      u.z = (unsigned)f2bf(f1.x) | ((unsigned)f2bf(f1.y) << 16);
      u.w = (unsigned)f2bf(f1.z) | ((unsigned)f2bf(f1.w) << 16);
      *(uint4*)&At[srow][scg] = u;
    }
    if (BBF) {
      const ushort_t* Bp = (const ushort_t*)Bb_ + (size_t)bl * sB + (size_t)(tn + srow) * 256 + k0 + scg;
      *(uint4*)&Bt[srow][scg] = *(const uint4*)Bp;
    } else {
      const float* Bp = (const float*)Bb_ + (size_t)bl * sB + (size_t)(tn + srow) * 256 + k0 + scg;
      float4 f0 = *(const float4*)Bp, f1 = *(const float4*)(Bp + 4);
      uint4 u;
      u.x = (unsigned)f2bf(f0.x) | ((unsigned)f2bf(f0.y) << 16);
      u.y = (unsigned)f2bf(f0.z) | ((unsigned)f2bf(f0.w) << 16);
      u.z = (unsigned)f2bf(f1.x) | ((unsigned)f2bf(f1.y) << 16);
      u.w = (unsigned)f2bf(f1.z) | ((unsigned)f2bf(f1.w) << 16);
      *(uint4*)&Bt[srow][scg] = u;
    }
    __syncthreads();
    bf16x8 av  = *(const bf16x8*)&At[arow][kc];
    bf16x8 bv0 = *(const bf16x8*)&Bt[ 0 + brow0][kc];
    bf16x8 bv1 = *(const bf16x8*)&Bt[16 + brow0][kc];
    bf16x8 bv2 = *(const bf16x8*)&Bt[32 + brow0][kc];
    bf16x8 bv3 = *(const bf16x8*)&Bt[48 + brow0][kc];
    acc0 = __builtin_amdgcn_mfma_f32_16x16x32_bf16(av, bv0, acc0, 0, 0, 0);
    acc1 = __builtin_amdgcn_mfma_f32_16x16x32_bf16(av, bv1, acc1, 0, 0, 0);
    acc2 = __builtin_amdgcn_mfma_f32_16x16x32_bf16(av, bv2, acc2, 0, 0, 0);
    acc3 = __builtin_amdgcn_mfma_f32_16x16x32_bf16(av, bv3, acc3, 0, 0, 0);
    __syncthreads();
  }

  const int m0 = tm + (w << 4) + ((l >> 4) << 2);
  if (CBF) {
    ushort_t* Cp = (ushort_t*)Cbase + (size_t)b * sC;
    #pragma unroll
    for (int q = 0; q < 4; ++q) {
      size_t r = (size_t)(m0 + q) * 256;
      Cp[r + tn +  0 + brow0] = f2bf(acc0[q]);
      Cp[r + tn + 16 + brow0] = f2bf(acc1[q]);
      Cp[r + tn + 32 + brow0] = f2bf(acc2[q]);
      Cp[r + tn + 48 + brow0] = f2bf(acc3[q]);
    }
  } else {
    float* Cp = (float*)Cbase + (size_t)b * sC;
    #pragma unroll
    for (int q = 0; q < 4; ++q) {
      size_t r = (size_t)(m0 + q) * 256;
      Cp[r + tn +  0 + brow0] = acc0[q];
      Cp[r + tn + 16 + brow0] = acc1[q];
      Cp[r + tn + 32 + brow0] = acc2[q];
      Cp[r + tn + 48 + brow0] = acc3[q];
    }
  }
}

// ---------------- fused symmetrize + Z reductions (diff/off/transform) ----------------
__global__ __launch_bounds__(256) void symm_reduce(const ushort_t* __restrict__ Zb,
                                                   const float* __restrict__ ti,
                                                   unsigned* __restrict__ Mp,
                                                   double* __restrict__ diffP, double* __restrict__ offP,
                                                   double* __restrict__ trP)
{
  __shared__ double dres[4][3];
  int mtx = blockIdx.x >> 4;
  int s = blockIdx.x & 15;
  int t = threadIdx.x;
  int lane = t & 63, wid = t >> 6;
  int z = mtx >> 6, b = mtx & 63;
  const ushort_t* M = Zb + (size_t)mtx * 65536;
  const float* Mr = ti + ((size_t)b * 6 + (z ? 5 : 4)) * 65536;
  int c0 = s << 4;
  uint4 r0 = *(const uint4*)(M + (size_t)t * 256 + c0);
  uint4 r1 = *(const uint4*)(M + (size_t)t * 256 + c0 + 8);
  float rj[16] = {bflo(r0.x),bfhi(r0.x),bflo(r0.y),bfhi(r0.y),bflo(r0.z),bfhi(r0.z),bflo(r0.w),bfhi(r0.w),
                  bflo(r1.x),bfhi(r1.x),bflo(r1.y),bfhi(r1.y),bflo(r1.z),bfhi(r1.z),bflo(r1.w),bfhi(r1.w)};
  float cv[16];
  double pd = 0.0, po = 0.0, ptr = 0.0;
  #pragma unroll
  for (int q = 0; q < 16; ++q) {
    int row = c0 + q;
    float av = b2f(M[(size_t)row * 256 + t]);
    cv[q] = av;
    float mrv = Mr[(size_t)row * 256 + t];
    bool diag = (t == row);
    pd += (double)fabsf(av - (diag ? 1.0f : 0.0f));
    po += diag ? 0.0 : (double)fabsf(av);
    ptr += (double)fabsf(av - mrv);
  }
  unsigned* Mo = Mp + (size_t)mtx * 32768;
  #pragma unroll
  for (int p = 0; p < 8; ++p) {
    float m0 = 0.5f * (rj[2 * p]     + cv[2 * p]);
    float m1 = 0.5f * (rj[2 * p + 1] + cv[2 * p + 1]);
    Mo[(size_t)((s << 3) + p) * 256 + t] = (unsigned)f2bf(m0) | ((unsigned)f2bf(m1) << 16);
  }
  #pragma unroll
  for (int off = 32; off > 0; off >>= 1) {
    pd += __shfl_down(pd, off);
    po += __shfl_down(po, off);
    ptr += __shfl_down(ptr, off);
  }
  if (lane == 0) { dres[wid][0] = pd; dres[wid][1] = po; dres[wid][2] = ptr; }
  __syncthreads();
  if (t == 0) {
    atomicAdd(&diffP[mtx], dres[0][0] + dres[1][0] + dres[2][0] + dres[3][0]);
    atomicAdd(&offP[mtx],  dres[0][1] + dres[1][1] + dres[2][1] + dres[3][1]);
    atomicAdd(&trP[mtx],   dres[0][2] + dres[1][2] + dres[2][2] + dres[3][2]);
  }
}

// ================= MEGA KERNEL: lanczos (0..127) | cp (128..223) | sreg (224) | head (225..228) =================
struct LanSh {
  unsigned vpack[128];
  float wtmp[4][256];
  float red[16][2];
  float red1[16];
  float alpha[LM];
  float betaArr[LM + 1];
  float beta2arr[LM + 1];
};
struct CpSh { float Bsh[4][256][4]; float Csh[4][256][4]; double red[4][256]; };
struct SregSh { double red[4][256]; };
struct HeadSh { float tri[16][4][3]; float cps[16][4]; float seds[16][4]; float hbuf[16][128]; };
union MegaSh { LanSh lan; CpSh cp; SregSh sreg; HeadSh head; };

__global__ __launch_bounds__(1024, 1) void mega_kernel(
    const unsigned* __restrict__ Mp, float* __restrict__ eig,
    const float* __restrict__ ti, const ushort_t* __restrict__ Zb,
    const float* __restrict__ cpA, const float* __restrict__ cpB, const float* __restrict__ cpC,
    double* __restrict__ smallp,
    const float* __restrict__ S1, const float* __restrict__ S2,
    const float* __restrict__ S3, const float* __restrict__ S4,
    const float* __restrict__ seed_ic, const float* __restrict__ seed_sir,
    const float* __restrict__ seed_icc, const float* __restrict__ seed_sirc,
    const float* __restrict__ scalars,
    const float* __restrict__ cpW1, const float* __restrict__ cpb1,
    const float* __restrict__ cpw2, const float* __restrict__ cpb2,
    const float* __restrict__ sW1, const float* __restrict__ sb1,
    const float* __restrict__ sw2, const float* __restrict__ sb2,
    const float* __restrict__ fW1, const float* __restrict__ fb1,
    const float* __restrict__ fw2, const float* __restrict__ fb2,
    float* __restrict__ out)
{
  __shared__ MegaSh sh;
  const int bid = blockIdx.x;
  const int t = threadIdx.x;

  if (bid < 128) {
    // ---------------- Lanczos: 16 waves, quarter-row partials ----------------
    int lane = t & 63, w16 = t >> 6;
    int r = t & 255, h = t >> 8;
    int mtx = bid;
    const unsigned* Mb = Mp + (size_t)mtx * 32768 + r;
    unsigned m[32];
    #pragma unroll
    for (int q = 0; q < 32; ++q) m[q] = Mb[(size_t)(h * 32 + q) * 256];

    unsigned u0 = (unsigned)r * 1103515245u + 12345u;
    float r0v = 0.05f + (float)((u0 >> 9) & 0x7FFF) * (1.0f / 32768.0f);
    float nv = r0v * r0v;
    #pragma unroll
    for (int off = 32; off > 0; off >>= 1) nv += __shfl_down(nv, off);
    if (lane == 0) sh.lan.red1[w16] = nv;
    __syncthreads();
    float nrm2 = 0.f;
    #pragma unroll
    for (int k = 0; k < 16; ++k) nrm2 += sh.lan.red1[k];
    nrm2 *= 0.25f;
    float vt = r0v * rsqrtf(nrm2);
    float vprev = 0.0f;
    if (t < 256) {
      float vo = __shfl_down(vt, 1);
      if ((lane & 1) == 0) sh.lan.vpack[t >> 1] = (unsigned)f2bf(vt) | ((unsigned)f2bf(vo) << 16);
    }
    __syncthreads();

    const uint4* vp4 = (const uint4*)sh.lan.vpack;
    float beta_prev = 0.0f;
    int meff = LM;
    for (int j = 0; j < LM; ++j) {
      float w0 = 0.f, w1 = 0.f, w2 = 0.f, w3 = 0.f;
      #pragma unroll
      for (int q = 0; q < 8; ++q) {
        uint4 vu = vp4[h * 8 + q];
        w0 = fmaf(bflo(m[4 * q + 0]), bflo(vu.x), w0); w0 = fmaf(bfhi(m[4 * q + 0]), bfhi(vu.x), w0);
        w1 = fmaf(bflo(m[4 * q + 1]), bflo(vu.y), w1); w1 = fmaf(bfhi(m[4 * q + 1]), bfhi(vu.y), w1);
        w2 = fmaf(bflo(m[4 * q + 2]), bflo(vu.z), w2); w2 = fmaf(bfhi(m[4 * q + 2]), bfhi(vu.z), w2);
        w3 = fmaf(bflo(m[4 * q + 3]), bflo(vu.w), w3); w3 = fmaf(bfhi(m[4 * q + 3]), bfhi(vu.w), w3);
      }
      sh.lan.wtmp[h][r] = (w0 + w1) + (w2 + w3);
      __syncthreads();                                      // B1
      float wt = sh.lan.wtmp[0][r] + sh.lan.wtmp[1][r] + sh.lan.wtmp[2][r] + sh.lan.wtmp[3][r];
      float s1 = wt * vt, s3 = wt * wt;
      #pragma unroll
      for (int off = 32; off > 0; off >>= 1) {
        s1 += __shfl_down(s1, off);
        s3 += __shfl_down(s3, off);
      }
      if (lane == 0) { sh.lan.red[w16][0] = s1; sh.lan.red[w16][1] = s3; }
      __syncthreads();                                      // B2
      float S1v = 0.f, S3v = 0.f;
      #pragma unroll
      for (int k = 0; k < 16; ++k) { S1v += sh.lan.red[k][0]; S3v += sh.lan.red[k][1]; }
      S1v *= 0.25f; S3v *= 0.25f;
      float bn2 = S3v - S1v * S1v - beta_prev * beta_prev;
      float bn = sqrtf(fmaxf(bn2, 1e-30f));
      if (t == 0) { sh.lan.alpha[j] = S1v; sh.lan.betaArr[j + 1] = bn; sh.lan.beta2arr[j + 1] = bn * bn; }
      if (bn < 1e-6f * (fabsf(S1v) + 1.0f)) { meff = j + 1; break; }
      float wn = (wt - S1v * vt - beta_prev * vprev) / bn;
      vprev = vt; vt = wn; beta_prev = bn;
      if (t < 256) {
        float vo = __shfl_down(vt, 1);
        if ((lane & 1) == 0) sh.lan.vpack[t >> 1] = (unsigned)f2bf(vt) | ((unsigned)f2bf(vo) << 16);
      }
      __syncthreads();                                      // B3
    }
    __syncthreads();

    if (w16 < 4) {
      float lo = 1e30f, hi = -1e30f;
      for (int i = 0; i < meff; ++i) {
        float bl = (i > 0) ? sh.lan.betaArr[i] : 0.0f;
        float bu = (i + 1 < meff) ? sh.lan.betaArr[i + 1] : 0.0f;
        lo = fminf(lo, sh.lan.alpha[i] - bl - bu);
        hi = fmaxf(hi, sh.lan.alpha[i] + bl + bu);
      }
      int q = w16 + 1; if (q > meff - 1) q = meff - 1;
      #pragma unroll
      for (int rr = 0; rr < 3; ++rr) {
        float step = (hi - lo) * (1.0f / 65.0f);
        float mid = lo + step * (float)(lane + 1);
        int cnt = 0;
        float d = sh.lan.alpha[0] - mid;
        if (fabsf(d) < 1e-20f) d = -1e-20f;
        cnt += (d < 0.0f);
        for (int i = 1; i < meff; ++i) {
          d = sh.lan.alpha[i] - mid - sh.lan.beta2arr[i] / d;
          if (fabsf(d) < 1e-20f) d = -1e-20f;
          cnt += (d < 0.0f);
        }
        unsigned long long mask = __ballot(cnt >= q + 1);
        if (mask == 0ULL) {
          lo = lo + step * 64.0f;
        } else {
          int idx = __ffsll(mask) - 1;
          float nlo = lo + step * (float)idx;
          hi = lo + step * (float)(idx + 1);
          lo = nlo;
        }
      }
      if (lane == 0) eig[mtx * 4 + w16] = 0.5f * (lo + hi);
    }
  } else if (bid < 224) {
    // ---------------- CP loss: 4 groups of 256 threads ----------------
    int g = t >> 8, tid = t & 255;
    int unit = (bid - 128) * 4 + g;
    int b = unit / 6, i = unit - b * 6;
    float (*Bsh)[4] = sh.cp.Bsh[g];
    float (*Csh)[4] = sh.cp.Csh[g];
    double* red = sh.cp.red[g];
    *(float4*)&Bsh[tid][0] = *(const float4*)(cpB + ((size_t)b * 256 + tid) * 4);
    *(float4*)&Csh[tid][0] = *(const float4*)(cpC + ((size_t)b * 256 + tid) * 4);
    float a0 = cpA[((size_t)b * 6 + i) * 4 + 0];
    float a1 = cpA[((size_t)b * 6 + i) * 4 + 1];
    float a2 = cpA[((size_t)b * 6 + i) * 4 + 2];
    float a3 = cpA[((size_t)b * 6 + i) * 4 + 3];
    __syncthreads();
    float c0 = Csh[tid][0], c1 = Csh[tid][1], c2 = Csh[tid][2], c3 = Csh[tid][3];
    double acc = 0;
    if (i < 4) {
      const float* T = ti + ((size_t)b * 6 + i) * 65536;
      #pragma unroll 4
      for (int j = 0; j < 256; ++j) {
        float recon = a0 * Bsh[j][0] * c0 + a1 * Bsh[j][1] * c1 + a2 * Bsh[j][2] * c2 + a3 * Bsh[j][3] * c3;
        float dv = recon - T[(size_t)j * 256 + tid];
        acc += (double)dv * (double)dv;
      }
    } else {
      const ushort_t* T = Zb + (size_t)((i == 4) ? b : 64 + b) * 65536;
      #pragma unroll 4
      for (int j = 0; j < 256; ++j) {
        float recon = a0 * Bsh[j][0] * c0 + a1 * Bsh[j][1] * c1 + a2 * Bsh[j][2] * c2 + a3 * Bsh[j][3] * c3;
        float dv = recon - b2f(T[(size_t)j * 256 + tid]);
        acc += (double)dv * (double)dv;
      }
    }
    red[tid] = acc; __syncthreads();
    #pragma unroll
    for (int s = 128; s > 0; s >>= 1) { if (tid < s) red[tid] += red[tid + s]; __syncthreads(); }
    if (tid == 0) atomicAdd(&smallp[0], red[0]);
  } else if (bid == 224) {
    // ---------------- sreg: 4 groups, one S matrix each ----------------
    int g = t >> 8, tid = t & 255;
    const float* S = (g == 0) ? S1 : (g == 1) ? S2 : (g == 2) ? S3 : S4;
    double* red = sh.sreg.red[g];
    double tot = 0;
    for (int e = tid; e < 65536; e += 256) {
      int i = e >> 8, j = e & 255;
      float a = S[e];
      tot += (double)fabsf(a - (i == j ? 1.0f : 0.0f));
      if (i != j) tot += (double)fabsf(a);
    }
    red[tid] = tot; __syncthreads();
    #pragma unroll
    for (int s = 128; s > 0; s >>= 1) { if (tid < s) red[tid] += red[tid + s]; __syncthreads(); }
    if (tid == 0) atomicAdd(&smallp[1], -red[0] / 65536.0);
  } else {
    // ---------------- heads: 16 groups of 64 lanes, one batch each ----------------
    int g = t >> 6, l = t & 63;
    int b = (bid - 225) * 16 + g;
    float (*tri)[3] = sh.head.tri[g];
    float* cps = sh.head.cps[g];
    float* seds = sh.head.seds[g];
    float* hbuf = sh.head.hbuf[g];
    if (l < 4) {
      float s = 0;
      #pragma unroll
      for (int i = 0; i < 6; ++i) s += cpA[((size_t)b * 6 + i) * 4 + l];
      tri[l][0] = s * (1.0f / 6.0f);
    }
    float4 sB = make_float4(0,0,0,0), sC = make_float4(0,0,0,0);
    for (int j = l; j < 256; j += 64) {
      float4 v = *(const float4*)(cpB + ((size_t)b * 256 + j) * 4);
      sB.x += v.x; sB.y += v.y; sB.z += v.z; sB.w += v.w;
      float4 w = *(const float4*)(cpC + ((size_t)b * 256 + j) * 4);
      sC.x += w.x; sC.y += w.y; sC.z += w.z; sC.w += w.w;
    }
    #pragma unroll
    for (int off = 32; off > 0; off >>= 1) {
      sB.x += __shfl_down(sB.x, off); sB.y += __shfl_down(sB.y, off);
      sB.z += __shfl_down(sB.z, off); sB.w += __shfl_down(sB.w, off);
      sC.x += __shfl_down(sC.x, off); sC.y += __shfl_down(sC.y, off);
      sC.z += __shfl_down(sC.z, off); sC.w += __shfl_down(sC.w, off);
    }
    if (l == 0) {
      tri[0][1] = sB.x * (1.0f/256.0f); tri[1][1] = sB.y * (1.0f/256.0f);
      tri[2][1] = sB.z * (1.0f/256.0f); tri[3][1] = sB.w * (1.0f/256.0f);
      tri[0][2] = sC.x * (1.0f/256.0f); tri[1][2] = sC.y * (1.0f/256.0f);
      tri[2][2] = sC.z * (1.0f/256.0f); tri[3][2] = sC.w * (1.0f/256.0f);
    }
    __syncthreads();
    if (l < 4) {
      float s = 0;
      for (int hh = 0; hh < 32; ++hh) {
        float z = cpb1[l * 32 + hh];
        #pragma unroll
        for (int d = 0; d < 3; ++d) z += tri[l][d] * cpW1[(l * 32 + hh) * 3 + d];
        z = fmaxf(z, 0.0f);
        s += z * cpw2[l * 32 + hh];
      }
      cps[l] = s + cpb2[l];
    }
    for (int p = l; p < 128; p += 64) {
      int j = p >> 5, hh = p & 31;
      const float* sv = (j == 0) ? seed_ic : (j == 1) ? seed_sir : (j == 2) ? seed_icc : seed_sirc;
      sv += (size_t)b * 256;
      const float* wrow = sW1 + ((size_t)(j * 32 + hh)) * 256;
      float z = sb1[j * 32 + hh];
      for (int k = 0; k < 256; k += 4) {
        float4 a = *(const float4*)(sv + k);
        float4 w4 = *(const float4*)(wrow + k);
        z += a.x * w4.x + a.y * w4.y + a.z * w4.z + a.w * w4.w;
      }
      z = fmaxf(z, 0.0f);
      hbuf[p] = z * sw2[j * 32 + hh];
    }
    __syncthreads();
    if (l < 4) {
      float s = 0;
      #pragma unroll
      for (int hh = 0; hh < 32; ++hh) s += hbuf[l * 32 + hh];
      seds[l] = s + sb2[l];
    }
    __syncthreads();
    float av = 0.0f;
    if (l < 32) {
      float z = fb1[l];
      #pragma unroll
      for (int d = 0; d < 10; ++d) {
        float cd = (d < 4) ? cps[d] : (d < 8) ? seds[d - 4] : scalars[b * 2 + (d - 8)];
        z += cd * fW1[l * 10 + d];
      }
      z = fmaxf(z, 0.0f);
      av = z * fw2[l];
    }
    #pragma unroll
    for (int off = 16; off > 0; off >>= 1) av += __shfl_down(av, off);
    if (l == 0) out[b] = av + fb2[0];
  }
}

// ---------------- final combine ----------------
__global__ __launch_bounds__(64) void combine_kernel(const float* __restrict__ eig,
    const double* __restrict__ diffP, const double* __restrict__ offP, const double* __restrict__ trP,
    const float* __restrict__ valo, const float* __restrict__ vali,
    const double* __restrict__ smallp, float* __restrict__ out)
{
  int l = threadIdx.x;
  float vo = valo[l], vi = vali[l];
  float el = 0, el2 = 0;
  #pragma unroll
  for (int e = 0; e < 4; ++e) {
    el  += fabsf(vo - eig[l * 4 + e]);
    el2 += fabsf(vi - eig[(64 + l) * 4 + e]);
  }
  float lo_ = el * 0.25f + 0.2f * (float)(diffP[l] * (1.0/65536.0)) - 0.1f * (float)(offP[l] * (1.0/65536.0));
  float li_ = el2 * 0.25f + 0.2f * (float)(diffP[64 + l] * (1.0/65536.0)) - 0.1f * (float)(offP[64 + l] * (1.0/65536.0));
  if (vo == 0.0f) lo_ = 0.0f;
  if (vi == 0.0f) li_ = 0.0f;
  float trb = (float)((trP[l] + trP[64 + l]) * (1.0/65536.0));
  #pragma unroll
  for (int off = 32; off > 0; off >>= 1) {
    lo_ += __shfl_down(lo_, off);
    li_ += __shfl_down(li_, off);
    trb += __shfl_down(trb, off);
  }
  if (l == 0) {
    out[64] = lo_ * (1.0f / 64.0f);
    out[65] = li_ * (1.0f / 64.0f);
    out[66] = (float)(smallp[0] / (64.0 * 6.0 * 65536.0));
    out[67] = 0.5f * (float)smallp[1] + 0.5f * (trb * (1.0f / 64.0f));
  }
}

extern "C" void kernel_launch(void* const* d_in, const int* in_sizes, int n_in,
                              void* d_out, int out_size, void* d_ws, size_t ws_size,
                              hipStream_t stream) {
  (void)in_sizes; (void)n_in; (void)out_size; (void)ws_size;
  const float* ti       = (const float*)d_in[0];
  const float* seed_ic  = (const float*)d_in[1];
  const float* seed_sir = (const float*)d_in[2];
  const float* seed_icc = (const float*)d_in[3];
  const float* seed_sirc= (const float*)d_in[4];
  const float* scalars  = (const float*)d_in[5];
  const float* valo     = (const float*)d_in[6];
  const float* vali     = (const float*)d_in[7];
  const float* S1p      = (const float*)d_in[8];
  const float* S2p      = (const float*)d_in[9];
  const float* S3p      = (const float*)d_in[10];
  const float* S4p      = (const float*)d_in[11];
  const float* cpA      = (const float*)d_in[12];
  const float* cpB      = (const float*)d_in[13];
  const float* cpC      = (const float*)d_in[14];
  const float* cpW1     = (const float*)d_in[15];
  const float* cpb1     = (const float*)d_in[16];
  const float* cpw2     = (const float*)d_in[17];
  const float* cpb2     = (const float*)d_in[18];
  const float* sW1      = (const float*)d_in[19];
  const float* sb1      = (const float*)d_in[20];
  const float* sw2      = (const float*)d_in[21];
  const float* sb2      = (const float*)d_in[22];
  const float* fW1      = (const float*)d_in[23];
  const float* fb1      = (const float*)d_in[24];
  const float* fw2      = (const float*)d_in[25];
  const float* fb2      = (const float*)d_in[26];

  char* ws = (char*)d_ws;
  ushort_t* RT     = (ushort_t*)(ws + OFF_RT);
  ushort_t* Q0     = (ushort_t*)(ws + OFF_Q0);
  ushort_t* Q1     = (ushort_t*)(ws + OFF_Q1);
  ushort_t* Zb     = (ushort_t*)(ws + OFF_ZB);
  unsigned* Mp     = (unsigned*)(ws + OFF_MP);
  ushort_t* ST     = (ushort_t*)(ws + OFF_ST);
  float*    eig    = (float*)(ws + OFF_EIG);
  double*   diffP  = (double*)(ws + OFF_DIFFP);
  double*   offP   = (double*)(ws + OFF_OFFP);
  double*   trP    = (double*)(ws + OFF_TRP);
  double*   smallp = (double*)(ws + OFF_SMALL);
  float*    out    = (float*)d_out;

  tconv_s<<<dim3(8, 8, 4), 256, 0, stream>>>(S1p, S2p, S3p, S4p, ST, smallp, diffP, offP, trP);
  tconv_z<<<dim3(8, 8, 128), 256, 0, stream>>>(ti, RT, RT + 64 * 65536);

  dim3 gg(4, 4, 128), gb(256);
  const size_t S6 = 6ull * 65536ull, S1b = 65536ull;
  gemm_mfma<false, true, true ><<<gg, gb, 0, stream>>>(
      (const void*)(ti + 0 * 65536), (const void*)(ti + 2 * 65536), S6,
      (const void*)(ST + 0 * 65536), (const void*)(ST + 2 * 65536), 0,
      (void*)Q0, S1b);
  gemm_mfma<true, true, true ><<<gg, gb, 0, stream>>>(
      (const void*)Q0, (const void*)(Q0 + 64 * 65536), S1b,
      (const void*)RT, (const void*)(RT + 64 * 65536), S1b,
      (void*)Q1, S1b);
  gemm_mfma<true, true, true ><<<gg, gb, 0, stream>>>(
      (const void*)Q1, (const void*)(Q1 + 64 * 65536), S1b,
      (const void*)(ST + 1 * 65536), (const void*)(ST + 3 * 65536), 0,
      (void*)Q0, S1b);
  gemm_mfma<true, false, true ><<<gg, gb, 0, stream>>>(
      (const void*)Q0, (const void*)(Q0 + 64 * 65536), S1b,
      (const void*)(ti + 3 * 65536), (const void*)(ti + 1 * 65536), S6,
      (void*)Zb, S1b);

  symm_reduce<<<2048, 256, 0, stream>>>(Zb, ti, Mp, diffP, offP, trP);

  mega_kernel<<<229, 1024, 0, stream>>>(
      Mp, eig, ti, Zb, cpA, cpB, cpC, smallp,
      S1p, S2p, S3p, S4p,
      seed_ic, seed_sir, seed_icc, seed_sirc, scalars,
      cpW1, cpb1, cpw2, cpb2, sW1, sb1, sw2, sb2,
      fW1, fb1, fw2, fb2, out);

  combine_kernel<<<1, 64, 0, stream>>>(eig, diffP, offP, trP, valo, vali, smallp, out);
}

// Round 10
// 205.807 us; speedup vs baseline: 6.6910x; 1.0282x over previous
//
#include <hip/hip_runtime.h>
#include <hip/hip_fp16.h>

#define LM 26

// ---------------- ws layout (bytes) ----------------
#define OFF_MP    0ull                    // packed f16 sym matrices (16MB)
#define OFF_Q0    16777216ull
#define OFF_Q1    33554432ull
#define OFF_ZB    33554432ull             // Zb overwrites Q1 after G3
#define OFF_EIG   50331648ull
#define OFF_DIFFP (OFF_EIG + 4096ull)
#define OFF_OFFP  (OFF_DIFFP + 1024ull)
#define OFF_TRP   (OFF_OFFP + 1024ull)
#define OFF_SMALL (OFF_TRP + 1024ull)

typedef unsigned short ushort_t;
typedef short bf16x8 __attribute__((ext_vector_type(8)));
typedef float f32x4 __attribute__((ext_vector_type(4)));

static __device__ __forceinline__ ushort_t f2bf(float f) {
  unsigned u = __float_as_uint(f);
  unsigned r = (u + 0x7fffu + ((u >> 16) & 1u)) >> 16;
  return (ushort_t)r;
}
static __device__ __forceinline__ float bflo(unsigned u) { return __uint_as_float(u << 16); }
static __device__ __forceinline__ float bfhi(unsigned u) { return __uint_as_float(u & 0xffff0000u); }
static __device__ __forceinline__ float b2f(ushort_t u) { return __uint_as_float(((unsigned)u) << 16); }
static __device__ __forceinline__ __half2 u2h2(unsigned u) { __half2 r; *reinterpret_cast<unsigned*>(&r) = u; return r; }

// ---------------- MFMA GEMM, 128 batches, split bases at b=64 ----------------
// BMODE 1: B stored [N][K] fp32 (C = A @ Bstored^T). BMODE 2: B stored [K][N] fp32, transpose-staged (C = A @ B).
template<bool ABF, int BMODE, bool INITP>
__global__ __launch_bounds__(256) void gemm_mfma(
    const void* __restrict__ A0, const void* __restrict__ A1, size_t sA,
    const void* __restrict__ B0, const void* __restrict__ B1, size_t sB,
    void* __restrict__ Cbase, size_t sC,
    double* __restrict__ smallp, double* __restrict__ diffP,
    double* __restrict__ offP, double* __restrict__ trP)
{
  __shared__ ushort_t At[64][40];
  __shared__ ushort_t Bt[64][40];
  const int t = threadIdx.x;
  if (INITP && blockIdx.x == 0 && blockIdx.y == 0 && blockIdx.z == 0) {
    if (t < 2) smallp[t] = 0.0;
    if (t < 128) { diffP[t] = 0.0; offP[t] = 0.0; trP[t] = 0.0; }
  }
  const int b = blockIdx.z;
  const int bl = (b < 64) ? b : b - 64;
  const void* Ab_ = (b < 64) ? A0 : A1;
  const void* Bb_ = (b < 64) ? B0 : B1;
  const int tm = blockIdx.y * 64, tn = blockIdx.x * 64;
  const int w = t >> 6, l = t & 63;
  const int srow = t >> 2, scg = (t & 3) << 3;
  const int arow = (w << 4) + (l & 15);
  const int kc = (l >> 4) << 3;
  const int brow0 = l & 15;

  f32x4 acc0 = {0.f,0.f,0.f,0.f}, acc1 = {0.f,0.f,0.f,0.f}, acc2 = {0.f,0.f,0.f,0.f}, acc3 = {0.f,0.f,0.f,0.f};

  for (int s8 = 0; s8 < 8; ++s8) {
    const int k0 = s8 << 5;
    if (ABF) {
      const ushort_t* Ap = (const ushort_t*)Ab_ + (size_t)bl * sA + (size_t)(tm + srow) * 256 + k0 + scg;
      *(uint4*)&At[srow][scg] = *(const uint4*)Ap;
    } else {
      const float* Ap = (const float*)Ab_ + (size_t)bl * sA + (size_t)(tm + srow) * 256 + k0 + scg;
      float4 f0 = *(const float4*)Ap, f1 = *(const float4*)(Ap + 4);
      uint4 u;
      u.x = (unsigned)f2bf(f0.x) | ((unsigned)f2bf(f0.y) << 16);
      u.y = (unsigned)f2bf(f0.z) | ((unsigned)f2bf(f0.w) << 16);
      u.z = (unsigned)f2bf(f1.x) | ((unsigned)f2bf(f1.y) << 16);
      u.w = (unsigned)f2bf(f1.z) | ((unsigned)f2bf(f1.w) << 16);
      *(uint4*)&At[srow][scg] = u;
    }
    if (BMODE == 1) {
      const float* Bp = (const float*)Bb_ + (size_t)bl * sB + (size_t)(tn + srow) * 256 + k0 + scg;
      float4 f0 = *(const float4*)Bp, f1 = *(const float4*)(Bp + 4);
      uint4 u;
      u.x = (unsigned)f2bf(f0.x) | ((unsigned)f2bf(f0.y) << 16);
      u.y = (unsigned)f2bf(f0.z) | ((unsigned)f2bf(f0.w) << 16);
      u.z = (unsigned)f2bf(f1.x) | ((unsigned)f2bf(f1.y) << 16);
      u.w = (unsigned)f2bf(f1.z) | ((unsigned)f2bf(f1.w) << 16);
      *(uint4*)&Bt[srow][scg] = u;
    } else {
      // BMODE == 2: stage B^T — Bt[n][k] = toBF(B[k0+k][tn+n])
      const int kk = t >> 3, c8 = t & 7;
      const float* Bp = (const float*)Bb_ + (size_t)bl * sB + (size_t)(k0 + kk) * 256 + tn;
      float4 f0 = *(const float4*)(Bp + c8 * 4);
      float4 f1 = *(const float4*)(Bp + 32 + c8 * 4);
      int n0 = c8 << 2;
      Bt[n0 + 0][kk] = f2bf(f0.x); Bt[n0 + 1][kk] = f2bf(f0.y);
      Bt[n0 + 2][kk] = f2bf(f0.z); Bt[n0 + 3][kk] = f2bf(f0.w);
      Bt[32 + n0 + 0][kk] = f2bf(f1.x); Bt[32 + n0 + 1][kk] = f2bf(f1.y);
      Bt[32 + n0 + 2][kk] = f2bf(f1.z); Bt[32 + n0 + 3][kk] = f2bf(f1.w);
    }
    __syncthreads();
    bf16x8 av  = *(const bf16x8*)&At[arow][kc];
    bf16x8 bv0 = *(const bf16x8*)&Bt[ 0 + brow0][kc];
    bf16x8 bv1 = *(const bf16x8*)&Bt[16 + brow0][kc];
    bf16x8 bv2 = *(const bf16x8*)&Bt[32 + brow0][kc];
    bf16x8 bv3 = *(const bf16x8*)&Bt[48 + brow0][kc];
    acc0 = __builtin_amdgcn_mfma_f32_16x16x32_bf16(av, bv0, acc0, 0, 0, 0);
    acc1 = __builtin_amdgcn_mfma_f32_16x16x32_bf16(av, bv1, acc1, 0, 0, 0);
    acc2 = __builtin_amdgcn_mfma_f32_16x16x32_bf16(av, bv2, acc2, 0, 0, 0);
    acc3 = __builtin_amdgcn_mfma_f32_16x16x32_bf16(av, bv3, acc3, 0, 0, 0);
    __syncthreads();
  }

  const int m0 = tm + (w << 4) + ((l >> 4) << 2);
  ushort_t* Cp = (ushort_t*)Cbase + (size_t)b * sC;
  #pragma unroll
  for (int q = 0; q < 4; ++q) {
    size_t r = (size_t)(m0 + q) * 256;
    Cp[r + tn +  0 + brow0] = f2bf(acc0[q]);
    Cp[r + tn + 16 + brow0] = f2bf(acc1[q]);
    Cp[r + tn + 32 + brow0] = f2bf(acc2[q]);
    Cp[r + tn + 48 + brow0] = f2bf(acc3[q]);
  }
}

// ---------------- fused symmetrize (-> packed f16, x1/64) + Z reductions ----------------
__global__ __launch_bounds__(256) void symm_reduce(const ushort_t* __restrict__ Zb,
                                                   const float* __restrict__ ti,
                                                   unsigned* __restrict__ Mp,
                                                   double* __restrict__ diffP, double* __restrict__ offP,
                                                   double* __restrict__ trP)
{
  __shared__ double dres[4][3];
  int mtx = blockIdx.x >> 4;
  int s = blockIdx.x & 15;
  int t = threadIdx.x;
  int lane = t & 63, wid = t >> 6;
  int z = mtx >> 6, b = mtx & 63;
  const ushort_t* M = Zb + (size_t)mtx * 65536;
  const float* Mr = ti + ((size_t)b * 6 + (z ? 5 : 4)) * 65536;
  int c0 = s << 4;
  uint4 r0 = *(const uint4*)(M + (size_t)t * 256 + c0);
  uint4 r1 = *(const uint4*)(M + (size_t)t * 256 + c0 + 8);
  float rj[16] = {bflo(r0.x),bfhi(r0.x),bflo(r0.y),bfhi(r0.y),bflo(r0.z),bfhi(r0.z),bflo(r0.w),bfhi(r0.w),
                  bflo(r1.x),bfhi(r1.x),bflo(r1.y),bfhi(r1.y),bflo(r1.z),bfhi(r1.z),bflo(r1.w),bfhi(r1.w)};
  float cv[16];
  double pd = 0.0, po = 0.0, ptr = 0.0;
  #pragma unroll
  for (int q = 0; q < 16; ++q) {
    int row = c0 + q;
    float av = b2f(M[(size_t)row * 256 + t]);
    cv[q] = av;
    float mrv = Mr[(size_t)row * 256 + t];
    bool diag = (t == row);
    pd += (double)fabsf(av - (diag ? 1.0f : 0.0f));
    po += diag ? 0.0 : (double)fabsf(av);
    ptr += (double)fabsf(av - mrv);
  }
  unsigned* Mo = Mp + (size_t)mtx * 32768;
  #pragma unroll
  for (int p = 0; p < 8; ++p) {
    float m0 = 0.5f * (rj[2 * p]     + cv[2 * p]) * 0.015625f;
    float m1 = 0.5f * (rj[2 * p + 1] + cv[2 * p + 1]) * 0.015625f;
    unsigned u = (unsigned)__half_as_ushort(__float2half_rn(m0)) |
                 ((unsigned)__half_as_ushort(__float2half_rn(m1)) << 16);
    Mo[(size_t)((s << 3) + p) * 256 + t] = u;
  }
  #pragma unroll
  for (int off = 32; off > 0; off >>= 1) {
    pd += __shfl_down(pd, off);
    po += __shfl_down(po, off);
    ptr += __shfl_down(ptr, off);
  }
  if (lane == 0) { dres[wid][0] = pd; dres[wid][1] = po; dres[wid][2] = ptr; }
  __syncthreads();
  if (t == 0) {
    atomicAdd(&diffP[mtx], dres[0][0] + dres[1][0] + dres[2][0] + dres[3][0]);
    atomicAdd(&offP[mtx],  dres[0][1] + dres[1][1] + dres[2][1] + dres[3][1]);
    atomicAdd(&trP[mtx],   dres[0][2] + dres[1][2] + dres[2][2] + dres[3][2]);
  }
}

// ================= MEGA KERNEL: lanczos (0..127) | cp (128..223) | sreg (224) | head (225..228) =================
struct LanSh {
  unsigned vpack[128];
  float wtmp[4][256];
  float red[16][2];
  float red1[16];
  float alpha[LM];
  float betaArr[LM + 1];
  float beta2arr[LM + 1];
};
struct CpSh { float Bsh[4][256][4]; float Csh[4][256][4]; double red[4][256]; };
struct SregSh { double red[4][256]; };
struct HeadSh { float tri[16][4][3]; float cps[16][4]; float seds[16][4]; float hbuf[16][128]; };
union MegaSh { LanSh lan; CpSh cp; SregSh sreg; HeadSh head; };

__global__ __launch_bounds__(1024, 1) void mega_kernel(
    const unsigned* __restrict__ Mp, float* __restrict__ eig,
    const float* __restrict__ ti, const ushort_t* __restrict__ Zb,
    const float* __restrict__ cpA, const float* __restrict__ cpB, const float* __restrict__ cpC,
    double* __restrict__ smallp,
    const float* __restrict__ S1, const float* __restrict__ S2,
    const float* __restrict__ S3, const float* __restrict__ S4,
    const float* __restrict__ seed_ic, const float* __restrict__ seed_sir,
    const float* __restrict__ seed_icc, const float* __restrict__ seed_sirc,
    const float* __restrict__ scalars,
    const float* __restrict__ cpW1, const float* __restrict__ cpb1,
    const float* __restrict__ cpw2, const float* __restrict__ cpb2,
    const float* __restrict__ sW1, const float* __restrict__ sb1,
    const float* __restrict__ sw2, const float* __restrict__ sb2,
    const float* __restrict__ fW1, const float* __restrict__ fb1,
    const float* __restrict__ fw2, const float* __restrict__ fb2,
    float* __restrict__ out)
{
  __shared__ MegaSh sh;
  const int bid = blockIdx.x;
  const int t = threadIdx.x;

  if (bid < 128) {
    // ---------------- Lanczos on M/64 (f16 packed), eig x64 at the end ----------------
    int lane = t & 63, w16 = t >> 6;
    int r = t & 255, h = t >> 8;
    int mtx = bid;
    const unsigned* Mb = Mp + (size_t)mtx * 32768 + r;
    unsigned m[32];
    #pragma unroll
    for (int q = 0; q < 32; ++q) m[q] = Mb[(size_t)(h * 32 + q) * 256];

    unsigned u0 = (unsigned)r * 1103515245u + 12345u;
    float r0v = 0.05f + (float)((u0 >> 9) & 0x7FFF) * (1.0f / 32768.0f);
    float nv = r0v * r0v;
    #pragma unroll
    for (int off = 32; off > 0; off >>= 1) nv += __shfl_down(nv, off);
    if (lane == 0) sh.lan.red1[w16] = nv;
    __syncthreads();
    float nrm2 = 0.f;
    #pragma unroll
    for (int k = 0; k < 16; ++k) nrm2 += sh.lan.red1[k];
    nrm2 *= 0.25f;
    float vt = r0v * rsqrtf(nrm2);
    float vprev = 0.0f;
    if (t < 256) {
      float vo = __shfl_down(vt, 1);
      if ((lane & 1) == 0)
        sh.lan.vpack[t >> 1] = (unsigned)__half_as_ushort(__float2half_rn(vt)) |
                               ((unsigned)__half_as_ushort(__float2half_rn(vo)) << 16);
    }
    __syncthreads();

    const uint4* vp4 = (const uint4*)sh.lan.vpack;
    float beta_prev = 0.0f;
    int meff = LM;
    for (int j = 0; j < LM; ++j) {
      __half2 h0 = u2h2(0u), h1 = u2h2(0u), h2 = u2h2(0u), h3 = u2h2(0u);
      #pragma unroll
      for (int q = 0; q < 8; ++q) {
        uint4 vu = vp4[h * 8 + q];
        h0 = __hfma2(u2h2(m[4 * q + 0]), u2h2(vu.x), h0);
        h1 = __hfma2(u2h2(m[4 * q + 1]), u2h2(vu.y), h1);
        h2 = __hfma2(u2h2(m[4 * q + 2]), u2h2(vu.z), h2);
        h3 = __hfma2(u2h2(m[4 * q + 3]), u2h2(vu.w), h3);
      }
      float2 f0 = __half22float2(h0), f1 = __half22float2(h1);
      float2 f2 = __half22float2(h2), f3 = __half22float2(h3);
      sh.lan.wtmp[h][r] = ((f0.x + f0.y) + (f1.x + f1.y)) + ((f2.x + f2.y) + (f3.x + f3.y));
      __syncthreads();                                      // B1
      float wt = sh.lan.wtmp[0][r] + sh.lan.wtmp[1][r] + sh.lan.wtmp[2][r] + sh.lan.wtmp[3][r];
      float s1 = wt * vt, s3 = wt * wt;
      #pragma unroll
      for (int off = 32; off > 0; off >>= 1) {
        s1 += __shfl_down(s1, off);
        s3 += __shfl_down(s3, off);
      }
      if (lane == 0) { sh.lan.red[w16][0] = s1; sh.lan.red[w16][1] = s3; }
      __syncthreads();                                      // B2
      float S1v = 0.f, S3v = 0.f;
      #pragma unroll
      for (int k = 0; k < 16; ++k) { S1v += sh.lan.red[k][0]; S3v += sh.lan.red[k][1]; }
      S1v *= 0.25f; S3v *= 0.25f;
      float bn2 = S3v - S1v * S1v - beta_prev * beta_prev;
      float bn = sqrtf(fmaxf(bn2, 1e-30f));
      if (t == 0) { sh.lan.alpha[j] = S1v; sh.lan.betaArr[j + 1] = bn; sh.lan.beta2arr[j + 1] = bn * bn; }
      if (bn < 1e-6f * (fabsf(S1v) + 1.0f)) { meff = j + 1; break; }
      float wn = (wt - S1v * vt - beta_prev * vprev) / bn;
      vprev = vt; vt = wn; beta_prev = bn;
      if (t < 256) {
        float vo = __shfl_down(vt, 1);
        if ((lane & 1) == 0)
          sh.lan.vpack[t >> 1] = (unsigned)__half_as_ushort(__float2half_rn(vt)) |
                                 ((unsigned)__half_as_ushort(__float2half_rn(vo)) << 16);
      }
      __syncthreads();                                      // B3
    }
    __syncthreads();

    if (w16 < 4) {
      float lo = 1e30f, hi = -1e30f;
      for (int i = 0; i < meff; ++i) {
        float bl = (i > 0) ? sh.lan.betaArr[i] : 0.0f;
        float bu = (i + 1 < meff) ? sh.lan.betaArr[i + 1] : 0.0f;
        lo = fminf(lo, sh.lan.alpha[i] - bl - bu);
        hi = fmaxf(hi, sh.lan.alpha[i] + bl + bu);
      }
      int q = w16 + 1; if (q > meff - 1) q = meff - 1;
      #pragma unroll
      for (int rr = 0; rr < 3; ++rr) {
        float step = (hi - lo) * (1.0f / 65.0f);
        float mid = lo + step * (float)(lane + 1);
        int cnt = 0;
        float d = sh.lan.alpha[0] - mid;
        if (fabsf(d) < 1e-20f) d = -1e-20f;
        cnt += (d < 0.0f);
        for (int i = 1; i < meff; ++i) {
          d = sh.lan.alpha[i] - mid - sh.lan.beta2arr[i] / d;
          if (fabsf(d) < 1e-20f) d = -1e-20f;
          cnt += (d < 0.0f);
        }
        unsigned long long mask = __ballot(cnt >= q + 1);
        if (mask == 0ULL) {
          lo = lo + step * 64.0f;
        } else {
          int idx = __ffsll(mask) - 1;
          float nlo = lo + step * (float)idx;
          hi = lo + step * (float)(idx + 1);
          lo = nlo;
        }
      }
      if (lane == 0) eig[mtx * 4 + w16] = 32.0f * (lo + hi);   // 0.5*(lo+hi) * 64
    }
  } else if (bid < 224) {
    // ---------------- CP loss: 4 groups of 256 threads ----------------
    int g = t >> 8, tid = t & 255;
    int unit = (bid - 128) * 4 + g;
    int b = unit / 6, i = unit - b * 6;
    float (*Bsh)[4] = sh.cp.Bsh[g];
    float (*Csh)[4] = sh.cp.Csh[g];
    double* red = sh.cp.red[g];
    *(float4*)&Bsh[tid][0] = *(const float4*)(cpB + ((size_t)b * 256 + tid) * 4);
    *(float4*)&Csh[tid][0] = *(const float4*)(cpC + ((size_t)b * 256 + tid) * 4);
    float a0 = cpA[((size_t)b * 6 + i) * 4 + 0];
    float a1 = cpA[((size_t)b * 6 + i) * 4 + 1];
    float a2 = cpA[((size_t)b * 6 + i) * 4 + 2];
    float a3 = cpA[((size_t)b * 6 + i) * 4 + 3];
    __syncthreads();
    float c0 = Csh[tid][0], c1 = Csh[tid][1], c2 = Csh[tid][2], c3 = Csh[tid][3];
    double acc = 0;
    if (i < 4) {
      const float* T = ti + ((size_t)b * 6 + i) * 65536;
      #pragma unroll 4
      for (int j = 0; j < 256; ++j) {
        float recon = a0 * Bsh[j][0] * c0 + a1 * Bsh[j][1] * c1 + a2 * Bsh[j][2] * c2 + a3 * Bsh[j][3] * c3;
        float dv = recon - T[(size_t)j * 256 + tid];
        acc += (double)dv * (double)dv;
      }
    } else {
      const ushort_t* T = Zb + (size_t)((i == 4) ? b : 64 + b) * 65536;
      #pragma unroll 4
      for (int j = 0; j < 256; ++j) {
        float recon = a0 * Bsh[j][0] * c0 + a1 * Bsh[j][1] * c1 + a2 * Bsh[j][2] * c2 + a3 * Bsh[j][3] * c3;
        float dv = recon - b2f(T[(size_t)j * 256 + tid]);
        acc += (double)dv * (double)dv;
      }
    }
    red[tid] = acc; __syncthreads();
    #pragma unroll
    for (int s = 128; s > 0; s >>= 1) { if (tid < s) red[tid] += red[tid + s]; __syncthreads(); }
    if (tid == 0) atomicAdd(&smallp[0], red[0]);
  } else if (bid == 224) {
    // ---------------- sreg: 4 groups, one S matrix each ----------------
    int g = t >> 8, tid = t & 255;
    const float* S = (g == 0) ? S1 : (g == 1) ? S2 : (g == 2) ? S3 : S4;
    double* red = sh.sreg.red[g];
    double tot = 0;
    for (int e = tid; e < 65536; e += 256) {
      int i = e >> 8, j = e & 255;
      float a = S[e];
      tot += (double)fabsf(a - (i == j ? 1.0f : 0.0f));
      if (i != j) tot += (double)fabsf(a);
    }
    red[tid] = tot; __syncthreads();
    #pragma unroll
    for (int s = 128; s > 0; s >>= 1) { if (tid < s) red[tid] += red[tid + s]; __syncthreads(); }
    if (tid == 0) atomicAdd(&smallp[1], -red[0] / 65536.0);
  } else {
    // ---------------- heads: 16 groups of 64 lanes, one batch each ----------------
    int g = t >> 6, l = t & 63;
    int b = (bid - 225) * 16 + g;
    float (*tri)[3] = sh.head.tri[g];
    float* cps = sh.head.cps[g];
    float* seds = sh.head.seds[g];
    float* hbuf = sh.head.hbuf[g];
    if (l < 4) {
      float s = 0;
      #pragma unroll
      for (int i = 0; i < 6; ++i) s += cpA[((size_t)b * 6 + i) * 4 + l];
      tri[l][0] = s * (1.0f / 6.0f);
    }
    float4 sB = make_float4(0,0,0,0), sC = make_float4(0,0,0,0);
    for (int j = l; j < 256; j += 64) {
      float4 v = *(const float4*)(cpB + ((size_t)b * 256 + j) * 4);
      sB.x += v.x; sB.y += v.y; sB.z += v.z; sB.w += v.w;
      float4 w = *(const float4*)(cpC + ((size_t)b * 256 + j) * 4);
      sC.x += w.x; sC.y += w.y; sC.z += w.z; sC.w += w.w;
    }
    #pragma unroll
    for (int off = 32; off > 0; off >>= 1) {
      sB.x += __shfl_down(sB.x, off); sB.y += __shfl_down(sB.y, off);
      sB.z += __shfl_down(sB.z, off); sB.w += __shfl_down(sB.w, off);
      sC.x += __shfl_down(sC.x, off); sC.y += __shfl_down(sC.y, off);
      sC.z += __shfl_down(sC.z, off); sC.w += __shfl_down(sC.w, off);
    }
    if (l == 0) {
      tri[0][1] = sB.x * (1.0f/256.0f); tri[1][1] = sB.y * (1.0f/256.0f);
      tri[2][1] = sB.z * (1.0f/256.0f); tri[3][1] = sB.w * (1.0f/256.0f);
      tri[0][2] = sC.x * (1.0f/256.0f); tri[1][2] = sC.y * (1.0f/256.0f);
      tri[2][2] = sC.z * (1.0f/256.0f); tri[3][2] = sC.w * (1.0f/256.0f);
    }
    __syncthreads();
    if (l < 4) {
      float s = 0;
      for (int hh = 0; hh < 32; ++hh) {
        float z = cpb1[l * 32 + hh];
        #pragma unroll
        for (int d = 0; d < 3; ++d) z += tri[l][d] * cpW1[(l * 32 + hh) * 3 + d];
        z = fmaxf(z, 0.0f);
        s += z * cpw2[l * 32 + hh];
      }
      cps[l] = s + cpb2[l];
    }
    for (int p = l; p < 128; p += 64) {
      int j = p >> 5, hh = p & 31;
      const float* sv = (j == 0) ? seed_ic : (j == 1) ? seed_sir : (j == 2) ? seed_icc : seed_sirc;
      sv += (size_t)b * 256;
      const float* wrow = sW1 + ((size_t)(j * 32 + hh)) * 256;
      float z = sb1[j * 32 + hh];
      for (int k = 0; k < 256; k += 4) {
        float4 a = *(const float4*)(sv + k);
        float4 w4 = *(const float4*)(wrow + k);
        z += a.x * w4.x + a.y * w4.y + a.z * w4.z + a.w * w4.w;
      }
      z = fmaxf(z, 0.0f);
      hbuf[p] = z * sw2[j * 32 + hh];
    }
    __syncthreads();
    if (l < 4) {
      float s = 0;
      #pragma unroll
      for (int hh = 0; hh < 32; ++hh) s += hbuf[l * 32 + hh];
      seds[l] = s + sb2[l];
    }
    __syncthreads();
    float av = 0.0f;
    if (l < 32) {
      float z = fb1[l];
      #pragma unroll
      for (int d = 0; d < 10; ++d) {
        float cd = (d < 4) ? cps[d] : (d < 8) ? seds[d - 4] : scalars[b * 2 + (d - 8)];
        z += cd * fW1[l * 10 + d];
      }
      z = fmaxf(z, 0.0f);
      av = z * fw2[l];
    }
    #pragma unroll
    for (int off = 16; off > 0; off >>= 1) av += __shfl_down(av, off);
    if (l == 0) out[b] = av + fb2[0];
  }
}

// ---------------- final combine ----------------
__global__ __launch_bounds__(64) void combine_kernel(const float* __restrict__ eig,
    const double* __restrict__ diffP, const double* __restrict__ offP, const double* __restrict__ trP,
    const float* __restrict__ valo, const float* __restrict__ vali,
    const double* __restrict__ smallp, float* __restrict__ out)
{
  int l = threadIdx.x;
  float vo = valo[l], vi = vali[l];
  float el = 0, el2 = 0;
  #pragma unroll
  for (int e = 0; e < 4; ++e) {
    el  += fabsf(vo - eig[l * 4 + e]);
    el2 += fabsf(vi - eig[(64 + l) * 4 + e]);
  }
  float lo_ = el * 0.25f + 0.2f * (float)(diffP[l] * (1.0/65536.0)) - 0.1f * (float)(offP[l] * (1.0/65536.0));
  float li_ = el2 * 0.25f + 0.2f * (float)(diffP[64 + l] * (1.0/65536.0)) - 0.1f * (float)(offP[64 + l] * (1.0/65536.0));
  if (vo == 0.0f) lo_ = 0.0f;
  if (vi == 0.0f) li_ = 0.0f;
  float trb = (float)((trP[l] + trP[64 + l]) * (1.0/65536.0));
  #pragma unroll
  for (int off = 32; off > 0; off >>= 1) {
    lo_ += __shfl_down(lo_, off);
    li_ += __shfl_down(li_, off);
    trb += __shfl_down(trb, off);
  }
  if (l == 0) {
    out[64] = lo_ * (1.0f / 64.0f);
    out[65] = li_ * (1.0f / 64.0f);
    out[66] = (float)(smallp[0] / (64.0 * 6.0 * 65536.0));
    out[67] = 0.5f * (float)smallp[1] + 0.5f * (trb * (1.0f / 64.0f));
  }
}

extern "C" void kernel_launch(void* const* d_in, const int* in_sizes, int n_in,
                              void* d_out, int out_size, void* d_ws, size_t ws_size,
                              hipStream_t stream) {
  (void)in_sizes; (void)n_in; (void)out_size; (void)ws_size;
  const float* ti       = (const float*)d_in[0];
  const float* seed_ic  = (const float*)d_in[1];
  const float* seed_sir = (const float*)d_in[2];
  const float* seed_icc = (const float*)d_in[3];
  const float* seed_sirc= (const float*)d_in[4];
  const float* scalars  = (const float*)d_in[5];
  const float* valo     = (const float*)d_in[6];
  const float* vali     = (const float*)d_in[7];
  const float* S1p      = (const float*)d_in[8];
  const float* S2p      = (const float*)d_in[9];
  const float* S3p      = (const float*)d_in[10];
  const float* S4p      = (const float*)d_in[11];
  const float* cpA      = (const float*)d_in[12];
  const float* cpB      = (const float*)d_in[13];
  const float* cpC      = (const float*)d_in[14];
  const float* cpW1     = (const float*)d_in[15];
  const float* cpb1     = (const float*)d_in[16];
  const float* cpw2     = (const float*)d_in[17];
  const float* cpb2     = (const float*)d_in[18];
  const float* sW1      = (const float*)d_in[19];
  const float* sb1      = (const float*)d_in[20];
  const float* sw2      = (const float*)d_in[21];
  const float* sb2      = (const float*)d_in[22];
  const float* fW1      = (const float*)d_in[23];
  const float* fb1      = (const float*)d_in[24];
  const float* fw2      = (const float*)d_in[25];
  const float* fb2      = (const float*)d_in[26];

  char* ws = (char*)d_ws;
  unsigned* Mp     = (unsigned*)(ws + OFF_MP);
  ushort_t* Q0     = (ushort_t*)(ws + OFF_Q0);
  ushort_t* Q1     = (ushort_t*)(ws + OFF_Q1);
  ushort_t* Zb     = (ushort_t*)(ws + OFF_ZB);
  float*    eig    = (float*)(ws + OFF_EIG);
  double*   diffP  = (double*)(ws + OFF_DIFFP);
  double*   offP   = (double*)(ws + OFF_OFFP);
  double*   trP    = (double*)(ws + OFF_TRP);
  double*   smallp = (double*)(ws + OFF_SMALL);
  float*    out    = (float*)d_out;

  dim3 gg(4, 4, 128), gb(256);
  const size_t S6 = 6ull * 65536ull, S1b = 65536ull;
  // G1: Q0 = toBF(ti[0|2]) @ S{1,3}   (B transpose-staged from fp32 [K][N]; also inits partials)
  gemm_mfma<false, 2, true ><<<gg, gb, 0, stream>>>(
      (const void*)(ti + 0 * 65536), (const void*)(ti + 2 * 65536), S6,
      (const void*)S1p, (const void*)S3p, 0,
      (void*)Q0, S1b, smallp, diffP, offP, trP);
  // G2: Q1 = Q0 @ Z{1,2}r  (B transpose-staged from ti[4|5])
  gemm_mfma<true, 2, false><<<gg, gb, 0, stream>>>(
      (const void*)Q0, (const void*)(Q0 + 64 * 65536), S1b,
      (const void*)(ti + 4 * 65536), (const void*)(ti + 5 * 65536), S6,
      (void*)Q1, S1b, smallp, diffP, offP, trP);
  // G3: Q0 = Q1 @ S{2,4}
  gemm_mfma<true, 2, false><<<gg, gb, 0, stream>>>(
      (const void*)Q1, (const void*)(Q1 + 64 * 65536), S1b,
      (const void*)S2p, (const void*)S4p, 0,
      (void*)Q0, S1b, smallp, diffP, offP, trP);
  // G4: Zb = Q0 @ (sir2|ic2)^T  (B natural [N][K] fp32)
  gemm_mfma<true, 1, false><<<gg, gb, 0, stream>>>(
      (const void*)Q0, (const void*)(Q0 + 64 * 65536), S1b,
      (const void*)(ti + 3 * 65536), (const void*)(ti + 1 * 65536), S6,
      (void*)Zb, S1b, smallp, diffP, offP, trP);

  symm_reduce<<<2048, 256, 0, stream>>>(Zb, ti, Mp, diffP, offP, trP);

  mega_kernel<<<229, 1024, 0, stream>>>(
      Mp, eig, ti, Zb, cpA, cpB, cpC, smallp,
      S1p, S2p, S3p, S4p,
      seed_ic, seed_sir, seed_icc, seed_sirc, scalars,
      cpW1, cpb1, cpw2, cpb2, sW1, sb1, sw2, sb2,
      fW1, fb1, fw2, fb2, out);

  combine_kernel<<<1, 64, 0, stream>>>(eig, diffP, offP, trP, valo, vali, smallp, out);
}

// Round 11
// 187.845 us; speedup vs baseline: 7.3308x; 1.0956x over previous
//
#include <hip/hip_runtime.h>
#include <hip/hip_fp16.h>

#define LM 24

// ---------------- ws layout (bytes) ----------------
#define OFF_MP    0ull                    // packed f16 sym matrices (16MB)
#define OFF_Q0    16777216ull
#define OFF_Q1    33554432ull
#define OFF_ZB    33554432ull             // Zb overwrites Q1 after G3
#define OFF_EIG   50331648ull
#define OFF_DIFFP (OFF_EIG + 4096ull)
#define OFF_OFFP  (OFF_DIFFP + 1024ull)
#define OFF_TRP   (OFF_OFFP + 1024ull)
#define OFF_SMALL (OFF_TRP + 1024ull)

typedef unsigned short ushort_t;
typedef short bf16x8 __attribute__((ext_vector_type(8)));
typedef float f32x4 __attribute__((ext_vector_type(4)));

static __device__ __forceinline__ ushort_t f2bf(float f) {
  unsigned u = __float_as_uint(f);
  unsigned r = (u + 0x7fffu + ((u >> 16) & 1u)) >> 16;
  return (ushort_t)r;
}
static __device__ __forceinline__ unsigned packbf(float a, float b) {
  return (unsigned)f2bf(a) | ((unsigned)f2bf(b) << 16);
}
static __device__ __forceinline__ float bflo(unsigned u) { return __uint_as_float(u << 16); }
static __device__ __forceinline__ float bfhi(unsigned u) { return __uint_as_float(u & 0xffff0000u); }
static __device__ __forceinline__ float b2f(ushort_t u) { return __uint_as_float(((unsigned)u) << 16); }
static __device__ __forceinline__ __half2 u2h2(unsigned u) { __half2 r; *reinterpret_cast<unsigned*>(&r) = u; return r; }

// ---------------- MFMA GEMM, 128x128 tile, BK=32, 128 batches (split bases at b=64) ----------------
// BMODE 1: B stored [N][K] fp32 (C = A @ Bstored^T). BMODE 2: B stored [K][N] fp32, transpose-staged (C = A @ B).
template<bool ABF, int BMODE, bool INITP>
__global__ __launch_bounds__(256) void gemm_mfma(
    const void* __restrict__ A0, const void* __restrict__ A1, size_t sA,
    const void* __restrict__ B0, const void* __restrict__ B1, size_t sB,
    void* __restrict__ Cbase, size_t sC,
    double* __restrict__ smallp, double* __restrict__ diffP,
    double* __restrict__ offP, double* __restrict__ trP)
{
  __shared__ ushort_t At[128][40];
  __shared__ ushort_t Bt[128][40];
  const int t = threadIdx.x;
  if (INITP && blockIdx.x == 0 && blockIdx.y == 0 && blockIdx.z == 0) {
    if (t < 2) smallp[t] = 0.0;
    if (t < 128) { diffP[t] = 0.0; offP[t] = 0.0; trP[t] = 0.0; }
  }
  const int b = blockIdx.z;
  const int bl = (b < 64) ? b : b - 64;
  const void* Ab_ = (b < 64) ? A0 : A1;
  const void* Bb_ = (b < 64) ? B0 : B1;
  const int tm = blockIdx.y * 128, tn = blockIdx.x * 128;
  const int w = t >> 6, l = t & 63;
  const int wr = w >> 1, wc = w & 1;
  const int fr = l & 15, kc = l >> 4;

  f32x4 acc[4][4] = {};

  for (int s8 = 0; s8 < 8; ++s8) {
    const int k0 = s8 << 5;
    // ---- stage A: 128x32, 2 uint4-chunks per thread ----
    #pragma unroll
    for (int cc = 0; cc < 2; ++cc) {
      int c = t + cc * 256;
      int row = c >> 2, q = c & 3;
      if (ABF) {
        const ushort_t* Ap = (const ushort_t*)Ab_ + (size_t)bl * sA + (size_t)(tm + row) * 256 + k0 + q * 8;
        *(uint4*)&At[row][q * 8] = *(const uint4*)Ap;
      } else {
        const float* Ap = (const float*)Ab_ + (size_t)bl * sA + (size_t)(tm + row) * 256 + k0 + q * 8;
        float4 f0 = *(const float4*)Ap, f1 = *(const float4*)(Ap + 4);
        uint4 u;
        u.x = packbf(f0.x, f0.y); u.y = packbf(f0.z, f0.w);
        u.z = packbf(f1.x, f1.y); u.w = packbf(f1.z, f1.w);
        *(uint4*)&At[row][q * 8] = u;
      }
    }
    // ---- stage B ----
    if (BMODE == 1) {
      #pragma unroll
      for (int cc = 0; cc < 2; ++cc) {
        int c = t + cc * 256;
        int row = c >> 2, q = c & 3;
        const float* Bp = (const float*)Bb_ + (size_t)bl * sB + (size_t)(tn + row) * 256 + k0 + q * 8;
        float4 f0 = *(const float4*)Bp, f1 = *(const float4*)(Bp + 4);
        uint4 u;
        u.x = packbf(f0.x, f0.y); u.y = packbf(f0.z, f0.w);
        u.z = packbf(f1.x, f1.y); u.w = packbf(f1.z, f1.w);
        *(uint4*)&Bt[row][q * 8] = u;
      }
    } else {
      // B stored [K][N] fp32: Bt[n][k] = B[k0+k][tn+n]; thread handles k-pair 2k2,2k2+1 and 8 n's
      int k2 = t & 15, c = t >> 4;
      const float* Bp0 = (const float*)Bb_ + (size_t)bl * sB + (size_t)(k0 + 2 * k2) * 256 + tn + c * 8;
      const float* Bp1 = Bp0 + 256;
      float4 a0 = *(const float4*)Bp0, a1 = *(const float4*)(Bp0 + 4);
      float4 c0v = *(const float4*)Bp1, c1v = *(const float4*)(Bp1 + 4);
      float lo[8] = {a0.x,a0.y,a0.z,a0.w,a1.x,a1.y,a1.z,a1.w};
      float hi[8] = {c0v.x,c0v.y,c0v.z,c0v.w,c1v.x,c1v.y,c1v.z,c1v.w};
      unsigned* Bd = (unsigned*)&Bt[0][0];
      #pragma unroll
      for (int i = 0; i < 8; ++i) {
        int n = c * 8 + i;
        Bd[n * 20 + k2] = packbf(lo[i], hi[i]);
      }
    }
    __syncthreads();
    bf16x8 af[4], bfv[4];
    #pragma unroll
    for (int i = 0; i < 4; ++i) af[i] = *(const bf16x8*)&At[wr * 64 + i * 16 + fr][kc * 8];
    #pragma unroll
    for (int jj = 0; jj < 4; ++jj) bfv[jj] = *(const bf16x8*)&Bt[wc * 64 + jj * 16 + fr][kc * 8];
    #pragma unroll
    for (int i = 0; i < 4; ++i) {
      #pragma unroll
      for (int jj = 0; jj < 4; ++jj) {
        acc[i][jj] = __builtin_amdgcn_mfma_f32_16x16x32_bf16(af[i], bfv[jj], acc[i][jj], 0, 0, 0);
      }
    }
    __syncthreads();
  }

  ushort_t* Cp = (ushort_t*)Cbase + (size_t)b * sC;
  #pragma unroll
  for (int i = 0; i < 4; ++i) {
    #pragma unroll
    for (int q = 0; q < 4; ++q) {
      size_t rbase = (size_t)(tm + wr * 64 + i * 16 + kc * 4 + q) * 256;
      #pragma unroll
      for (int jj = 0; jj < 4; ++jj) {
        Cp[rbase + tn + wc * 64 + jj * 16 + fr] = f2bf(acc[i][jj][q]);
      }
    }
  }
}

// ---------------- fused symmetrize (-> packed f16, x1/64) + Z reductions ----------------
__global__ __launch_bounds__(256) void symm_reduce(const ushort_t* __restrict__ Zb,
                                                   const float* __restrict__ ti,
                                                   unsigned* __restrict__ Mp,
                                                   double* __restrict__ diffP, double* __restrict__ offP,
                                                   double* __restrict__ trP)
{
  __shared__ double dres[4][3];
  int mtx = blockIdx.x >> 4;
  int s = blockIdx.x & 15;
  int t = threadIdx.x;
  int lane = t & 63, wid = t >> 6;
  int z = mtx >> 6, b = mtx & 63;
  const ushort_t* M = Zb + (size_t)mtx * 65536;
  const float* Mr = ti + ((size_t)b * 6 + (z ? 5 : 4)) * 65536;
  int c0 = s << 4;
  uint4 r0 = *(const uint4*)(M + (size_t)t * 256 + c0);
  uint4 r1 = *(const uint4*)(M + (size_t)t * 256 + c0 + 8);
  float rj[16] = {bflo(r0.x),bfhi(r0.x),bflo(r0.y),bfhi(r0.y),bflo(r0.z),bfhi(r0.z),bflo(r0.w),bfhi(r0.w),
                  bflo(r1.x),bfhi(r1.x),bflo(r1.y),bfhi(r1.y),bflo(r1.z),bfhi(r1.z),bflo(r1.w),bfhi(r1.w)};
  float cv[16];
  double pd = 0.0, po = 0.0, ptr = 0.0;
  #pragma unroll
  for (int q = 0; q < 16; ++q) {
    int row = c0 + q;
    float av = b2f(M[(size_t)row * 256 + t]);
    cv[q] = av;
    float mrv = Mr[(size_t)row * 256 + t];
    bool diag = (t == row);
    pd += (double)fabsf(av - (diag ? 1.0f : 0.0f));
    po += diag ? 0.0 : (double)fabsf(av);
    ptr += (double)fabsf(av - mrv);
  }
  unsigned* Mo = Mp + (size_t)mtx * 32768;
  #pragma unroll
  for (int p = 0; p < 8; ++p) {
    float m0 = 0.5f * (rj[2 * p]     + cv[2 * p]) * 0.015625f;
    float m1 = 0.5f * (rj[2 * p + 1] + cv[2 * p + 1]) * 0.015625f;
    unsigned u = (unsigned)__half_as_ushort(__float2half_rn(m0)) |
                 ((unsigned)__half_as_ushort(__float2half_rn(m1)) << 16);
    Mo[(size_t)((s << 3) + p) * 256 + t] = u;
  }
  #pragma unroll
  for (int off = 32; off > 0; off >>= 1) {
    pd += __shfl_down(pd, off);
    po += __shfl_down(po, off);
    ptr += __shfl_down(ptr, off);
  }
  if (lane == 0) { dres[wid][0] = pd; dres[wid][1] = po; dres[wid][2] = ptr; }
  __syncthreads();
  if (t == 0) {
    atomicAdd(&diffP[mtx], dres[0][0] + dres[1][0] + dres[2][0] + dres[3][0]);
    atomicAdd(&offP[mtx],  dres[0][1] + dres[1][1] + dres[2][1] + dres[3][1]);
    atomicAdd(&trP[mtx],   dres[0][2] + dres[1][2] + dres[2][2] + dres[3][2]);
  }
}

// ================= MEGA KERNEL: lanczos (0..127) | cp (128..223) | sreg (224) | head (225..228) =================
struct LanSh {
  unsigned vpack[128];
  float wtmp[4][256];
  float red2[4][2];
  float red1[16];
  float alpha[LM];
  float betaArr[LM + 1];
  float beta2arr[LM + 1];
};
struct CpSh { float Bsh[4][256][4]; float Csh[4][256][4]; double red[4][256]; };
struct SregSh { double red[4][256]; };
struct HeadSh { float tri[16][4][3]; float cps[16][4]; float seds[16][4]; float hbuf[16][128]; };
union MegaSh { LanSh lan; CpSh cp; SregSh sreg; HeadSh head; };

__global__ __launch_bounds__(1024, 1) void mega_kernel(
    const unsigned* __restrict__ Mp, float* __restrict__ eig,
    const float* __restrict__ ti, const ushort_t* __restrict__ Zb,
    const float* __restrict__ cpA, const float* __restrict__ cpB, const float* __restrict__ cpC,
    double* __restrict__ smallp,
    const float* __restrict__ S1, const float* __restrict__ S2,
    const float* __restrict__ S3, const float* __restrict__ S4,
    const float* __restrict__ seed_ic, const float* __restrict__ seed_sir,
    const float* __restrict__ seed_icc, const float* __restrict__ seed_sirc,
    const float* __restrict__ scalars,
    const float* __restrict__ cpW1, const float* __restrict__ cpb1,
    const float* __restrict__ cpw2, const float* __restrict__ cpb2,
    const float* __restrict__ sW1, const float* __restrict__ sb1,
    const float* __restrict__ sw2, const float* __restrict__ sb2,
    const float* __restrict__ fW1, const float* __restrict__ fb1,
    const float* __restrict__ fw2, const float* __restrict__ fb2,
    float* __restrict__ out)
{
  __shared__ MegaSh sh;
  const int bid = blockIdx.x;
  const int t = threadIdx.x;

  if (bid < 128) {
    // ---------------- Lanczos on M/64 (f16), h0-waves own the vector state ----------------
    int lane = t & 63, w16 = t >> 6;
    int r = t & 255, h = t >> 8;
    int mtx = bid;
    const unsigned* Mb = Mp + (size_t)mtx * 32768 + r;
    unsigned m[32];
    #pragma unroll
    for (int q = 0; q < 32; ++q) m[q] = Mb[(size_t)(h * 32 + q) * 256];

    unsigned u0 = (unsigned)r * 1103515245u + 12345u;
    float r0v = 0.05f + (float)((u0 >> 9) & 0x7FFF) * (1.0f / 32768.0f);
    float vt = 0.0f, vprev = 0.0f;
    {
      float nv = r0v * r0v;
      #pragma unroll
      for (int off = 32; off > 0; off >>= 1) nv += __shfl_down(nv, off);
      if (lane == 0) sh.lan.red1[w16] = nv;
    }
    __syncthreads();
    {
      float nrm2 = sh.lan.red1[0] + sh.lan.red1[1] + sh.lan.red1[2] + sh.lan.red1[3];
      vt = r0v * rsqrtf(nrm2);
      if (h == 0) {
        float vo = __shfl_down(vt, 1);
        if ((lane & 1) == 0)
          sh.lan.vpack[t >> 1] = (unsigned)__half_as_ushort(__float2half_rn(vt)) |
                                 ((unsigned)__half_as_ushort(__float2half_rn(vo)) << 16);
      }
    }
    __syncthreads();

    const uint4* vp4 = (const uint4*)sh.lan.vpack;
    float2* red2 = (float2*)&sh.lan.red2[0][0];
    float beta_prev = 0.0f;
    int meff = LM;
    for (int j = 0; j < LM; ++j) {
      __half2 h0v = u2h2(0u), h1v = u2h2(0u), h2v = u2h2(0u), h3v = u2h2(0u);
      #pragma unroll
      for (int q = 0; q < 8; ++q) {
        uint4 vu = vp4[h * 8 + q];
        h0v = __hfma2(u2h2(m[4 * q + 0]), u2h2(vu.x), h0v);
        h1v = __hfma2(u2h2(m[4 * q + 1]), u2h2(vu.y), h1v);
        h2v = __hfma2(u2h2(m[4 * q + 2]), u2h2(vu.z), h2v);
        h3v = __hfma2(u2h2(m[4 * q + 3]), u2h2(vu.w), h3v);
      }
      float2 f0 = __half22float2(h0v), f1 = __half22float2(h1v);
      float2 f2 = __half22float2(h2v), f3 = __half22float2(h3v);
      sh.lan.wtmp[h][r] = ((f0.x + f0.y) + (f1.x + f1.y)) + ((f2.x + f2.y) + (f3.x + f3.y));
      float wt = 0.0f;
      __syncthreads();                                      // B1
      if (h == 0) {
        wt = sh.lan.wtmp[0][r] + sh.lan.wtmp[1][r] + sh.lan.wtmp[2][r] + sh.lan.wtmp[3][r];
        float s1 = wt * vt, s3 = wt * wt;
        #pragma unroll
        for (int off = 32; off > 0; off >>= 1) {
          s1 += __shfl_down(s1, off);
          s3 += __shfl_down(s3, off);
        }
        if (lane == 0) red2[w16] = make_float2(s1, s3);
      }
      __syncthreads();                                      // B2
      float2 p0 = red2[0], p1 = red2[1], p2 = red2[2], p3 = red2[3];
      float S1v = ((p0.x + p1.x) + (p2.x + p3.x));
      float S3v = ((p0.y + p1.y) + (p2.y + p3.y));
      float bn2 = S3v - S1v * S1v - beta_prev * beta_prev;
      float bn = sqrtf(fmaxf(bn2, 1e-30f));
      if (t == 0) { sh.lan.alpha[j] = S1v; sh.lan.betaArr[j + 1] = bn; sh.lan.beta2arr[j + 1] = bn * bn; }
      if (bn < 1e-6f * (fabsf(S1v) + 1.0f)) { meff = j + 1; break; }
      if (h == 0) {
        float wn = (wt - S1v * vt - beta_prev * vprev) / bn;
        vprev = vt; vt = wn;
        float vo = __shfl_down(vt, 1);
        if ((lane & 1) == 0)
          sh.lan.vpack[t >> 1] = (unsigned)__half_as_ushort(__float2half_rn(vt)) |
                                 ((unsigned)__half_as_ushort(__float2half_rn(vo)) << 16);
      }
      beta_prev = bn;
      __syncthreads();                                      // B3
    }
    __syncthreads();

    if (w16 < 4) {
      float lo = 1e30f, hi = -1e30f;
      for (int i = 0; i < meff; ++i) {
        float bl = (i > 0) ? sh.lan.betaArr[i] : 0.0f;
        float bu = (i + 1 < meff) ? sh.lan.betaArr[i + 1] : 0.0f;
        lo = fminf(lo, sh.lan.alpha[i] - bl - bu);
        hi = fmaxf(hi, sh.lan.alpha[i] + bl + bu);
      }
      int q = w16 + 1; if (q > meff - 1) q = meff - 1;
      #pragma unroll
      for (int rr = 0; rr < 3; ++rr) {
        float step = (hi - lo) * (1.0f / 65.0f);
        float mid = lo + step * (float)(lane + 1);
        int cnt = 0;
        float d = sh.lan.alpha[0] - mid;
        if (fabsf(d) < 1e-20f) d = -1e-20f;
        cnt += (d < 0.0f);
        for (int i = 1; i < meff; ++i) {
          d = sh.lan.alpha[i] - mid - sh.lan.beta2arr[i] / d;
          if (fabsf(d) < 1e-20f) d = -1e-20f;
          cnt += (d < 0.0f);
        }
        unsigned long long mask = __ballot(cnt >= q + 1);
        if (mask == 0ULL) {
          lo = lo + step * 64.0f;
        } else {
          int idx = __ffsll(mask) - 1;
          float nlo = lo + step * (float)idx;
          hi = lo + step * (float)(idx + 1);
          lo = nlo;
        }
      }
      if (lane == 0) eig[mtx * 4 + w16] = 32.0f * (lo + hi);   // 0.5*(lo+hi) * 64
    }
  } else if (bid < 224) {
    // ---------------- CP loss: 4 groups of 256 threads ----------------
    int g = t >> 8, tid = t & 255;
    int unit = (bid - 128) * 4 + g;
    int b = unit / 6, i = unit - b * 6;
    float (*Bsh)[4] = sh.cp.Bsh[g];
    float (*Csh)[4] = sh.cp.Csh[g];
    double* red = sh.cp.red[g];
    *(float4*)&Bsh[tid][0] = *(const float4*)(cpB + ((size_t)b * 256 + tid) * 4);
    *(float4*)&Csh[tid][0] = *(const float4*)(cpC + ((size_t)b * 256 + tid) * 4);
    float a0 = cpA[((size_t)b * 6 + i) * 4 + 0];
    float a1 = cpA[((size_t)b * 6 + i) * 4 + 1];
    float a2 = cpA[((size_t)b * 6 + i) * 4 + 2];
    float a3 = cpA[((size_t)b * 6 + i) * 4 + 3];
    __syncthreads();
    float c0 = Csh[tid][0], c1 = Csh[tid][1], c2 = Csh[tid][2], c3 = Csh[tid][3];
    double acc = 0;
    if (i < 4) {
      const float* T = ti + ((size_t)b * 6 + i) * 65536;
      #pragma unroll 4
      for (int j = 0; j < 256; ++j) {
        float recon = a0 * Bsh[j][0] * c0 + a1 * Bsh[j][1] * c1 + a2 * Bsh[j][2] * c2 + a3 * Bsh[j][3] * c3;
        float dv = recon - T[(size_t)j * 256 + tid];
        acc += (double)dv * (double)dv;
      }
    } else {
      const ushort_t* T = Zb + (size_t)((i == 4) ? b : 64 + b) * 65536;
      #pragma unroll 4
      for (int j = 0; j < 256; ++j) {
        float recon = a0 * Bsh[j][0] * c0 + a1 * Bsh[j][1] * c1 + a2 * Bsh[j][2] * c2 + a3 * Bsh[j][3] * c3;
        float dv = recon - b2f(T[(size_t)j * 256 + tid]);
        acc += (double)dv * (double)dv;
      }
    }
    red[tid] = acc; __syncthreads();
    #pragma unroll
    for (int s = 128; s > 0; s >>= 1) { if (tid < s) red[tid] += red[tid + s]; __syncthreads(); }
    if (tid == 0) atomicAdd(&smallp[0], red[0]);
  } else if (bid == 224) {
    // ---------------- sreg: 4 groups, one S matrix each ----------------
    int g = t >> 8, tid = t & 255;
    const float* S = (g == 0) ? S1 : (g == 1) ? S2 : (g == 2) ? S3 : S4;
    double* red = sh.sreg.red[g];
    double tot = 0;
    for (int e = tid; e < 65536; e += 256) {
      int i = e >> 8, j = e & 255;
      float a = S[e];
      tot += (double)fabsf(a - (i == j ? 1.0f : 0.0f));
      if (i != j) tot += (double)fabsf(a);
    }
    red[tid] = tot; __syncthreads();
    #pragma unroll
    for (int s = 128; s > 0; s >>= 1) { if (tid < s) red[tid] += red[tid + s]; __syncthreads(); }
    if (tid == 0) atomicAdd(&smallp[1], -red[0] / 65536.0);
  } else {
    // ---------------- heads: 16 groups of 64 lanes, one batch each ----------------
    int g = t >> 6, l = t & 63;
    int b = (bid - 225) * 16 + g;
    float (*tri)[3] = sh.head.tri[g];
    float* cps = sh.head.cps[g];
    float* seds = sh.head.seds[g];
    float* hbuf = sh.head.hbuf[g];
    if (l < 4) {
      float s = 0;
      #pragma unroll
      for (int i = 0; i < 6; ++i) s += cpA[((size_t)b * 6 + i) * 4 + l];
      tri[l][0] = s * (1.0f / 6.0f);
    }
    float4 sB = make_float4(0,0,0,0), sC = make_float4(0,0,0,0);
    for (int j = l; j < 256; j += 64) {
      float4 v = *(const float4*)(cpB + ((size_t)b * 256 + j) * 4);
      sB.x += v.x; sB.y += v.y; sB.z += v.z; sB.w += v.w;
      float4 w = *(const float4*)(cpC + ((size_t)b * 256 + j) * 4);
      sC.x += w.x; sC.y += w.y; sC.z += w.z; sC.w += w.w;
    }
    #pragma unroll
    for (int off = 32; off > 0; off >>= 1) {
      sB.x += __shfl_down(sB.x, off); sB.y += __shfl_down(sB.y, off);
      sB.z += __shfl_down(sB.z, off); sB.w += __shfl_down(sB.w, off);
      sC.x += __shfl_down(sC.x, off); sC.y += __shfl_down(sC.y, off);
      sC.z += __shfl_down(sC.z, off); sC.w += __shfl_down(sC.w, off);
    }
    if (l == 0) {
      tri[0][1] = sB.x * (1.0f/256.0f); tri[1][1] = sB.y * (1.0f/256.0f);
      tri[2][1] = sB.z * (1.0f/256.0f); tri[3][1] = sB.w * (1.0f/256.0f);
      tri[0][2] = sC.x * (1.0f/256.0f); tri[1][2] = sC.y * (1.0f/256.0f);
      tri[2][2] = sC.z * (1.0f/256.0f); tri[3][2] = sC.w * (1.0f/256.0f);
    }
    __syncthreads();
    if (l < 4) {
      float s = 0;
      for (int hh = 0; hh < 32; ++hh) {
        float z = cpb1[l * 32 + hh];
        #pragma unroll
        for (int d = 0; d < 3; ++d) z += tri[l][d] * cpW1[(l * 32 + hh) * 3 + d];
        z = fmaxf(z, 0.0f);
        s += z * cpw2[l * 32 + hh];
      }
      cps[l] = s + cpb2[l];
    }
    for (int p = l; p < 128; p += 64) {
      int j = p >> 5, hh = p & 31;
      const float* sv = (j == 0) ? seed_ic : (j == 1) ? seed_sir : (j == 2) ? seed_icc : seed_sirc;
      sv += (size_t)b * 256;
      const float* wrow = sW1 + ((size_t)(j * 32 + hh)) * 256;
      float z = sb1[j * 32 + hh];
      for (int k = 0; k < 256; k += 4) {
        float4 a = *(const float4*)(sv + k);
        float4 w4 = *(const float4*)(wrow + k);
        z += a.x * w4.x + a.y * w4.y + a.z * w4.z + a.w * w4.w;
      }
      z = fmaxf(z, 0.0f);
      hbuf[p] = z * sw2[j * 32 + hh];
    }
    __syncthreads();
    if (l < 4) {
      float s = 0;
      #pragma unroll
      for (int hh = 0; hh < 32; ++hh) s += hbuf[l * 32 + hh];
      seds[l] = s + sb2[l];
    }
    __syncthreads();
    float av = 0.0f;
    if (l < 32) {
      float z = fb1[l];
      #pragma unroll
      for (int d = 0; d < 10; ++d) {
        float cd = (d < 4) ? cps[d] : (d < 8) ? seds[d - 4] : scalars[b * 2 + (d - 8)];
        z += cd * fW1[l * 10 + d];
      }
      z = fmaxf(z, 0.0f);
      av = z * fw2[l];
    }
    #pragma unroll
    for (int off = 16; off > 0; off >>= 1) av += __shfl_down(av, off);
    if (l == 0) out[b] = av + fb2[0];
  }
}

// ---------------- final combine ----------------
__global__ __launch_bounds__(64) void combine_kernel(const float* __restrict__ eig,
    const double* __restrict__ diffP, const double* __restrict__ offP, const double* __restrict__ trP,
    const float* __restrict__ valo, const float* __restrict__ vali,
    const double* __restrict__ smallp, float* __restrict__ out)
{
  int l = threadIdx.x;
  float vo = valo[l], vi = vali[l];
  float el = 0, el2 = 0;
  #pragma unroll
  for (int e = 0; e < 4; ++e) {
    el  += fabsf(vo - eig[l * 4 + e]);
    el2 += fabsf(vi - eig[(64 + l) * 4 + e]);
  }
  float lo_ = el * 0.25f + 0.2f * (float)(diffP[l] * (1.0/65536.0)) - 0.1f * (float)(offP[l] * (1.0/65536.0));
  float li_ = el2 * 0.25f + 0.2f * (float)(diffP[64 + l] * (1.0/65536.0)) - 0.1f * (float)(offP[64 + l] * (1.0/65536.0));
  if (vo == 0.0f) lo_ = 0.0f;
  if (vi == 0.0f) li_ = 0.0f;
  float trb = (float)((trP[l] + trP[64 + l]) * (1.0/65536.0));
  #pragma unroll
  for (int off = 32; off > 0; off >>= 1) {
    lo_ += __shfl_down(lo_, off);
    li_ += __shfl_down(li_, off);
    trb += __shfl_down(trb, off);
  }
  if (l == 0) {
    out[64] = lo_ * (1.0f / 64.0f);
    out[65] = li_ * (1.0f / 64.0f);
    out[66] = (float)(smallp[0] / (64.0 * 6.0 * 65536.0));
    out[67] = 0.5f * (float)smallp[1] + 0.5f * (trb * (1.0f / 64.0f));
  }
}

extern "C" void kernel_launch(void* const* d_in, const int* in_sizes, int n_in,
                              void* d_out, int out_size, void* d_ws, size_t ws_size,
                              hipStream_t stream) {
  (void)in_sizes; (void)n_in; (void)out_size; (void)ws_size;
  const float* ti       = (const float*)d_in[0];
  const float* seed_ic  = (const float*)d_in[1];
  const float* seed_sir = (const float*)d_in[2];
  const float* seed_icc = (const float*)d_in[3];
  const float* seed_sirc= (const float*)d_in[4];
  const float* scalars  = (const float*)d_in[5];
  const float* valo     = (const float*)d_in[6];
  const float* vali     = (const float*)d_in[7];
  const float* S1p      = (const float*)d_in[8];
  const float* S2p      = (const float*)d_in[9];
  const float* S3p      = (const float*)d_in[10];
  const float* S4p      = (const float*)d_in[11];
  const float* cpA      = (const float*)d_in[12];
  const float* cpB      = (const float*)d_in[13];
  const float* cpC      = (const float*)d_in[14];
  const float* cpW1     = (const float*)d_in[15];
  const float* cpb1     = (const float*)d_in[16];
  const float* cpw2     = (const float*)d_in[17];
  const float* cpb2     = (const float*)d_in[18];
  const float* sW1      = (const float*)d_in[19];
  const float* sb1      = (const float*)d_in[20];
  const float* sw2      = (const float*)d_in[21];
  const float* sb2      = (const float*)d_in[22];
  const float* fW1      = (const float*)d_in[23];
  const float* fb1      = (const float*)d_in[24];
  const float* fw2      = (const float*)d_in[25];
  const float* fb2      = (const float*)d_in[26];

  char* ws = (char*)d_ws;
  unsigned* Mp     = (unsigned*)(ws + OFF_MP);
  ushort_t* Q0     = (ushort_t*)(ws + OFF_Q0);
  ushort_t* Q1     = (ushort_t*)(ws + OFF_Q1);
  ushort_t* Zb     = (ushort_t*)(ws + OFF_ZB);
  float*    eig    = (float*)(ws + OFF_EIG);
  double*   diffP  = (double*)(ws + OFF_DIFFP);
  double*   offP   = (double*)(ws + OFF_OFFP);
  double*   trP    = (double*)(ws + OFF_TRP);
  double*   smallp = (double*)(ws + OFF_SMALL);
  float*    out    = (float*)d_out;

  dim3 gg(2, 2, 128), gb(256);
  const size_t S6 = 6ull * 65536ull, S1b = 65536ull;
  // G1: Q0 = toBF(ti[0|2]) @ S{1,3}   (B transpose-staged from fp32 [K][N]; also inits partials)
  gemm_mfma<false, 2, true ><<<gg, gb, 0, stream>>>(
      (const void*)(ti + 0 * 65536), (const void*)(ti + 2 * 65536), S6,
      (const void*)S1p, (const void*)S3p, 0,
      (void*)Q0, S1b, smallp, diffP, offP, trP);
  // G2: Q1 = Q0 @ Z{1,2}r  (B transpose-staged from ti[4|5])
  gemm_mfma<true, 2, false><<<gg, gb, 0, stream>>>(
      (const void*)Q0, (const void*)(Q0 + 64 * 65536), S1b,
      (const void*)(ti + 4 * 65536), (const void*)(ti + 5 * 65536), S6,
      (void*)Q1, S1b, smallp, diffP, offP, trP);
  // G3: Q0 = Q1 @ S{2,4}
  gemm_mfma<true, 2, false><<<gg, gb, 0, stream>>>(
      (const void*)Q1, (const void*)(Q1 + 64 * 65536), S1b,
      (const void*)S2p, (const void*)S4p, 0,
      (void*)Q0, S1b, smallp, diffP, offP, trP);
  // G4: Zb = Q0 @ (sir2|ic2)^T  (B natural [N][K] fp32)
  gemm_mfma<true, 1, false><<<gg, gb, 0, stream>>>(
      (const void*)Q0, (const void*)(Q0 + 64 * 65536), S1b,
      (const void*)(ti + 3 * 65536), (const void*)(ti + 1 * 65536), S6,
      (void*)Zb, S1b, smallp, diffP, offP, trP);

  symm_reduce<<<2048, 256, 0, stream>>>(Zb, ti, Mp, diffP, offP, trP);

  mega_kernel<<<229, 1024, 0, stream>>>(
      Mp, eig, ti, Zb, cpA, cpB, cpC, smallp,
      S1p, S2p, S3p, S4p,
      seed_ic, seed_sir, seed_icc, seed_sirc, scalars,
      cpW1, cpb1, cpw2, cpb2, sW1, sb1, sw2, sb2,
      fW1, fb1, fw2, fb2, out);

  combine_kernel<<<1, 64, 0, stream>>>(eig, diffP, offP, trP, valo, vali, smallp, out);
}